// Round 1
// baseline (841.672 us; speedup 1.0000x reference)
//
#include <hip/hip_runtime.h>
#include <math.h>

typedef unsigned short u16;
typedef unsigned int u32;
typedef __bf16 bf16x8 __attribute__((ext_vector_type(8)));
typedef float f32x4 __attribute__((ext_vector_type(4)));

#define NPQ 512
#define MNP 4096
#define BSZ 8
#define DIM 256
#define NH 8
#define HD 32
#define TOPK 32
#define FFD 2048
#define SCALE 0.17677669529663687f  // 1/sqrt(32)

__device__ __forceinline__ u16 f2bf(float f){
  u32 u = __builtin_bit_cast(u32, f);
  u = (u + 0x7FFFu + ((u >> 16) & 1u)) >> 16;
  return (u16)u;
}
__device__ __forceinline__ float bf2f(u16 h){
  u32 u = ((u32)h) << 16;
  return __builtin_bit_cast(float, u);
}
__device__ __forceinline__ float wredsum(float v){
#pragma unroll
  for (int m = 32; m; m >>= 1) v += __shfl_xor(v, m, 64);
  return v;
}
__device__ __forceinline__ float gelu_exact(float x){
  return 0.5f * x * (1.0f + erff(x * 0.70710678118654752f));
}

// ---------------- fp32 -> bf16 convert ----------------
__global__ __launch_bounds__(256)
void cvt_bf16(const float* __restrict__ s, u16* __restrict__ d, int n){
  for (int i = blockIdx.x*256 + threadIdx.x; i < n; i += gridDim.x*256)
    d[i] = f2bf(s[i]);
}

// ---------------- prep: normalize + split + pos-add ----------------
__global__ __launch_bounds__(256)
void prep_tgt(const float* __restrict__ tgt, const float* __restrict__ qpos,
              u16* __restrict__ xnh, u16* __restrict__ xnl, u16* __restrict__ qc){
  __shared__ float sc[4];
  int r = blockIdx.x, t = threadIdx.x;
  int b = r >> 9, n = r & 511;
  long src = ((long)n*BSZ + b)*DIM + t;
  float x = tgt[src];
  float s = wredsum(x*x);
  if ((t & 63) == 0) sc[t >> 6] = s;
  __syncthreads();
  float tot = sc[0]+sc[1]+sc[2]+sc[3];
  float xn = x / sqrtf(tot);
  u16 hi = f2bf(xn);
  long dst = (long)r*DIM + t;
  xnh[dst] = hi;
  xnl[dst] = f2bf(xn - bf2f(hi));
  qc[dst]  = f2bf(x + qpos[src]);
}

__global__ __launch_bounds__(256)
void prep_mem(const float* __restrict__ mem, const float* __restrict__ kpos,
              u16* __restrict__ mnh, u16* __restrict__ mnl,
              u16* __restrict__ kc, u16* __restrict__ vc){
  __shared__ float sc[4];
  int r = blockIdx.x, t = threadIdx.x;
  int b = r >> 12, mp = r & 4095;
  long src = ((long)mp*BSZ + b)*DIM + t;
  float x = mem[src];
  float s = wredsum(x*x);
  if ((t & 63) == 0) sc[t >> 6] = s;
  __syncthreads();
  float tot = sc[0]+sc[1]+sc[2]+sc[3];
  float xn = x / sqrtf(tot);
  u16 hi = f2bf(xn);
  long dst = (long)r*DIM + t;
  mnh[dst] = hi;
  mnl[dst] = f2bf(xn - bf2f(hi));
  kc[dst]  = f2bf(x + kpos[src]);
  vc[dst]  = f2bf(x);
}

// ---------------- MFMA GEMM: C[M,N] = A[M,K] * B[N,K]^T (+bias, act) ----
// lda == ldb == K, ldc == N.  SPLIT: A=(A+A2),B=(B+B2) hi/lo, drop lo*lo.
template<int OUT_BF16, int ACT, int SPLIT>
__global__ __launch_bounds__(256)
void gemm_bt(const u16* __restrict__ A, const u16* __restrict__ A2,
             const u16* __restrict__ B, const u16* __restrict__ B2,
             const float* __restrict__ bias, void* __restrict__ Cv,
             int M, int N, int K, long sA, long sB, long sC){
  int lane = threadIdx.x & 63, wv = threadIdx.x >> 6;
  int ml = lane & 15, quad = lane >> 4;
  int tM = blockIdx.x * 128 + (wv & 1) * 64;
  int tN = blockIdx.y * 128 + (wv >> 1) * 64;
  const u16* Ap  = A + (long)blockIdx.z*sA + (long)(tM + ml)*K + quad*8;
  const u16* Bp  = B + (long)blockIdx.z*sB + (long)(tN + ml)*K + quad*8;
  const u16* Ap2 = Ap; const u16* Bp2 = Bp;
  if (SPLIT){
    Ap2 = A2 + (long)blockIdx.z*sA + (long)(tM + ml)*K + quad*8;
    Bp2 = B2 + (long)blockIdx.z*sB + (long)(tN + ml)*K + quad*8;
  }
  f32x4 acc[4][4];
  f32x4 zer = {0.f, 0.f, 0.f, 0.f};
#pragma unroll
  for (int i = 0; i < 4; i++)
#pragma unroll
    for (int j = 0; j < 4; j++) acc[i][j] = zer;
  long rs = (long)16 * K;
  for (int k0 = 0; k0 < K; k0 += 32){
    bf16x8 a[4], b[4];
#pragma unroll
    for (int i = 0; i < 4; i++) a[i] = *(const bf16x8*)(Ap + i*rs + k0);
#pragma unroll
    for (int j = 0; j < 4; j++) b[j] = *(const bf16x8*)(Bp + j*rs + k0);
#pragma unroll
    for (int i = 0; i < 4; i++)
#pragma unroll
      for (int j = 0; j < 4; j++)
        acc[i][j] = __builtin_amdgcn_mfma_f32_16x16x32_bf16(a[i], b[j], acc[i][j], 0, 0, 0);
    if (SPLIT){
      bf16x8 a2[4], b2[4];
#pragma unroll
      for (int i = 0; i < 4; i++) a2[i] = *(const bf16x8*)(Ap2 + i*rs + k0);
#pragma unroll
      for (int j = 0; j < 4; j++) b2[j] = *(const bf16x8*)(Bp2 + j*rs + k0);
#pragma unroll
      for (int i = 0; i < 4; i++)
#pragma unroll
        for (int j = 0; j < 4; j++){
          acc[i][j] = __builtin_amdgcn_mfma_f32_16x16x32_bf16(a[i],  b2[j], acc[i][j], 0, 0, 0);
          acc[i][j] = __builtin_amdgcn_mfma_f32_16x16x32_bf16(a2[i], b[j],  acc[i][j], 0, 0, 0);
        }
    }
  }
  long zC = (long)blockIdx.z * sC;
#pragma unroll
  for (int j = 0; j < 4; j++){
    int col = tN + j*16 + ml;
    float bv = bias ? bias[col] : 0.0f;
#pragma unroll
    for (int i = 0; i < 4; i++){
#pragma unroll
      for (int r = 0; r < 4; r++){
        int row = tM + i*16 + quad*4 + r;
        float v = acc[i][j][r] + bv;
        if (ACT == 1) v = gelu_exact(v);
        long idx = zC + (long)row * N + col;
        if (OUT_BF16) ((u16*)Cv)[idx] = f2bf(v);
        else ((float*)Cv)[idx] = v;
      }
    }
  }
}

// ---------------- top-k (exact: value desc, index asc tie-break) --------
__global__ __launch_bounds__(256)
void topk_k(const float* __restrict__ sim, int* __restrict__ rns){
  __shared__ float v[4096];
  __shared__ float wr[4];
  __shared__ int   wi[4];
  int r = blockIdx.x, t = threadIdx.x;
  const float* row = sim + (long)r * 4096;
  for (int i = t; i < 4096; i += 256) v[i] = row[i];
  __syncthreads();
  for (int sel = 0; sel < 32; sel++){
    float bv = -3.4e38f; int bi = 0;
    for (int i = t; i < 4096; i += 256){
      float x = v[i];
      if (x > bv){ bv = x; bi = i; }
    }
#pragma unroll
    for (int m = 32; m; m >>= 1){
      float ov = __shfl_xor(bv, m, 64);
      int   oi = __shfl_xor(bi, m, 64);
      if (ov > bv || (ov == bv && oi < bi)){ bv = ov; bi = oi; }
    }
    if ((t & 63) == 0){ wr[t >> 6] = bv; wi[t >> 6] = bi; }
    __syncthreads();
    if (t == 0){
      for (int k = 1; k < 4; k++)
        if (wr[k] > bv || (wr[k] == bv && wi[k] < bi)){ bv = wr[k]; bi = wi[k]; }
      rns[(long)r*32 + sel] = bi;
      v[bi] = -3.4e38f;
    }
    __syncthreads();
  }
}

// ---------------- sparse gathered cross-attention ----------------
#define CAS 270
__global__ __launch_bounds__(256)
void cross_attn(const u16* __restrict__ qh, const u16* __restrict__ kh,
                const u16* __restrict__ vh, const int* __restrict__ rns,
                float* __restrict__ crossO){
  __shared__ u16 Kg[32*CAS];
  __shared__ u16 Vg[32*CAS];
  __shared__ float qv[256];
  __shared__ int idxs[32];
  __shared__ float L[256];
  __shared__ float pm[8], ps[8];
  int r = blockIdx.x, t = threadIdx.x;
  int b = r >> 9;
  if (t < 32) idxs[t] = rns[(long)r*32 + t];
  qv[t] = bf2f(qh[(long)r*DIM + t]);
  __syncthreads();
  for (int i = t; i < 32*DIM; i += 256){
    int k = i >> 8, d = i & 255;
    long src = ((long)b*MNP + idxs[k])*DIM + d;
    Kg[k*CAS + d] = kh[src];
    Vg[k*CAS + d] = vh[src];
  }
  __syncthreads();
  {
    int h = t >> 5, k = t & 31;
    float acc = 0.f;
#pragma unroll
    for (int d = 0; d < 32; d++) acc += qv[h*HD + d] * bf2f(Kg[k*CAS + h*HD + d]);
    L[t] = acc * SCALE;
  }
  __syncthreads();
  if (t < 8){
    float m = L[t*32];
    for (int k = 1; k < 32; k++) m = fmaxf(m, L[t*32 + k]);
    float s = 0.f;
    for (int k = 0; k < 32; k++) s += expf(L[t*32 + k] - m);
    pm[t] = m; ps[t] = s;
  }
  __syncthreads();
  {
    int h = t >> 5, dd = t & 31;
    float m = pm[h], inv = 1.0f/ps[h], acc = 0.f;
#pragma unroll
    for (int k = 0; k < 32; k++) acc += expf(L[h*32 + k] - m) * bf2f(Vg[k*CAS + h*HD + dd]);
    crossO[(long)r*DIM + t] = acc * inv;
  }
}

// ---------------- fused layernorms ----------------
// MODE 1: x = tgt[n-major] + xb[b-major]; out t1(f32,b), t1b(bf16), qkb=bf16(t1+qpos)
// MODE 2: x = xa[b] + xb[b];              out t2(f32,b), t2b(bf16)
// MODE 3: x = xa[b] + xb[b];              out yf[n-major] (d_out)
template<int MODE>
__global__ __launch_bounds__(256)
void ln_k(const float* __restrict__ xa, const float* __restrict__ xb,
          const float* __restrict__ qpos,
          const float* __restrict__ w, const float* __restrict__ bsh,
          float* __restrict__ yf, u16* __restrict__ yb, u16* __restrict__ qkb){
  __shared__ float sc[8];
  int r = blockIdx.x, t = threadIdx.x;
  int b = r >> 9, n = r & 511;
  long bidx = (long)r*DIM + t;
  long nidx = ((long)n*BSZ + b)*DIM + t;
  float x = (MODE == 1 ? xa[nidx] : xa[bidx]) + xb[bidx];
  float s  = wredsum(x);
  float s2 = wredsum(x*x);
  int wv = t >> 6;
  if ((t & 63) == 0){ sc[wv] = s; sc[4 + wv] = s2; }
  __syncthreads();
  float S  = sc[0]+sc[1]+sc[2]+sc[3];
  float S2 = sc[4]+sc[5]+sc[6]+sc[7];
  float mu  = S * (1.f/256.f);
  float var = S2 * (1.f/256.f) - mu*mu;
  float y = (x - mu) * (1.0f / sqrtf(var + 1e-5f)) * w[t] + bsh[t];
  if (MODE == 3){
    yf[nidx] = y;
  } else {
    yf[bidx] = y;
    yb[bidx] = f2bf(y);
    if (MODE == 1) qkb[bidx] = f2bf(y + qpos[nidx]);
  }
}

// ---------------- fused dense self-attention ----------------
// block = (qtile 32, head, batch); scores in registers, softmax per-wave.
__global__ __launch_bounds__(256)
void self_attn(const u16* __restrict__ q2, const u16* __restrict__ k2,
               const u16* __restrict__ v2, u16* __restrict__ sa_pre){
  __shared__ __align__(16) char smem[65536];
  u16*   Kh = (u16*)smem;                // phase1 [512][34]
  float* Qs = (float*)(smem + 34816);    // phase1 [32][33]
  u16*   P  = (u16*)smem;                // phase2 [32][512]
  u16*   Vh = (u16*)(smem + 32768);      // phase2 [512][32]
  int qt = blockIdx.x, h = blockIdx.y, b = blockIdx.z;
  int t = threadIdx.x, lane = t & 63, wv = t >> 6;
  int n0 = qt * 32;
  for (int i = t; i < 32*32; i += 256){
    int q = i >> 5, d = i & 31;
    Qs[q*33 + d] = bf2f(q2[((long)b*NPQ + n0 + q)*DIM + h*HD + d]);
  }
  for (int i = t; i < 512*32; i += 256){
    int j = i >> 5, d = i & 31;
    Kh[j*34 + d] = k2[((long)b*NPQ + j)*DIM + h*HD + d];
  }
  __syncthreads();
  float S[8][8];
  float sum_[8];
#pragma unroll
  for (int qi = 0; qi < 8; qi++){
    int q = wv*8 + qi;
    float qreg[32];
#pragma unroll
    for (int d = 0; d < 32; d++) qreg[d] = Qs[q*33 + d];
#pragma unroll
    for (int s8 = 0; s8 < 8; s8++){
      int j = lane + 64*s8;
      float acc = 0.f;
#pragma unroll
      for (int d = 0; d < 32; d++) acc += qreg[d] * bf2f(Kh[j*34 + d]);
      S[qi][s8] = acc * SCALE;
    }
    float m = S[qi][0];
#pragma unroll
    for (int s8 = 1; s8 < 8; s8++) m = fmaxf(m, S[qi][s8]);
#pragma unroll
    for (int o = 32; o; o >>= 1) m = fmaxf(m, __shfl_xor(m, o, 64));
    float e = 0.f;
#pragma unroll
    for (int s8 = 0; s8 < 8; s8++){ float ex = expf(S[qi][s8] - m); S[qi][s8] = ex; e += ex; }
    sum_[qi] = wredsum(e);
  }
  __syncthreads();  // Kh / Qs dead
#pragma unroll
  for (int qi = 0; qi < 8; qi++){
    float inv = 1.0f / sum_[qi];
    int q = wv*8 + qi;
#pragma unroll
    for (int s8 = 0; s8 < 8; s8++)
      P[q*512 + lane + 64*s8] = f2bf(S[qi][s8] * inv);
  }
  for (int i = t; i < 512*32; i += 256){
    int j = i >> 5, d = i & 31;
    Vh[j*32 + d] = v2[((long)b*NPQ + j)*DIM + h*HD + d];
  }
  __syncthreads();
  for (int o = t; o < 32*32; o += 256){
    int q = o >> 5, dd = o & 31;
    float acc = 0.f;
    for (int j = 0; j < 512; j++) acc += bf2f(P[q*512 + j]) * bf2f(Vh[j*32 + dd]);
    sa_pre[((long)b*NPQ + n0 + q)*DIM + h*HD + dd] = f2bf(acc);
  }
}

// =====================================================================
extern "C" void kernel_launch(void* const* d_in, const int* in_sizes, int n_in,
                              void* d_out, int out_size, void* d_ws, size_t ws_size,
                              hipStream_t stream){
  (void)in_sizes; (void)n_in; (void)out_size; (void)ws_size;
  const float* tgt  = (const float*)d_in[0];
  const float* mem  = (const float*)d_in[1];
  const float* qpos = (const float*)d_in[2];
  const float* kpos = (const float*)d_in[3];
  const float* cw1  = (const float*)d_in[4];  const float* cb1 = (const float*)d_in[5];
  const float* cw2  = (const float*)d_in[6];  const float* cb2 = (const float*)d_in[7];
  const float* cw3  = (const float*)d_in[8];  const float* cb3 = (const float*)d_in[9];
  const float* saw  = (const float*)d_in[10]; const float* sab = (const float*)d_in[11];
  const float* sow  = (const float*)d_in[12]; const float* sob = (const float*)d_in[13];
  const float* ln1w = (const float*)d_in[14]; const float* ln1b = (const float*)d_in[15];
  const float* ln2w = (const float*)d_in[16]; const float* ln2b = (const float*)d_in[17];
  const float* ln3w = (const float*)d_in[18]; const float* ln3b = (const float*)d_in[19];
  const float* f1w  = (const float*)d_in[20]; const float* f1bs = (const float*)d_in[21];
  const float* f2w  = (const float*)d_in[22]; const float* f2bs = (const float*)d_in[23];

  char* base = (char*)d_ws;
  size_t off = 0;
  auto alloc = [&](size_t bytes) -> char* {
    char* p = base + off;
    off += (bytes + 255) & ~(size_t)255;
    return p;
  };
  // persistent
  u16* cw1b = (u16*)alloc(65536u*2);
  u16* cw2b = (u16*)alloc(65536u*2);
  u16* cw3b = (u16*)alloc(65536u*2);
  u16* sawb = (u16*)alloc(196608u*2);
  u16* sowb = (u16*)alloc(65536u*2);
  u16* f1wb = (u16*)alloc(524288u*2);
  u16* f2wb = (u16*)alloc(524288u*2);
  int* rns  = (int*)alloc(4096u*32*4);
  // region B (staging; dead after launch 8, then overlaid)
  size_t offB = off;
  u16* xnh = (u16*)alloc((size_t)4096*256*2);
  u16* xnl = (u16*)alloc((size_t)4096*256*2);
  u16* mnh = (u16*)alloc((size_t)32768*256*2);
  u16* mnl = (u16*)alloc((size_t)32768*256*2);
  u16* qc  = (u16*)alloc((size_t)4096*256*2);
  u16* kc  = (u16*)alloc((size_t)32768*256*2);
  u16* vc  = (u16*)alloc((size_t)32768*256*2);
  // region C: sim, later overlaid by qh/kh/vh
  float* sim = (float*)alloc((size_t)8*512*4096*4);

  char* regC = (char*)sim;
  u16* qh = (u16*)regC;                          // 4096*256*2  = 2 MB
  u16* kh = (u16*)(regC + 2097152);              // 32768*256*2 = 16 MB
  u16* vh = (u16*)(regC + 2097152 + 16777216);   // 16 MB
  char* regB = base + offB;
  size_t ob = 0;
  auto allocB = [&](size_t bytes) -> char* {
    char* p = regB + ob;
    ob += (bytes + 255) & ~(size_t)255;
    return p;
  };
  float* cross = (float*)allocB((size_t)4096*256*4);
  float* t1    = (float*)allocB((size_t)4096*256*4);
  u16*   t1b   = (u16*)allocB((size_t)4096*256*2);
  u16*   qkb   = (u16*)allocB((size_t)4096*256*2);
  u16*   q2    = (u16*)allocB((size_t)4096*256*2);
  u16*   k2    = (u16*)allocB((size_t)4096*256*2);
  u16*   v2    = (u16*)allocB((size_t)4096*256*2);
  u16*   sa_pre= (u16*)allocB((size_t)4096*256*2);
  float* sa    = (float*)allocB((size_t)4096*256*4);
  float* t2    = (float*)allocB((size_t)4096*256*4);
  u16*   t2b   = (u16*)allocB((size_t)4096*256*2);
  u16*   h1    = (u16*)allocB((size_t)4096*2048*2);
  float* ff    = (float*)allocB((size_t)4096*256*4);

  dim3 blk(256);
  // 1) weights -> bf16
  cvt_bf16<<<dim3(256), blk, 0, stream>>>(cw1, cw1b, 65536);
  cvt_bf16<<<dim3(256), blk, 0, stream>>>(cw2, cw2b, 65536);
  cvt_bf16<<<dim3(256), blk, 0, stream>>>(cw3, cw3b, 65536);
  cvt_bf16<<<dim3(256), blk, 0, stream>>>(saw, sawb, 196608);
  cvt_bf16<<<dim3(256), blk, 0, stream>>>(sow, sowb, 65536);
  cvt_bf16<<<dim3(256), blk, 0, stream>>>(f1w, f1wb, 524288);
  cvt_bf16<<<dim3(256), blk, 0, stream>>>(f2w, f2wb, 524288);
  // 2) activation prep
  prep_tgt<<<dim3(4096), blk, 0, stream>>>(tgt, qpos, xnh, xnl, qc);
  prep_mem<<<dim3(32768), blk, 0, stream>>>(mem, kpos, mnh, mnl, kc, vc);
  // 3) sim = xn @ mn^T (split bf16 ~ fp32 accuracy), batched over 8
  gemm_bt<0,0,1><<<dim3(4,32,8), blk, 0, stream>>>(xnh, xnl, mnh, mnl, nullptr, sim,
      512, 4096, 256, (long)512*256, (long)4096*256, (long)512*4096);
  // 4) exact top-32 per row
  topk_k<<<dim3(4096), blk, 0, stream>>>(sim, rns);
  // 5) q/k/v cross projections (overwrite sim region)
  gemm_bt<1,0,0><<<dim3(32,2,1), blk, 0, stream>>>(qc, nullptr, cw1b, nullptr, cb1, qh,
      4096, 256, 256, 0, 0, 0);
  gemm_bt<1,0,0><<<dim3(256,2,1), blk, 0, stream>>>(kc, nullptr, cw2b, nullptr, cb2, kh,
      32768, 256, 256, 0, 0, 0);
  gemm_bt<1,0,0><<<dim3(256,2,1), blk, 0, stream>>>(vc, nullptr, cw3b, nullptr, cb3, vh,
      32768, 256, 256, 0, 0, 0);
  // 6) sparse cross-attention
  cross_attn<<<dim3(4096), blk, 0, stream>>>(qh, kh, vh, rns, cross);
  // 7) LN1 (+ qk staging)
  ln_k<1><<<dim3(4096), blk, 0, stream>>>(tgt, cross, qpos, ln1w, ln1b, t1, t1b, qkb);
  // 8) self-attn projections
  gemm_bt<1,0,0><<<dim3(32,2,1), blk, 0, stream>>>(qkb, nullptr, sawb, nullptr, sab, q2,
      4096, 256, 256, 0, 0, 0);
  gemm_bt<1,0,0><<<dim3(32,2,1), blk, 0, stream>>>(qkb, nullptr, sawb + 65536, nullptr, sab + 256, k2,
      4096, 256, 256, 0, 0, 0);
  gemm_bt<1,0,0><<<dim3(32,2,1), blk, 0, stream>>>(t1b, nullptr, sawb + 131072, nullptr, sab + 512, v2,
      4096, 256, 256, 0, 0, 0);
  // 9) fused dense self-attention
  self_attn<<<dim3(16,8,8), blk, 0, stream>>>(q2, k2, v2, sa_pre);
  // 10) output projection
  gemm_bt<0,0,0><<<dim3(32,2,1), blk, 0, stream>>>(sa_pre, nullptr, sowb, nullptr, sob, sa,
      4096, 256, 256, 0, 0, 0);
  // 11) LN2
  ln_k<2><<<dim3(4096), blk, 0, stream>>>(t1, sa, nullptr, ln2w, ln2b, t2, t2b, nullptr);
  // 12) FFN
  gemm_bt<1,1,0><<<dim3(32,16,1), blk, 0, stream>>>(t2b, nullptr, f1wb, nullptr, f1bs, h1,
      4096, 2048, 256, 0, 0, 0);
  gemm_bt<0,0,0><<<dim3(32,2,1), blk, 0, stream>>>(h1, nullptr, f2wb, nullptr, f2bs, ff,
      4096, 256, 2048, 0, 0, 0);
  // 13) LN3 -> output (n-major)
  ln_k<3><<<dim3(4096), blk, 0, stream>>>(t2, ff, nullptr, ln3w, ln3b, (float*)d_out, nullptr, nullptr);
}

// Round 2
// 680.743 us; speedup vs baseline: 1.2364x; 1.2364x over previous
//
#include <hip/hip_runtime.h>
#include <math.h>

typedef unsigned short u16;
typedef unsigned int u32;
typedef __bf16 bf16x8 __attribute__((ext_vector_type(8)));
typedef float f32x4 __attribute__((ext_vector_type(4)));

#define NPQ 512
#define MNP 4096
#define BSZ 8
#define DIM 256
#define NH 8
#define HD 32
#define TOPK 32
#define FFD 2048
#define SCALE 0.17677669529663687f  // 1/sqrt(32)

__device__ __forceinline__ u16 f2bf(float f){
  u32 u = __builtin_bit_cast(u32, f);
  u = (u + 0x7FFFu + ((u >> 16) & 1u)) >> 16;
  return (u16)u;
}
__device__ __forceinline__ float bf2f(u16 h){
  u32 u = ((u32)h) << 16;
  return __builtin_bit_cast(float, u);
}
__device__ __forceinline__ float wredsum(float v){
#pragma unroll
  for (int m = 32; m; m >>= 1) v += __shfl_xor(v, m, 64);
  return v;
}
__device__ __forceinline__ float gelu_exact(float x){
  return 0.5f * x * (1.0f + erff(x * 0.70710678118654752f));
}

// ---------------- fp32 -> bf16 convert ----------------
__global__ __launch_bounds__(256)
void cvt_bf16(const float* __restrict__ s, u16* __restrict__ d, int n){
  for (int i = blockIdx.x*256 + threadIdx.x; i < n; i += gridDim.x*256)
    d[i] = f2bf(s[i]);
}

// ---------------- prep: normalize + split + pos-add ----------------
__global__ __launch_bounds__(256)
void prep_tgt(const float* __restrict__ tgt, const float* __restrict__ qpos,
              u16* __restrict__ xnh, u16* __restrict__ xnl, u16* __restrict__ qc){
  __shared__ float sc[4];
  int r = blockIdx.x, t = threadIdx.x;
  int b = r >> 9, n = r & 511;
  long src = ((long)n*BSZ + b)*DIM + t;
  float x = tgt[src];
  float s = wredsum(x*x);
  if ((t & 63) == 0) sc[t >> 6] = s;
  __syncthreads();
  float tot = sc[0]+sc[1]+sc[2]+sc[3];
  float xn = x / sqrtf(tot);
  u16 hi = f2bf(xn);
  long dst = (long)r*DIM + t;
  xnh[dst] = hi;
  xnl[dst] = f2bf(xn - bf2f(hi));
  qc[dst]  = f2bf(x + qpos[src]);
}

__global__ __launch_bounds__(256)
void prep_mem(const float* __restrict__ mem, const float* __restrict__ kpos,
              u16* __restrict__ mnh, u16* __restrict__ mnl,
              u16* __restrict__ kc, u16* __restrict__ vc){
  __shared__ float sc[4];
  int r = blockIdx.x, t = threadIdx.x;
  int b = r >> 12, mp = r & 4095;
  long src = ((long)mp*BSZ + b)*DIM + t;
  float x = mem[src];
  float s = wredsum(x*x);
  if ((t & 63) == 0) sc[t >> 6] = s;
  __syncthreads();
  float tot = sc[0]+sc[1]+sc[2]+sc[3];
  float xn = x / sqrtf(tot);
  u16 hi = f2bf(xn);
  long dst = (long)r*DIM + t;
  mnh[dst] = hi;
  mnl[dst] = f2bf(xn - bf2f(hi));
  kc[dst]  = f2bf(x + kpos[src]);
  vc[dst]  = f2bf(x);
}

// ---------------- MFMA GEMM: C[M,N] = A[M,K] * B[N,K]^T (+bias, act) ----
template<int OUT_BF16, int ACT, int SPLIT>
__global__ __launch_bounds__(256)
void gemm_bt(const u16* __restrict__ A, const u16* __restrict__ A2,
             const u16* __restrict__ B, const u16* __restrict__ B2,
             const float* __restrict__ bias, void* __restrict__ Cv,
             int M, int N, int K, long sA, long sB, long sC){
  int lane = threadIdx.x & 63, wv = threadIdx.x >> 6;
  int ml = lane & 15, quad = lane >> 4;
  int tM = blockIdx.x * 128 + (wv & 1) * 64;
  int tN = blockIdx.y * 128 + (wv >> 1) * 64;
  const u16* Ap  = A + (long)blockIdx.z*sA + (long)(tM + ml)*K + quad*8;
  const u16* Bp  = B + (long)blockIdx.z*sB + (long)(tN + ml)*K + quad*8;
  const u16* Ap2 = Ap; const u16* Bp2 = Bp;
  if (SPLIT){
    Ap2 = A2 + (long)blockIdx.z*sA + (long)(tM + ml)*K + quad*8;
    Bp2 = B2 + (long)blockIdx.z*sB + (long)(tN + ml)*K + quad*8;
  }
  f32x4 acc[4][4];
  f32x4 zer = {0.f, 0.f, 0.f, 0.f};
#pragma unroll
  for (int i = 0; i < 4; i++)
#pragma unroll
    for (int j = 0; j < 4; j++) acc[i][j] = zer;
  long rs = (long)16 * K;
  for (int k0 = 0; k0 < K; k0 += 32){
    bf16x8 a[4], b[4];
#pragma unroll
    for (int i = 0; i < 4; i++) a[i] = *(const bf16x8*)(Ap + i*rs + k0);
#pragma unroll
    for (int j = 0; j < 4; j++) b[j] = *(const bf16x8*)(Bp + j*rs + k0);
#pragma unroll
    for (int i = 0; i < 4; i++)
#pragma unroll
      for (int j = 0; j < 4; j++)
        acc[i][j] = __builtin_amdgcn_mfma_f32_16x16x32_bf16(a[i], b[j], acc[i][j], 0, 0, 0);
    if (SPLIT){
      bf16x8 a2[4], b2[4];
#pragma unroll
      for (int i = 0; i < 4; i++) a2[i] = *(const bf16x8*)(Ap2 + i*rs + k0);
#pragma unroll
      for (int j = 0; j < 4; j++) b2[j] = *(const bf16x8*)(Bp2 + j*rs + k0);
#pragma unroll
      for (int i = 0; i < 4; i++)
#pragma unroll
        for (int j = 0; j < 4; j++){
          acc[i][j] = __builtin_amdgcn_mfma_f32_16x16x32_bf16(a[i],  b2[j], acc[i][j], 0, 0, 0);
          acc[i][j] = __builtin_amdgcn_mfma_f32_16x16x32_bf16(a2[i], b[j],  acc[i][j], 0, 0, 0);
        }
    }
  }
  long zC = (long)blockIdx.z * sC;
#pragma unroll
  for (int j = 0; j < 4; j++){
    int col = tN + j*16 + ml;
    float bv = bias ? bias[col] : 0.0f;
#pragma unroll
    for (int i = 0; i < 4; i++){
#pragma unroll
      for (int r = 0; r < 4; r++){
        int row = tM + i*16 + quad*4 + r;
        float v = acc[i][j][r] + bv;
        if (ACT == 1) v = gelu_exact(v);
        long idx = zC + (long)row * N + col;
        if (OUT_BF16) ((u16*)Cv)[idx] = f2bf(v);
        else ((float*)Cv)[idx] = v;
      }
    }
  }
}

// ---------------- top-k (exact: value desc, index asc tie-break) --------
__global__ __launch_bounds__(256)
void topk_k(const float* __restrict__ sim, int* __restrict__ rns){
  __shared__ float v[4096];
  __shared__ float wr[4];
  __shared__ int   wi[4];
  int r = blockIdx.x, t = threadIdx.x;
  const float* row = sim + (long)r * 4096;
  for (int i = t; i < 4096; i += 256) v[i] = row[i];
  __syncthreads();
  for (int sel = 0; sel < 32; sel++){
    float bv = -3.4e38f; int bi = 0;
    for (int i = t; i < 4096; i += 256){
      float x = v[i];
      if (x > bv){ bv = x; bi = i; }
    }
#pragma unroll
    for (int m = 32; m; m >>= 1){
      float ov = __shfl_xor(bv, m, 64);
      int   oi = __shfl_xor(bi, m, 64);
      if (ov > bv || (ov == bv && oi < bi)){ bv = ov; bi = oi; }
    }
    if ((t & 63) == 0){ wr[t >> 6] = bv; wi[t >> 6] = bi; }
    __syncthreads();
    if (t == 0){
      for (int k = 1; k < 4; k++)
        if (wr[k] > bv || (wr[k] == bv && wi[k] < bi)){ bv = wr[k]; bi = wi[k]; }
      rns[(long)r*32 + sel] = bi;
      v[bi] = -3.4e38f;
    }
    __syncthreads();
  }
}

// ---------------- sparse gathered cross-attention ----------------
#define CAS 270
__global__ __launch_bounds__(256)
void cross_attn(const u16* __restrict__ qh, const u16* __restrict__ kh,
                const u16* __restrict__ vh, const int* __restrict__ rns,
                float* __restrict__ crossO){
  __shared__ u16 Kg[32*CAS];
  __shared__ u16 Vg[32*CAS];
  __shared__ float qv[256];
  __shared__ int idxs[32];
  __shared__ float L[256];
  __shared__ float pm[8], ps[8];
  int r = blockIdx.x, t = threadIdx.x;
  int b = r >> 9;
  if (t < 32) idxs[t] = rns[(long)r*32 + t];
  qv[t] = bf2f(qh[(long)r*DIM + t]);
  __syncthreads();
  for (int i = t; i < 32*DIM; i += 256){
    int k = i >> 8, d = i & 255;
    long src = ((long)b*MNP + idxs[k])*DIM + d;
    Kg[k*CAS + d] = kh[src];
    Vg[k*CAS + d] = vh[src];
  }
  __syncthreads();
  {
    int h = t >> 5, k = t & 31;
    float acc = 0.f;
#pragma unroll
    for (int d = 0; d < 32; d++) acc += qv[h*HD + d] * bf2f(Kg[k*CAS + h*HD + d]);
    L[t] = acc * SCALE;
  }
  __syncthreads();
  if (t < 8){
    float m = L[t*32];
    for (int k = 1; k < 32; k++) m = fmaxf(m, L[t*32 + k]);
    float s = 0.f;
    for (int k = 0; k < 32; k++) s += expf(L[t*32 + k] - m);
    pm[t] = m; ps[t] = s;
  }
  __syncthreads();
  {
    int h = t >> 5, dd = t & 31;
    float m = pm[h], inv = 1.0f/ps[h], acc = 0.f;
#pragma unroll
    for (int k = 0; k < 32; k++) acc += expf(L[h*32 + k] - m) * bf2f(Vg[k*CAS + h*HD + dd]);
    crossO[(long)r*DIM + t] = acc * inv;
  }
}

// ---------------- fused layernorms ----------------
template<int MODE>
__global__ __launch_bounds__(256)
void ln_k(const float* __restrict__ xa, const float* __restrict__ xb,
          const float* __restrict__ qpos,
          const float* __restrict__ w, const float* __restrict__ bsh,
          float* __restrict__ yf, u16* __restrict__ yb, u16* __restrict__ qkb){
  __shared__ float sc[8];
  int r = blockIdx.x, t = threadIdx.x;
  int b = r >> 9, n = r & 511;
  long bidx = (long)r*DIM + t;
  long nidx = ((long)n*BSZ + b)*DIM + t;
  float x = (MODE == 1 ? xa[nidx] : xa[bidx]) + xb[bidx];
  float s  = wredsum(x);
  float s2 = wredsum(x*x);
  int wv = t >> 6;
  if ((t & 63) == 0){ sc[wv] = s; sc[4 + wv] = s2; }
  __syncthreads();
  float S  = sc[0]+sc[1]+sc[2]+sc[3];
  float S2 = sc[4]+sc[5]+sc[6]+sc[7];
  float mu  = S * (1.f/256.f);
  float var = S2 * (1.f/256.f) - mu*mu;
  float y = (x - mu) * (1.0f / sqrtf(var + 1e-5f)) * w[t] + bsh[t];
  if (MODE == 3){
    yf[nidx] = y;
  } else {
    yf[bidx] = y;
    yb[bidx] = f2bf(y);
    if (MODE == 1) qkb[bidx] = f2bf(y + qpos[nidx]);
  }
}

// ---------------- fused dense self-attention (MFMA) ----------------
// block = (qtile of 32, head, batch), 4 waves.
// Phase 1: stage Q[32][40], K[512][40] bf16 in LDS; QK^T via mfma 16x16x32
//   (wave w owns key cols [w*128, w*128+128) for all 32 rows).
// Softmax: in-register; 16-lane butterfly + cross-wave LDS reduce; inv kept
//   in registers (PV C-layout rows are a subset of QK C-layout rows).
// Phase 2 (two 256-key halves, P+Vt overlay dead K buffer):
//   P[32][264] (A-layout), Vt[32][264] (B-layout = V transposed); 4 waves
//   each compute one 16x16 output tile over the half's K=256.
#define KST 40
#define PST 264
__global__ __launch_bounds__(256)
void self_attn(const u16* __restrict__ q2, const u16* __restrict__ k2,
               const u16* __restrict__ v2, u16* __restrict__ sa_pre){
  __shared__ __align__(16) u16 KS[512*KST];   // 40960 B; phase2: P + Vt overlay
  __shared__ __align__(16) u16 QS[32*KST];    // 2560 B
  __shared__ float mbuf[128];
  __shared__ float sbuf[128];
  u16* P  = KS;                // 32*PST*2 = 16896 B
  u16* Vt = KS + 32*PST;       // 16896 B  (offset 16B-aligned)

  int qt = blockIdx.x, h = blockIdx.y, b = blockIdx.z;
  int t = threadIdx.x, lane = t & 63, wv = t >> 6;
  int ml = lane & 15, quad = lane >> 4;
  int n0 = qt * 32;

  // ---- stage Q (32x32) and K (512x32) as bf16, 4-wide ----
  {
    int q = t >> 3, d4 = (t & 7) * 4;
    const u16* src = q2 + ((long)b*NPQ + n0 + q)*DIM + h*HD + d4;
    *(ushort2*)(QS + q*KST + d4)     = *(const ushort2*)(src);
    *(ushort2*)(QS + q*KST + d4 + 2) = *(const ushort2*)(src + 2);
  }
  for (int i = t; i < 512*8; i += 256){
    int j = i >> 3, d4 = (i & 7) * 4;
    const u16* src = k2 + ((long)b*NPQ + j)*DIM + h*HD + d4;
    *(ushort2*)(KS + j*KST + d4)     = *(const ushort2*)(src);
    *(ushort2*)(KS + j*KST + d4 + 2) = *(const ushort2*)(src + 2);
  }
  __syncthreads();

  // ---- QK^T: wave w -> cols [w*128, w*128+128), rows 0..31 ----
  f32x4 acc[2][8];
  {
    bf16x8 aq[2];
#pragma unroll
    for (int mi = 0; mi < 2; mi++)
      aq[mi] = *(const bf16x8*)(QS + (mi*16 + ml)*KST + quad*8);
#pragma unroll
    for (int nj = 0; nj < 8; nj++){
      bf16x8 bk = *(const bf16x8*)(KS + (wv*128 + nj*16 + ml)*KST + quad*8);
      f32x4 z = {0.f,0.f,0.f,0.f};
#pragma unroll
      for (int mi = 0; mi < 2; mi++)
        acc[mi][nj] = __builtin_amdgcn_mfma_f32_16x16x32_bf16(aq[mi], bk,
                        (mi==0||1)?z:z, 0, 0, 0);
      // (separate zero-init per tile)
    }
  }
  // redo properly: accumulate with zero C (the loop above already set acc)
  // scale + row max
  float lmax[2][4];
#pragma unroll
  for (int mi = 0; mi < 2; mi++)
#pragma unroll
    for (int r = 0; r < 4; r++) lmax[mi][r] = -3.4e38f;
#pragma unroll
  for (int mi = 0; mi < 2; mi++)
#pragma unroll
    for (int nj = 0; nj < 8; nj++)
#pragma unroll
      for (int r = 0; r < 4; r++){
        float v = acc[mi][nj][r] * SCALE;
        acc[mi][nj][r] = v;
        lmax[mi][r] = fmaxf(lmax[mi][r], v);
      }
#pragma unroll
  for (int m = 1; m < 16; m <<= 1)
#pragma unroll
    for (int mi = 0; mi < 2; mi++)
#pragma unroll
      for (int r = 0; r < 4; r++)
        lmax[mi][r] = fmaxf(lmax[mi][r], __shfl_xor(lmax[mi][r], m, 64));
  if (ml == 0){
#pragma unroll
    for (int mi = 0; mi < 2; mi++)
#pragma unroll
      for (int r = 0; r < 4; r++)
        mbuf[(mi*16 + quad*4 + r)*4 + wv] = lmax[mi][r];
  }
  __syncthreads();
  float inv_[2][4];
  float lsum[2][4];
#pragma unroll
  for (int mi = 0; mi < 2; mi++)
#pragma unroll
    for (int r = 0; r < 4; r++){
      int row = mi*16 + quad*4 + r;
      float m0 = fmaxf(fmaxf(mbuf[row*4+0], mbuf[row*4+1]),
                       fmaxf(mbuf[row*4+2], mbuf[row*4+3]));
      float s = 0.f;
#pragma unroll
      for (int nj = 0; nj < 8; nj++){
        float e = __expf(acc[mi][nj][r] - m0);
        acc[mi][nj][r] = e;
        s += e;
      }
      lsum[mi][r] = s;
    }
#pragma unroll
  for (int m = 1; m < 16; m <<= 1)
#pragma unroll
    for (int mi = 0; mi < 2; mi++)
#pragma unroll
      for (int r = 0; r < 4; r++)
        lsum[mi][r] += __shfl_xor(lsum[mi][r], m, 64);
  if (ml == 0){
#pragma unroll
    for (int mi = 0; mi < 2; mi++)
#pragma unroll
      for (int r = 0; r < 4; r++)
        sbuf[(mi*16 + quad*4 + r)*4 + wv] = lsum[mi][r];
  }
  __syncthreads();
#pragma unroll
  for (int mi = 0; mi < 2; mi++)
#pragma unroll
    for (int r = 0; r < 4; r++){
      int row = mi*16 + quad*4 + r;
      inv_[mi][r] = 1.0f / (sbuf[row*4+0]+sbuf[row*4+1]+sbuf[row*4+2]+sbuf[row*4+3]);
    }

  // ---- PV over two 256-key halves ----
  int mi2 = wv >> 1, ni = wv & 1;
  f32x4 acc2 = {0.f,0.f,0.f,0.f};
  for (int half = 0; half < 2; half++){
    __syncthreads();   // prior reads of KS region (QK or previous half PV) done
    if ((wv >> 1) == half){
      int cbase = (wv & 1) * 128;
#pragma unroll
      for (int mi = 0; mi < 2; mi++)
#pragma unroll
        for (int nj = 0; nj < 8; nj++)
#pragma unroll
          for (int r = 0; r < 4; r++)
            P[(mi*16 + quad*4 + r)*PST + cbase + nj*16 + ml] = f2bf(acc[mi][nj][r]);
    }
    // stage V^T for this half: Vt[d][j] = v[half*256+j][d]
    for (int i = t; i < 2048; i += 256){
      int j = i >> 3, d4 = (i & 7) * 4;
      const u16* src = v2 + ((long)b*NPQ + half*256 + j)*DIM + h*HD + d4;
      u16 v0 = src[0], v1 = src[1], v2e = src[2], v3 = src[3];
      Vt[(d4+0)*PST + j] = v0;
      Vt[(d4+1)*PST + j] = v1;
      Vt[(d4+2)*PST + j] = v2e;
      Vt[(d4+3)*PST + j] = v3;
    }
    __syncthreads();
#pragma unroll
    for (int k0 = 0; k0 < 256; k0 += 32){
      bf16x8 ap = *(const bf16x8*)(P  + (mi2*16 + ml)*PST + k0 + quad*8);
      bf16x8 bv = *(const bf16x8*)(Vt + (ni*16  + ml)*PST + k0 + quad*8);
      acc2 = __builtin_amdgcn_mfma_f32_16x16x32_bf16(ap, bv, acc2, 0, 0, 0);
    }
  }
  // ---- write out (normalize rows) ----
#pragma unroll
  for (int r = 0; r < 4; r++){
    int row = mi2*16 + quad*4 + r;
    sa_pre[((long)b*NPQ + n0 + row)*DIM + h*HD + ni*16 + ml] =
        f2bf(acc2[r] * inv_[mi2][r]);
  }
}

// =====================================================================
extern "C" void kernel_launch(void* const* d_in, const int* in_sizes, int n_in,
                              void* d_out, int out_size, void* d_ws, size_t ws_size,
                              hipStream_t stream){
  (void)in_sizes; (void)n_in; (void)out_size; (void)ws_size;
  const float* tgt  = (const float*)d_in[0];
  const float* mem  = (const float*)d_in[1];
  const float* qpos = (const float*)d_in[2];
  const float* kpos = (const float*)d_in[3];
  const float* cw1  = (const float*)d_in[4];  const float* cb1 = (const float*)d_in[5];
  const float* cw2  = (const float*)d_in[6];  const float* cb2 = (const float*)d_in[7];
  const float* cw3  = (const float*)d_in[8];  const float* cb3 = (const float*)d_in[9];
  const float* saw  = (const float*)d_in[10]; const float* sab = (const float*)d_in[11];
  const float* sow  = (const float*)d_in[12]; const float* sob = (const float*)d_in[13];
  const float* ln1w = (const float*)d_in[14]; const float* ln1b = (const float*)d_in[15];
  const float* ln2w = (const float*)d_in[16]; const float* ln2b = (const float*)d_in[17];
  const float* ln3w = (const float*)d_in[18]; const float* ln3b = (const float*)d_in[19];
  const float* f1w  = (const float*)d_in[20]; const float* f1bs = (const float*)d_in[21];
  const float* f2w  = (const float*)d_in[22]; const float* f2bs = (const float*)d_in[23];

  char* base = (char*)d_ws;
  size_t off = 0;
  auto alloc = [&](size_t bytes) -> char* {
    char* p = base + off;
    off += (bytes + 255) & ~(size_t)255;
    return p;
  };
  // persistent
  u16* cw1b = (u16*)alloc(65536u*2);
  u16* cw2b = (u16*)alloc(65536u*2);
  u16* cw3b = (u16*)alloc(65536u*2);
  u16* sawb = (u16*)alloc(196608u*2);
  u16* sowb = (u16*)alloc(65536u*2);
  u16* f1wb = (u16*)alloc(524288u*2);
  u16* f2wb = (u16*)alloc(524288u*2);
  int* rns  = (int*)alloc(4096u*32*4);
  // region B (staging; dead after cross projections, then overlaid)
  size_t offB = off;
  u16* xnh = (u16*)alloc((size_t)4096*256*2);
  u16* xnl = (u16*)alloc((size_t)4096*256*2);
  u16* mnh = (u16*)alloc((size_t)32768*256*2);
  u16* mnl = (u16*)alloc((size_t)32768*256*2);
  u16* qc  = (u16*)alloc((size_t)4096*256*2);
  u16* kc  = (u16*)alloc((size_t)32768*256*2);
  u16* vc  = (u16*)alloc((size_t)32768*256*2);
  // region C: sim, later overlaid by qh/kh/vh
  float* sim = (float*)alloc((size_t)8*512*4096*4);

  char* regC = (char*)sim;
  u16* qh = (u16*)regC;
  u16* kh = (u16*)(regC + 2097152);
  u16* vh = (u16*)(regC + 2097152 + 16777216);
  char* regB = base + offB;
  size_t ob = 0;
  auto allocB = [&](size_t bytes) -> char* {
    char* p = regB + ob;
    ob += (bytes + 255) & ~(size_t)255;
    return p;
  };
  float* cross = (float*)allocB((size_t)4096*256*4);
  float* t1    = (float*)allocB((size_t)4096*256*4);
  u16*   t1b   = (u16*)allocB((size_t)4096*256*2);
  u16*   qkb   = (u16*)allocB((size_t)4096*256*2);
  u16*   q2    = (u16*)allocB((size_t)4096*256*2);
  u16*   k2    = (u16*)allocB((size_t)4096*256*2);
  u16*   v2    = (u16*)allocB((size_t)4096*256*2);
  u16*   sa_pre= (u16*)allocB((size_t)4096*256*2);
  float* sa    = (float*)allocB((size_t)4096*256*4);
  float* t2    = (float*)allocB((size_t)4096*256*4);
  u16*   t2b   = (u16*)allocB((size_t)4096*256*2);
  u16*   h1    = (u16*)allocB((size_t)4096*2048*2);
  float* ff    = (float*)allocB((size_t)4096*256*4);

  dim3 blk(256);
  cvt_bf16<<<dim3(256), blk, 0, stream>>>(cw1, cw1b, 65536);
  cvt_bf16<<<dim3(256), blk, 0, stream>>>(cw2, cw2b, 65536);
  cvt_bf16<<<dim3(256), blk, 0, stream>>>(cw3, cw3b, 65536);
  cvt_bf16<<<dim3(256), blk, 0, stream>>>(saw, sawb, 196608);
  cvt_bf16<<<dim3(256), blk, 0, stream>>>(sow, sowb, 65536);
  cvt_bf16<<<dim3(256), blk, 0, stream>>>(f1w, f1wb, 524288);
  cvt_bf16<<<dim3(256), blk, 0, stream>>>(f2w, f2wb, 524288);
  prep_tgt<<<dim3(4096), blk, 0, stream>>>(tgt, qpos, xnh, xnl, qc);
  prep_mem<<<dim3(32768), blk, 0, stream>>>(mem, kpos, mnh, mnl, kc, vc);
  gemm_bt<0,0,1><<<dim3(4,32,8), blk, 0, stream>>>(xnh, xnl, mnh, mnl, nullptr, sim,
      512, 4096, 256, (long)512*256, (long)4096*256, (long)512*4096);
  topk_k<<<dim3(4096), blk, 0, stream>>>(sim, rns);
  gemm_bt<1,0,0><<<dim3(32,2,1), blk, 0, stream>>>(qc, nullptr, cw1b, nullptr, cb1, qh,
      4096, 256, 256, 0, 0, 0);
  gemm_bt<1,0,0><<<dim3(256,2,1), blk, 0, stream>>>(kc, nullptr, cw2b, nullptr, cb2, kh,
      32768, 256, 256, 0, 0, 0);
  gemm_bt<1,0,0><<<dim3(256,2,1), blk, 0, stream>>>(vc, nullptr, cw3b, nullptr, cb3, vh,
      32768, 256, 256, 0, 0, 0);
  cross_attn<<<dim3(4096), blk, 0, stream>>>(qh, kh, vh, rns, cross);
  ln_k<1><<<dim3(4096), blk, 0, stream>>>(tgt, cross, qpos, ln1w, ln1b, t1, t1b, qkb);
  gemm_bt<1,0,0><<<dim3(32,2,1), blk, 0, stream>>>(qkb, nullptr, sawb, nullptr, sab, q2,
      4096, 256, 256, 0, 0, 0);
  gemm_bt<1,0,0><<<dim3(32,2,1), blk, 0, stream>>>(qkb, nullptr, sawb + 65536, nullptr, sab + 256, k2,
      4096, 256, 256, 0, 0, 0);
  gemm_bt<1,0,0><<<dim3(32,2,1), blk, 0, stream>>>(t1b, nullptr, sawb + 131072, nullptr, sab + 512, v2,
      4096, 256, 256, 0, 0, 0);
  self_attn<<<dim3(16,8,8), blk, 0, stream>>>(q2, k2, v2, sa_pre);
  gemm_bt<0,0,0><<<dim3(32,2,1), blk, 0, stream>>>(sa_pre, nullptr, sowb, nullptr, sob, sa,
      4096, 256, 256, 0, 0, 0);
  ln_k<2><<<dim3(4096), blk, 0, stream>>>(t1, sa, nullptr, ln2w, ln2b, t2, t2b, nullptr);
  gemm_bt<1,1,0><<<dim3(32,16,1), blk, 0, stream>>>(t2b, nullptr, f1wb, nullptr, f1bs, h1,
      4096, 2048, 256, 0, 0, 0);
  gemm_bt<0,0,0><<<dim3(32,2,1), blk, 0, stream>>>(h1, nullptr, f2wb, nullptr, f2bs, ff,
      4096, 256, 2048, 0, 0, 0);
  ln_k<3><<<dim3(4096), blk, 0, stream>>>(t2, ff, nullptr, ln3w, ln3b, (float*)d_out, nullptr, nullptr);
}

// Round 3
// 629.233 us; speedup vs baseline: 1.3376x; 1.0819x over previous
//
#include <hip/hip_runtime.h>
#include <math.h>

typedef unsigned short u16;
typedef unsigned int u32;
typedef __bf16 bf16x8 __attribute__((ext_vector_type(8)));
typedef float f32x4 __attribute__((ext_vector_type(4)));

#define NPQ 512
#define MNP 4096
#define BSZ 8
#define DIM 256
#define NH 8
#define HD 32
#define TOPK 32
#define FFD 2048
#define SCALE 0.17677669529663687f  // 1/sqrt(32)

__device__ __forceinline__ u16 f2bf(float f){
  u32 u = __builtin_bit_cast(u32, f);
  u = (u + 0x7FFFu + ((u >> 16) & 1u)) >> 16;
  return (u16)u;
}
__device__ __forceinline__ float bf2f(u16 h){
  u32 u = ((u32)h) << 16;
  return __builtin_bit_cast(float, u);
}
__device__ __forceinline__ float wredsum(float v){
#pragma unroll
  for (int m = 32; m; m >>= 1) v += __shfl_xor(v, m, 64);
  return v;
}
__device__ __forceinline__ float gelu_exact(float x){
  return 0.5f * x * (1.0f + erff(x * 0.70710678118654752f));
}

// ---------------- fp32 -> bf16 convert ----------------
__global__ __launch_bounds__(256)
void cvt_bf16(const float* __restrict__ s, u16* __restrict__ d, int n){
  for (int i = blockIdx.x*256 + threadIdx.x; i < n; i += gridDim.x*256)
    d[i] = f2bf(s[i]);
}

// ---------------- prep: normalize + split + pos-add ----------------
__global__ __launch_bounds__(256)
void prep_tgt(const float* __restrict__ tgt, const float* __restrict__ qpos,
              u16* __restrict__ xnh, u16* __restrict__ xnl, u16* __restrict__ qc){
  __shared__ float sc[4];
  int r = blockIdx.x, t = threadIdx.x;
  int b = r >> 9, n = r & 511;
  long src = ((long)n*BSZ + b)*DIM + t;
  float x = tgt[src];
  float s = wredsum(x*x);
  if ((t & 63) == 0) sc[t >> 6] = s;
  __syncthreads();
  float tot = sc[0]+sc[1]+sc[2]+sc[3];
  float xn = x / sqrtf(tot);
  u16 hi = f2bf(xn);
  long dst = (long)r*DIM + t;
  xnh[dst] = hi;
  xnl[dst] = f2bf(xn - bf2f(hi));
  qc[dst]  = f2bf(x + qpos[src]);
}

__global__ __launch_bounds__(256)
void prep_mem(const float* __restrict__ mem, const float* __restrict__ kpos,
              u16* __restrict__ mnh, u16* __restrict__ mnl,
              u16* __restrict__ kc, u16* __restrict__ vc){
  __shared__ float sc[4];
  int r = blockIdx.x, t = threadIdx.x;
  int b = r >> 12, mp = r & 4095;
  long src = ((long)mp*BSZ + b)*DIM + t;
  float x = mem[src];
  float s = wredsum(x*x);
  if ((t & 63) == 0) sc[t >> 6] = s;
  __syncthreads();
  float tot = sc[0]+sc[1]+sc[2]+sc[3];
  float xn = x / sqrtf(tot);
  u16 hi = f2bf(xn);
  long dst = (long)r*DIM + t;
  mnh[dst] = hi;
  mnl[dst] = f2bf(xn - bf2f(hi));
  kc[dst]  = f2bf(x + kpos[src]);
  vc[dst]  = f2bf(x);
}

// ---------------- MFMA GEMM: C[M,N] = A[M,K] * B[N,K]^T (+bias, act) ----
template<int OUT_BF16, int ACT, int SPLIT>
__global__ __launch_bounds__(256)
void gemm_bt(const u16* __restrict__ A, const u16* __restrict__ A2,
             const u16* __restrict__ B, const u16* __restrict__ B2,
             const float* __restrict__ bias, void* __restrict__ Cv,
             int M, int N, int K, long sA, long sB, long sC){
  int lane = threadIdx.x & 63, wv = threadIdx.x >> 6;
  int ml = lane & 15, quad = lane >> 4;
  int tM = blockIdx.x * 128 + (wv & 1) * 64;
  int tN = blockIdx.y * 128 + (wv >> 1) * 64;
  const u16* Ap  = A + (long)blockIdx.z*sA + (long)(tM + ml)*K + quad*8;
  const u16* Bp  = B + (long)blockIdx.z*sB + (long)(tN + ml)*K + quad*8;
  const u16* Ap2 = Ap; const u16* Bp2 = Bp;
  if (SPLIT){
    Ap2 = A2 + (long)blockIdx.z*sA + (long)(tM + ml)*K + quad*8;
    Bp2 = B2 + (long)blockIdx.z*sB + (long)(tN + ml)*K + quad*8;
  }
  f32x4 acc[4][4];
  f32x4 zer = {0.f, 0.f, 0.f, 0.f};
#pragma unroll
  for (int i = 0; i < 4; i++)
#pragma unroll
    for (int j = 0; j < 4; j++) acc[i][j] = zer;
  long rs = (long)16 * K;
  for (int k0 = 0; k0 < K; k0 += 32){
    bf16x8 a[4], b[4];
#pragma unroll
    for (int i = 0; i < 4; i++) a[i] = *(const bf16x8*)(Ap + i*rs + k0);
#pragma unroll
    for (int j = 0; j < 4; j++) b[j] = *(const bf16x8*)(Bp + j*rs + k0);
#pragma unroll
    for (int i = 0; i < 4; i++)
#pragma unroll
      for (int j = 0; j < 4; j++)
        acc[i][j] = __builtin_amdgcn_mfma_f32_16x16x32_bf16(a[i], b[j], acc[i][j], 0, 0, 0);
    if (SPLIT){
      bf16x8 a2[4], b2[4];
#pragma unroll
      for (int i = 0; i < 4; i++) a2[i] = *(const bf16x8*)(Ap2 + i*rs + k0);
#pragma unroll
      for (int j = 0; j < 4; j++) b2[j] = *(const bf16x8*)(Bp2 + j*rs + k0);
#pragma unroll
      for (int i = 0; i < 4; i++)
#pragma unroll
        for (int j = 0; j < 4; j++){
          acc[i][j] = __builtin_amdgcn_mfma_f32_16x16x32_bf16(a[i],  b2[j], acc[i][j], 0, 0, 0);
          acc[i][j] = __builtin_amdgcn_mfma_f32_16x16x32_bf16(a2[i], b[j],  acc[i][j], 0, 0, 0);
        }
    }
  }
  long zC = (long)blockIdx.z * sC;
#pragma unroll
  for (int j = 0; j < 4; j++){
    int col = tN + j*16 + ml;
    float bv = bias ? bias[col] : 0.0f;
#pragma unroll
    for (int i = 0; i < 4; i++){
#pragma unroll
      for (int r = 0; r < 4; r++){
        int row = tM + i*16 + quad*4 + r;
        float v = acc[i][j][r] + bv;
        if (ACT == 1) v = gelu_exact(v);
        long idx = zC + (long)row * N + col;
        if (OUT_BF16) ((u16*)Cv)[idx] = f2bf(v);
        else ((float*)Cv)[idx] = v;
      }
    }
  }
}

// ---------------- top-k via exact radix select ----------------
// Only the SET of top-32 indices matters downstream (mask scatter).
// jax.lax.top_k tie semantics: ties broken by smaller index.
__global__ __launch_bounds__(256)
void topk_k(const float* __restrict__ sim, int* __restrict__ rns){
  __shared__ int hist[256];
  __shared__ int scal[2];
  __shared__ int ties[512];
  __shared__ int tcnt, ocnt;
  int r = blockIdx.x, t = threadIdx.x;
  const float* row = sim + (long)r * 4096;
  u32 key[16];
#pragma unroll
  for (int i = 0; i < 16; i++){
    u32 u = __builtin_bit_cast(u32, row[i*256 + t]);
    key[i] = u ^ (((u32)((int)u >> 31)) | 0x80000000u);
  }
  int k_rem = 32;
  u32 prefix = 0, pmask = 0;
  for (int lvl = 0; lvl < 4; lvl++){
    int shift = 24 - 8*lvl;
    hist[t] = 0;
    __syncthreads();
#pragma unroll
    for (int i = 0; i < 16; i++){
      if ((key[i] & pmask) == prefix)
        atomicAdd(&hist[(key[i] >> shift) & 0xFF], 1);
    }
    __syncthreads();
    if (t == 0){
      int cum = 0, b = 255;
      for (; b > 0; b--){
        cum += hist[b];
        if (cum >= k_rem) break;
      }
      if (cum < k_rem) cum += (b == 0 ? hist[0] : 0);  // b==0 fallthrough
      scal[0] = b;
      scal[1] = k_rem - (cum - hist[b]);
    }
    __syncthreads();
    int b = scal[0];
    k_rem = scal[1];
    prefix |= ((u32)b) << shift;
    pmask |= (0xFFu << shift);
    __syncthreads();
  }
  // prefix == exact key of the 32nd-largest value
  if (t == 0){ tcnt = 0; ocnt = 0; }
  __syncthreads();
  int* out = rns + (long)r * 32;
#pragma unroll
  for (int i = 0; i < 16; i++){
    if (key[i] > prefix){
      int p = atomicAdd(&ocnt, 1);
      out[p] = i*256 + t;
    } else if (key[i] == prefix){
      int p = atomicAdd(&tcnt, 1);
      if (p < 512) ties[p] = i*256 + t;
    }
  }
  __syncthreads();
  if (t == 0){
    int need = k_rem;
    int n = tcnt < 512 ? tcnt : 512;
    for (int s = 0; s < need; s++){
      int mb = 0;
      for (int j = 1; j < n; j++) if (ties[j] < ties[mb]) mb = j;
      out[ocnt + s] = ties[mb];
      ties[mb] = 0x7FFFFFFF;
    }
  }
}

// ---------------- sparse gathered cross-attention ----------------
#define CAS 270
__global__ __launch_bounds__(256)
void cross_attn(const u16* __restrict__ qh, const u16* __restrict__ kh,
                const u16* __restrict__ vh, const int* __restrict__ rns,
                float* __restrict__ crossO){
  __shared__ u16 Kg[32*CAS];
  __shared__ u16 Vg[32*CAS];
  __shared__ float qv[256];
  __shared__ int idxs[32];
  __shared__ float L[256];
  __shared__ float pm[8], ps[8];
  int r = blockIdx.x, t = threadIdx.x;
  int b = r >> 9;
  if (t < 32) idxs[t] = rns[(long)r*32 + t];
  qv[t] = bf2f(qh[(long)r*DIM + t]);
  __syncthreads();
  for (int i = t; i < 32*DIM; i += 256){
    int k = i >> 8, d = i & 255;
    long src = ((long)b*MNP + idxs[k])*DIM + d;
    Kg[k*CAS + d] = kh[src];
    Vg[k*CAS + d] = vh[src];
  }
  __syncthreads();
  {
    int h = t >> 5, k = t & 31;
    float acc = 0.f;
#pragma unroll
    for (int d = 0; d < 32; d++) acc += qv[h*HD + d] * bf2f(Kg[k*CAS + h*HD + d]);
    L[t] = acc * SCALE;
  }
  __syncthreads();
  if (t < 8){
    float m = L[t*32];
    for (int k = 1; k < 32; k++) m = fmaxf(m, L[t*32 + k]);
    float s = 0.f;
    for (int k = 0; k < 32; k++) s += expf(L[t*32 + k] - m);
    pm[t] = m; ps[t] = s;
  }
  __syncthreads();
  {
    int h = t >> 5, dd = t & 31;
    float m = pm[h], inv = 1.0f/ps[h], acc = 0.f;
#pragma unroll
    for (int k = 0; k < 32; k++) acc += expf(L[h*32 + k] - m) * bf2f(Vg[k*CAS + h*HD + dd]);
    crossO[(long)r*DIM + t] = acc * inv;
  }
}

// ---------------- fused layernorms ----------------
template<int MODE>
__global__ __launch_bounds__(256)
void ln_k(const float* __restrict__ xa, const float* __restrict__ xb,
          const float* __restrict__ qpos,
          const float* __restrict__ w, const float* __restrict__ bsh,
          float* __restrict__ yf, u16* __restrict__ yb, u16* __restrict__ qkb){
  __shared__ float sc[8];
  int r = blockIdx.x, t = threadIdx.x;
  int b = r >> 9, n = r & 511;
  long bidx = (long)r*DIM + t;
  long nidx = ((long)n*BSZ + b)*DIM + t;
  float x = (MODE == 1 ? xa[nidx] : xa[bidx]) + xb[bidx];
  float s  = wredsum(x);
  float s2 = wredsum(x*x);
  int wv = t >> 6;
  if ((t & 63) == 0){ sc[wv] = s; sc[4 + wv] = s2; }
  __syncthreads();
  float S  = sc[0]+sc[1]+sc[2]+sc[3];
  float S2 = sc[4]+sc[5]+sc[6]+sc[7];
  float mu  = S * (1.f/256.f);
  float var = S2 * (1.f/256.f) - mu*mu;
  float y = (x - mu) * (1.0f / sqrtf(var + 1e-5f)) * w[t] + bsh[t];
  if (MODE == 3){
    yf[nidx] = y;
  } else {
    yf[bidx] = y;
    yb[bidx] = f2bf(y);
    if (MODE == 1) qkb[bidx] = f2bf(y + qpos[nidx]);
  }
}

// ---------------- fused dense self-attention (MFMA) ----------------
#define KST 40
#define PST 264
__global__ __launch_bounds__(256)
void self_attn(const u16* __restrict__ q2, const u16* __restrict__ k2,
               const u16* __restrict__ v2, u16* __restrict__ sa_pre){
  __shared__ __align__(16) u16 KS[512*KST];
  __shared__ __align__(16) u16 QS[32*KST];
  __shared__ float mbuf[128];
  __shared__ float sbuf[128];
  u16* P  = KS;
  u16* Vt = KS + 32*PST;

  int qt = blockIdx.x, h = blockIdx.y, b = blockIdx.z;
  int t = threadIdx.x, lane = t & 63, wv = t >> 6;
  int ml = lane & 15, quad = lane >> 4;
  int n0 = qt * 32;

  {
    int q = t >> 3, d4 = (t & 7) * 4;
    const u16* src = q2 + ((long)b*NPQ + n0 + q)*DIM + h*HD + d4;
    *(ushort2*)(QS + q*KST + d4)     = *(const ushort2*)(src);
    *(ushort2*)(QS + q*KST + d4 + 2) = *(const ushort2*)(src + 2);
  }
  for (int i = t; i < 512*8; i += 256){
    int j = i >> 3, d4 = (i & 7) * 4;
    const u16* src = k2 + ((long)b*NPQ + j)*DIM + h*HD + d4;
    *(ushort2*)(KS + j*KST + d4)     = *(const ushort2*)(src);
    *(ushort2*)(KS + j*KST + d4 + 2) = *(const ushort2*)(src + 2);
  }
  __syncthreads();

  f32x4 acc[2][8];
  {
    bf16x8 aq[2];
#pragma unroll
    for (int mi = 0; mi < 2; mi++)
      aq[mi] = *(const bf16x8*)(QS + (mi*16 + ml)*KST + quad*8);
#pragma unroll
    for (int nj = 0; nj < 8; nj++){
      bf16x8 bk = *(const bf16x8*)(KS + (wv*128 + nj*16 + ml)*KST + quad*8);
      f32x4 z = {0.f,0.f,0.f,0.f};
#pragma unroll
      for (int mi = 0; mi < 2; mi++)
        acc[mi][nj] = __builtin_amdgcn_mfma_f32_16x16x32_bf16(aq[mi], bk, z, 0, 0, 0);
    }
  }
  float lmax[2][4];
#pragma unroll
  for (int mi = 0; mi < 2; mi++)
#pragma unroll
    for (int r = 0; r < 4; r++) lmax[mi][r] = -3.4e38f;
#pragma unroll
  for (int mi = 0; mi < 2; mi++)
#pragma unroll
    for (int nj = 0; nj < 8; nj++)
#pragma unroll
      for (int r = 0; r < 4; r++){
        float v = acc[mi][nj][r] * SCALE;
        acc[mi][nj][r] = v;
        lmax[mi][r] = fmaxf(lmax[mi][r], v);
      }
#pragma unroll
  for (int m = 1; m < 16; m <<= 1)
#pragma unroll
    for (int mi = 0; mi < 2; mi++)
#pragma unroll
      for (int r = 0; r < 4; r++)
        lmax[mi][r] = fmaxf(lmax[mi][r], __shfl_xor(lmax[mi][r], m, 64));
  if (ml == 0){
#pragma unroll
    for (int mi = 0; mi < 2; mi++)
#pragma unroll
      for (int r = 0; r < 4; r++)
        mbuf[(mi*16 + quad*4 + r)*4 + wv] = lmax[mi][r];
  }
  __syncthreads();
  float inv_[2][4];
  float lsum[2][4];
#pragma unroll
  for (int mi = 0; mi < 2; mi++)
#pragma unroll
    for (int r = 0; r < 4; r++){
      int row = mi*16 + quad*4 + r;
      float m0 = fmaxf(fmaxf(mbuf[row*4+0], mbuf[row*4+1]),
                       fmaxf(mbuf[row*4+2], mbuf[row*4+3]));
      float s = 0.f;
#pragma unroll
      for (int nj = 0; nj < 8; nj++){
        float e = __expf(acc[mi][nj][r] - m0);
        acc[mi][nj][r] = e;
        s += e;
      }
      lsum[mi][r] = s;
    }
#pragma unroll
  for (int m = 1; m < 16; m <<= 1)
#pragma unroll
    for (int mi = 0; mi < 2; mi++)
#pragma unroll
      for (int r = 0; r < 4; r++)
        lsum[mi][r] += __shfl_xor(lsum[mi][r], m, 64);
  if (ml == 0){
#pragma unroll
    for (int mi = 0; mi < 2; mi++)
#pragma unroll
      for (int r = 0; r < 4; r++)
        sbuf[(mi*16 + quad*4 + r)*4 + wv] = lsum[mi][r];
  }
  __syncthreads();
#pragma unroll
  for (int mi = 0; mi < 2; mi++)
#pragma unroll
    for (int r = 0; r < 4; r++){
      int row = mi*16 + quad*4 + r;
      inv_[mi][r] = 1.0f / (sbuf[row*4+0]+sbuf[row*4+1]+sbuf[row*4+2]+sbuf[row*4+3]);
    }

  int mi2 = wv >> 1, ni = wv & 1;
  f32x4 acc2 = {0.f,0.f,0.f,0.f};
  for (int half = 0; half < 2; half++){
    __syncthreads();
    if ((wv >> 1) == half){
      int cbase = (wv & 1) * 128;
#pragma unroll
      for (int mi = 0; mi < 2; mi++)
#pragma unroll
        for (int nj = 0; nj < 8; nj++)
#pragma unroll
          for (int r = 0; r < 4; r++)
            P[(mi*16 + quad*4 + r)*PST + cbase + nj*16 + ml] = f2bf(acc[mi][nj][r]);
    }
    for (int i = t; i < 2048; i += 256){
      int j = i >> 3, d4 = (i & 7) * 4;
      const u16* src = v2 + ((long)b*NPQ + half*256 + j)*DIM + h*HD + d4;
      u16 v0 = src[0], v1 = src[1], v2e = src[2], v3 = src[3];
      Vt[(d4+0)*PST + j] = v0;
      Vt[(d4+1)*PST + j] = v1;
      Vt[(d4+2)*PST + j] = v2e;
      Vt[(d4+3)*PST + j] = v3;
    }
    __syncthreads();
#pragma unroll
    for (int k0 = 0; k0 < 256; k0 += 32){
      bf16x8 ap = *(const bf16x8*)(P  + (mi2*16 + ml)*PST + k0 + quad*8);
      bf16x8 bv = *(const bf16x8*)(Vt + (ni*16  + ml)*PST + k0 + quad*8);
      acc2 = __builtin_amdgcn_mfma_f32_16x16x32_bf16(ap, bv, acc2, 0, 0, 0);
    }
  }
#pragma unroll
  for (int r = 0; r < 4; r++){
    int row = mi2*16 + quad*4 + r;
    sa_pre[((long)b*NPQ + n0 + row)*DIM + h*HD + ni*16 + ml] =
        f2bf(acc2[r] * inv_[mi2][r]);
  }
}

// =====================================================================
extern "C" void kernel_launch(void* const* d_in, const int* in_sizes, int n_in,
                              void* d_out, int out_size, void* d_ws, size_t ws_size,
                              hipStream_t stream){
  (void)in_sizes; (void)n_in; (void)out_size; (void)ws_size;
  const float* tgt  = (const float*)d_in[0];
  const float* mem  = (const float*)d_in[1];
  const float* qpos = (const float*)d_in[2];
  const float* kpos = (const float*)d_in[3];
  const float* cw1  = (const float*)d_in[4];  const float* cb1 = (const float*)d_in[5];
  const float* cw2  = (const float*)d_in[6];  const float* cb2 = (const float*)d_in[7];
  const float* cw3  = (const float*)d_in[8];  const float* cb3 = (const float*)d_in[9];
  const float* saw  = (const float*)d_in[10]; const float* sab = (const float*)d_in[11];
  const float* sow  = (const float*)d_in[12]; const float* sob = (const float*)d_in[13];
  const float* ln1w = (const float*)d_in[14]; const float* ln1b = (const float*)d_in[15];
  const float* ln2w = (const float*)d_in[16]; const float* ln2b = (const float*)d_in[17];
  const float* ln3w = (const float*)d_in[18]; const float* ln3b = (const float*)d_in[19];
  const float* f1w  = (const float*)d_in[20]; const float* f1bs = (const float*)d_in[21];
  const float* f2w  = (const float*)d_in[22]; const float* f2bs = (const float*)d_in[23];

  char* base = (char*)d_ws;
  size_t off = 0;
  auto alloc = [&](size_t bytes) -> char* {
    char* p = base + off;
    off += (bytes + 255) & ~(size_t)255;
    return p;
  };
  u16* cw1b = (u16*)alloc(65536u*2);
  u16* cw2b = (u16*)alloc(65536u*2);
  u16* cw3b = (u16*)alloc(65536u*2);
  u16* sawb = (u16*)alloc(196608u*2);
  u16* sowb = (u16*)alloc(65536u*2);
  u16* f1wb = (u16*)alloc(524288u*2);
  u16* f2wb = (u16*)alloc(524288u*2);
  int* rns  = (int*)alloc(4096u*32*4);
  size_t offB = off;
  u16* xnh = (u16*)alloc((size_t)4096*256*2);
  u16* xnl = (u16*)alloc((size_t)4096*256*2);
  u16* mnh = (u16*)alloc((size_t)32768*256*2);
  u16* mnl = (u16*)alloc((size_t)32768*256*2);
  u16* qc  = (u16*)alloc((size_t)4096*256*2);
  u16* kc  = (u16*)alloc((size_t)32768*256*2);
  u16* vc  = (u16*)alloc((size_t)32768*256*2);
  float* sim = (float*)alloc((size_t)8*512*4096*4);

  char* regC = (char*)sim;
  u16* qh = (u16*)regC;
  u16* kh = (u16*)(regC + 2097152);
  u16* vh = (u16*)(regC + 2097152 + 16777216);
  char* regB = base + offB;
  size_t ob = 0;
  auto allocB = [&](size_t bytes) -> char* {
    char* p = regB + ob;
    ob += (bytes + 255) & ~(size_t)255;
    return p;
  };
  float* cross = (float*)allocB((size_t)4096*256*4);
  float* t1    = (float*)allocB((size_t)4096*256*4);
  u16*   t1b   = (u16*)allocB((size_t)4096*256*2);
  u16*   qkb   = (u16*)allocB((size_t)4096*256*2);
  u16*   q2    = (u16*)allocB((size_t)4096*256*2);
  u16*   k2    = (u16*)allocB((size_t)4096*256*2);
  u16*   v2    = (u16*)allocB((size_t)4096*256*2);
  u16*   sa_pre= (u16*)allocB((size_t)4096*256*2);
  float* sa    = (float*)allocB((size_t)4096*256*4);
  float* t2    = (float*)allocB((size_t)4096*256*4);
  u16*   t2b   = (u16*)allocB((size_t)4096*256*2);
  u16*   h1    = (u16*)allocB((size_t)4096*2048*2);
  float* ff    = (float*)allocB((size_t)4096*256*4);

  dim3 blk(256);
  cvt_bf16<<<dim3(256), blk, 0, stream>>>(cw1, cw1b, 65536);
  cvt_bf16<<<dim3(256), blk, 0, stream>>>(cw2, cw2b, 65536);
  cvt_bf16<<<dim3(256), blk, 0, stream>>>(cw3, cw3b, 65536);
  cvt_bf16<<<dim3(256), blk, 0, stream>>>(saw, sawb, 196608);
  cvt_bf16<<<dim3(256), blk, 0, stream>>>(sow, sowb, 65536);
  cvt_bf16<<<dim3(256), blk, 0, stream>>>(f1w, f1wb, 524288);
  cvt_bf16<<<dim3(256), blk, 0, stream>>>(f2w, f2wb, 524288);
  prep_tgt<<<dim3(4096), blk, 0, stream>>>(tgt, qpos, xnh, xnl, qc);
  prep_mem<<<dim3(32768), blk, 0, stream>>>(mem, kpos, mnh, mnl, kc, vc);
  gemm_bt<0,0,1><<<dim3(4,32,8), blk, 0, stream>>>(xnh, xnl, mnh, mnl, nullptr, sim,
      512, 4096, 256, (long)512*256, (long)4096*256, (long)512*4096);
  topk_k<<<dim3(4096), blk, 0, stream>>>(sim, rns);
  gemm_bt<1,0,0><<<dim3(32,2,1), blk, 0, stream>>>(qc, nullptr, cw1b, nullptr, cb1, qh,
      4096, 256, 256, 0, 0, 0);
  gemm_bt<1,0,0><<<dim3(256,2,1), blk, 0, stream>>>(kc, nullptr, cw2b, nullptr, cb2, kh,
      32768, 256, 256, 0, 0, 0);
  gemm_bt<1,0,0><<<dim3(256,2,1), blk, 0, stream>>>(vc, nullptr, cw3b, nullptr, cb3, vh,
      32768, 256, 256, 0, 0, 0);
  cross_attn<<<dim3(4096), blk, 0, stream>>>(qh, kh, vh, rns, cross);
  ln_k<1><<<dim3(4096), blk, 0, stream>>>(tgt, cross, qpos, ln1w, ln1b, t1, t1b, qkb);
  gemm_bt<1,0,0><<<dim3(32,2,1), blk, 0, stream>>>(qkb, nullptr, sawb, nullptr, sab, q2,
      4096, 256, 256, 0, 0, 0);
  gemm_bt<1,0,0><<<dim3(32,2,1), blk, 0, stream>>>(qkb, nullptr, sawb + 65536, nullptr, sab + 256, k2,
      4096, 256, 256, 0, 0, 0);
  gemm_bt<1,0,0><<<dim3(32,2,1), blk, 0, stream>>>(t1b, nullptr, sawb + 131072, nullptr, sab + 512, v2,
      4096, 256, 256, 0, 0, 0);
  self_attn<<<dim3(16,8,8), blk, 0, stream>>>(q2, k2, v2, sa_pre);
  gemm_bt<0,0,0><<<dim3(32,2,1), blk, 0, stream>>>(sa_pre, nullptr, sowb, nullptr, sob, sa,
      4096, 256, 256, 0, 0, 0);
  ln_k<2><<<dim3(4096), blk, 0, stream>>>(t1, sa, nullptr, ln2w, ln2b, t2, t2b, nullptr);
  gemm_bt<1,1,0><<<dim3(32,16,1), blk, 0, stream>>>(t2b, nullptr, f1wb, nullptr, f1bs, h1,
      4096, 2048, 256, 0, 0, 0);
  gemm_bt<0,0,0><<<dim3(32,2,1), blk, 0, stream>>>(h1, nullptr, f2wb, nullptr, f2bs, ff,
      4096, 256, 2048, 0, 0, 0);
  ln_k<3><<<dim3(4096), blk, 0, stream>>>(t2, ff, nullptr, ln3w, ln3b, (float*)d_out, nullptr, nullptr);
}

// Round 4
// 624.857 us; speedup vs baseline: 1.3470x; 1.0070x over previous
//
#include <hip/hip_runtime.h>
#include <math.h>

typedef unsigned short u16;
typedef unsigned int u32;
typedef __bf16 bf16x8 __attribute__((ext_vector_type(8)));
typedef float f32x4 __attribute__((ext_vector_type(4)));

#define NPQ 512
#define MNP 4096
#define BSZ 8
#define DIM 256
#define NH 8
#define HD 32
#define TOPK 32
#define FFD 2048
#define SCALE 0.17677669529663687f  // 1/sqrt(32)

__device__ __forceinline__ u16 f2bf(float f){
  u32 u = __builtin_bit_cast(u32, f);
  u = (u + 0x7FFFu + ((u >> 16) & 1u)) >> 16;
  return (u16)u;
}
__device__ __forceinline__ float bf2f(u16 h){
  u32 u = ((u32)h) << 16;
  return __builtin_bit_cast(float, u);
}
__device__ __forceinline__ float wredsum(float v){
#pragma unroll
  for (int m = 32; m; m >>= 1) v += __shfl_xor(v, m, 64);
  return v;
}
__device__ __forceinline__ int wredsumi(int v){
#pragma unroll
  for (int m = 32; m; m >>= 1) v += __shfl_xor(v, m, 64);
  return v;
}
__device__ __forceinline__ float gelu_exact(float x){
  return 0.5f * x * (1.0f + erff(x * 0.70710678118654752f));
}

// ---------------- fp32 -> bf16 convert ----------------
__global__ __launch_bounds__(256)
void cvt_bf16(const float* __restrict__ s, u16* __restrict__ d, int n){
  for (int i = blockIdx.x*256 + threadIdx.x; i < n; i += gridDim.x*256)
    d[i] = f2bf(s[i]);
}

// ---------------- prep: normalize + split + pos-add ----------------
__global__ __launch_bounds__(256)
void prep_tgt(const float* __restrict__ tgt, const float* __restrict__ qpos,
              u16* __restrict__ xnh, u16* __restrict__ xnl, u16* __restrict__ qc){
  __shared__ float sc[4];
  int r = blockIdx.x, t = threadIdx.x;
  int b = r >> 9, n = r & 511;
  long src = ((long)n*BSZ + b)*DIM + t;
  float x = tgt[src];
  float s = wredsum(x*x);
  if ((t & 63) == 0) sc[t >> 6] = s;
  __syncthreads();
  float tot = sc[0]+sc[1]+sc[2]+sc[3];
  float xn = x / sqrtf(tot);
  u16 hi = f2bf(xn);
  long dst = (long)r*DIM + t;
  xnh[dst] = hi;
  xnl[dst] = f2bf(xn - bf2f(hi));
  qc[dst]  = f2bf(x + qpos[src]);
}

__global__ __launch_bounds__(256)
void prep_mem(const float* __restrict__ mem, const float* __restrict__ kpos,
              u16* __restrict__ mnh, u16* __restrict__ mnl,
              u16* __restrict__ kc, u16* __restrict__ vc){
  __shared__ float sc[4];
  int r = blockIdx.x, t = threadIdx.x;
  int b = r >> 12, mp = r & 4095;
  long src = ((long)mp*BSZ + b)*DIM + t;
  float x = mem[src];
  float s = wredsum(x*x);
  if ((t & 63) == 0) sc[t >> 6] = s;
  __syncthreads();
  float tot = sc[0]+sc[1]+sc[2]+sc[3];
  float xn = x / sqrtf(tot);
  u16 hi = f2bf(xn);
  long dst = (long)r*DIM + t;
  mnh[dst] = hi;
  mnl[dst] = f2bf(xn - bf2f(hi));
  kc[dst]  = f2bf(x + kpos[src]);
  vc[dst]  = f2bf(x);
}

// ---------------- MFMA GEMM: C[M,N] = A[M,K] * B[N,K]^T (+bias, act) ----
template<int OUT_BF16, int ACT, int SPLIT>
__global__ __launch_bounds__(256)
void gemm_bt(const u16* __restrict__ A, const u16* __restrict__ A2,
             const u16* __restrict__ B, const u16* __restrict__ B2,
             const float* __restrict__ bias, void* __restrict__ Cv,
             int M, int N, int K, long sA, long sB, long sC){
  int lane = threadIdx.x & 63, wv = threadIdx.x >> 6;
  int ml = lane & 15, quad = lane >> 4;
  int tM = blockIdx.x * 128 + (wv & 1) * 64;
  int tN = blockIdx.y * 128 + (wv >> 1) * 64;
  const u16* Ap  = A + (long)blockIdx.z*sA + (long)(tM + ml)*K + quad*8;
  const u16* Bp  = B + (long)blockIdx.z*sB + (long)(tN + ml)*K + quad*8;
  const u16* Ap2 = Ap; const u16* Bp2 = Bp;
  if (SPLIT){
    Ap2 = A2 + (long)blockIdx.z*sA + (long)(tM + ml)*K + quad*8;
    Bp2 = B2 + (long)blockIdx.z*sB + (long)(tN + ml)*K + quad*8;
  }
  f32x4 acc[4][4];
  f32x4 zer = {0.f, 0.f, 0.f, 0.f};
#pragma unroll
  for (int i = 0; i < 4; i++)
#pragma unroll
    for (int j = 0; j < 4; j++) acc[i][j] = zer;
  long rs = (long)16 * K;
  for (int k0 = 0; k0 < K; k0 += 32){
    bf16x8 a[4], b[4];
#pragma unroll
    for (int i = 0; i < 4; i++) a[i] = *(const bf16x8*)(Ap + i*rs + k0);
#pragma unroll
    for (int j = 0; j < 4; j++) b[j] = *(const bf16x8*)(Bp + j*rs + k0);
#pragma unroll
    for (int i = 0; i < 4; i++)
#pragma unroll
      for (int j = 0; j < 4; j++)
        acc[i][j] = __builtin_amdgcn_mfma_f32_16x16x32_bf16(a[i], b[j], acc[i][j], 0, 0, 0);
    if (SPLIT){
      bf16x8 a2[4], b2[4];
#pragma unroll
      for (int i = 0; i < 4; i++) a2[i] = *(const bf16x8*)(Ap2 + i*rs + k0);
#pragma unroll
      for (int j = 0; j < 4; j++) b2[j] = *(const bf16x8*)(Bp2 + j*rs + k0);
#pragma unroll
      for (int i = 0; i < 4; i++)
#pragma unroll
        for (int j = 0; j < 4; j++){
          acc[i][j] = __builtin_amdgcn_mfma_f32_16x16x32_bf16(a[i],  b2[j], acc[i][j], 0, 0, 0);
          acc[i][j] = __builtin_amdgcn_mfma_f32_16x16x32_bf16(a2[i], b[j],  acc[i][j], 0, 0, 0);
        }
    }
  }
  long zC = (long)blockIdx.z * sC;
#pragma unroll
  for (int j = 0; j < 4; j++){
    int col = tN + j*16 + ml;
    float bv = bias ? bias[col] : 0.0f;
#pragma unroll
    for (int i = 0; i < 4; i++){
#pragma unroll
      for (int r = 0; r < 4; r++){
        int row = tM + i*16 + quad*4 + r;
        float v = acc[i][j][r] + bv;
        if (ACT == 1) v = gelu_exact(v);
        long idx = zC + (long)row * N + col;
        if (OUT_BF16) ((u16*)Cv)[idx] = f2bf(v);
        else ((float*)Cv)[idx] = v;
      }
    }
  }
}

// ---------------- top-k via atomic-free bit-descent select ----------------
// Only the SET of top-32 indices matters downstream (mask scatter).
// jax.lax.top_k tie semantics: ties broken by smaller index.
__global__ __launch_bounds__(256)
void topk_k(const float* __restrict__ sim, int* __restrict__ rns){
  __shared__ int red[2][4];
  __shared__ int ties[64];
  __shared__ int tcnt, ocnt;
  int r = blockIdx.x, t = threadIdx.x;
  int lane = t & 63, wv = t >> 6;
  const float* row = sim + (long)r * 4096;
  u32 key[16];
#pragma unroll
  for (int i = 0; i < 16; i++){
    u32 u = __builtin_bit_cast(u32, row[i*256 + t]);
    key[i] = u ^ (((u32)((int)u >> 31)) | 0x80000000u);
  }
  if (t == 0){ tcnt = 0; ocnt = 0; }
  // binary descent: pref ends as the exact 32nd-largest key
  u32 pref = 0;
  for (int bit = 31; bit >= 0; bit--){
    u32 cand = pref | (1u << bit);
    int c = 0;
#pragma unroll
    for (int i = 0; i < 16; i++) c += (key[i] >= cand) ? 1 : 0;
    c = wredsumi(c);
    int p = bit & 1;
    if (lane == 0) red[p][wv] = c;
    __syncthreads();
    int tot = red[p][0] + red[p][1] + red[p][2] + red[p][3];
    if (tot >= TOPK) pref = cand;
  }
  // count strictly greater (for tie budget)
  int cg = 0;
#pragma unroll
  for (int i = 0; i < 16; i++) cg += (key[i] > pref) ? 1 : 0;
  cg = wredsumi(cg);
  if (lane == 0) red[0][wv] = cg;
  __syncthreads();
  int ngt = red[0][0] + red[0][1] + red[0][2] + red[0][3];
  int k_rem = TOPK - ngt;   // #ties at pref to take (smallest indices)
  int* out = rns + (long)r * 32;
#pragma unroll
  for (int i = 0; i < 16; i++){
    if (key[i] > pref){
      int p = atomicAdd(&ocnt, 1);
      out[p] = i*256 + t;
    } else if (key[i] == pref){
      int p = atomicAdd(&tcnt, 1);
      if (p < 64) ties[p] = i*256 + t;
    }
  }
  __syncthreads();
  if (t == 0){
    int n = tcnt < 64 ? tcnt : 64;
    for (int s = 0; s < k_rem; s++){
      int mb = 0;
      for (int j = 1; j < n; j++) if (ties[j] < ties[mb]) mb = j;
      out[ngt + s] = ties[mb];
      ties[mb] = 0x7FFFFFFF;
    }
  }
}

// ---------------- sparse gathered cross-attention ----------------
#define CAS 270
__global__ __launch_bounds__(256)
void cross_attn(const u16* __restrict__ qh, const u16* __restrict__ kh,
                const u16* __restrict__ vh, const int* __restrict__ rns,
                float* __restrict__ crossO){
  __shared__ u16 Kg[32*CAS];
  __shared__ u16 Vg[32*CAS];
  __shared__ float qv[256];
  __shared__ int idxs[32];
  __shared__ float L[256];
  __shared__ float pm[8], ps[8];
  int r = blockIdx.x, t = threadIdx.x;
  int b = r >> 9;
  if (t < 32) idxs[t] = rns[(long)r*32 + t];
  qv[t] = bf2f(qh[(long)r*DIM + t]);
  __syncthreads();
  for (int i = t; i < 32*DIM; i += 256){
    int k = i >> 8, d = i & 255;
    long src = ((long)b*MNP + idxs[k])*DIM + d;
    Kg[k*CAS + d] = kh[src];
    Vg[k*CAS + d] = vh[src];
  }
  __syncthreads();
  {
    int h = t >> 5, k = t & 31;
    float acc = 0.f;
#pragma unroll
    for (int d = 0; d < 32; d++) acc += qv[h*HD + d] * bf2f(Kg[k*CAS + h*HD + d]);
    L[t] = acc * SCALE;
  }
  __syncthreads();
  if (t < 8){
    float m = L[t*32];
    for (int k = 1; k < 32; k++) m = fmaxf(m, L[t*32 + k]);
    float s = 0.f;
    for (int k = 0; k < 32; k++) s += expf(L[t*32 + k] - m);
    pm[t] = m; ps[t] = s;
  }
  __syncthreads();
  {
    int h = t >> 5, dd = t & 31;
    float m = pm[h], inv = 1.0f/ps[h], acc = 0.f;
#pragma unroll
    for (int k = 0; k < 32; k++) acc += expf(L[h*32 + k] - m) * bf2f(Vg[k*CAS + h*HD + dd]);
    crossO[(long)r*DIM + t] = acc * inv;
  }
}

// ---------------- fused layernorms ----------------
template<int MODE>
__global__ __launch_bounds__(256)
void ln_k(const float* __restrict__ xa, const float* __restrict__ xb,
          const float* __restrict__ qpos,
          const float* __restrict__ w, const float* __restrict__ bsh,
          float* __restrict__ yf, u16* __restrict__ yb, u16* __restrict__ qkb){
  __shared__ float sc[8];
  int r = blockIdx.x, t = threadIdx.x;
  int b = r >> 9, n = r & 511;
  long bidx = (long)r*DIM + t;
  long nidx = ((long)n*BSZ + b)*DIM + t;
  float x = (MODE == 1 ? xa[nidx] : xa[bidx]) + xb[bidx];
  float s  = wredsum(x);
  float s2 = wredsum(x*x);
  int wv = t >> 6;
  if ((t & 63) == 0){ sc[wv] = s; sc[4 + wv] = s2; }
  __syncthreads();
  float S  = sc[0]+sc[1]+sc[2]+sc[3];
  float S2 = sc[4]+sc[5]+sc[6]+sc[7];
  float mu  = S * (1.f/256.f);
  float var = S2 * (1.f/256.f) - mu*mu;
  float y = (x - mu) * (1.0f / sqrtf(var + 1e-5f)) * w[t] + bsh[t];
  if (MODE == 3){
    yf[nidx] = y;
  } else {
    yf[bidx] = y;
    yb[bidx] = f2bf(y);
    if (MODE == 1) qkb[bidx] = f2bf(y + qpos[nidx]);
  }
}

// ---------------- fused dense self-attention (MFMA) ----------------
#define KST 40
#define PST 264
__global__ __launch_bounds__(256)
void self_attn(const u16* __restrict__ q2, const u16* __restrict__ k2,
               const u16* __restrict__ v2, u16* __restrict__ sa_pre){
  __shared__ __align__(16) u16 KS[512*KST];
  __shared__ __align__(16) u16 QS[32*KST];
  __shared__ float mbuf[128];
  __shared__ float sbuf[128];
  u16* P  = KS;
  u16* Vt = KS + 32*PST;

  int qt = blockIdx.x, h = blockIdx.y, b = blockIdx.z;
  int t = threadIdx.x, lane = t & 63, wv = t >> 6;
  int ml = lane & 15, quad = lane >> 4;
  int n0 = qt * 32;

  {
    int q = t >> 3, d4 = (t & 7) * 4;
    const u16* src = q2 + ((long)b*NPQ + n0 + q)*DIM + h*HD + d4;
    *(ushort2*)(QS + q*KST + d4)     = *(const ushort2*)(src);
    *(ushort2*)(QS + q*KST + d4 + 2) = *(const ushort2*)(src + 2);
  }
  for (int i = t; i < 512*8; i += 256){
    int j = i >> 3, d4 = (i & 7) * 4;
    const u16* src = k2 + ((long)b*NPQ + j)*DIM + h*HD + d4;
    *(ushort2*)(KS + j*KST + d4)     = *(const ushort2*)(src);
    *(ushort2*)(KS + j*KST + d4 + 2) = *(const ushort2*)(src + 2);
  }
  __syncthreads();

  f32x4 acc[2][8];
  {
    bf16x8 aq[2];
#pragma unroll
    for (int mi = 0; mi < 2; mi++)
      aq[mi] = *(const bf16x8*)(QS + (mi*16 + ml)*KST + quad*8);
#pragma unroll
    for (int nj = 0; nj < 8; nj++){
      bf16x8 bk = *(const bf16x8*)(KS + (wv*128 + nj*16 + ml)*KST + quad*8);
      f32x4 z = {0.f,0.f,0.f,0.f};
#pragma unroll
      for (int mi = 0; mi < 2; mi++)
        acc[mi][nj] = __builtin_amdgcn_mfma_f32_16x16x32_bf16(aq[mi], bk, z, 0, 0, 0);
    }
  }
  float lmax[2][4];
#pragma unroll
  for (int mi = 0; mi < 2; mi++)
#pragma unroll
    for (int r = 0; r < 4; r++) lmax[mi][r] = -3.4e38f;
#pragma unroll
  for (int mi = 0; mi < 2; mi++)
#pragma unroll
    for (int nj = 0; nj < 8; nj++)
#pragma unroll
      for (int r = 0; r < 4; r++){
        float v = acc[mi][nj][r] * SCALE;
        acc[mi][nj][r] = v;
        lmax[mi][r] = fmaxf(lmax[mi][r], v);
      }
#pragma unroll
  for (int m = 1; m < 16; m <<= 1)
#pragma unroll
    for (int mi = 0; mi < 2; mi++)
#pragma unroll
      for (int r = 0; r < 4; r++)
        lmax[mi][r] = fmaxf(lmax[mi][r], __shfl_xor(lmax[mi][r], m, 64));
  if (ml == 0){
#pragma unroll
    for (int mi = 0; mi < 2; mi++)
#pragma unroll
      for (int r = 0; r < 4; r++)
        mbuf[(mi*16 + quad*4 + r)*4 + wv] = lmax[mi][r];
  }
  __syncthreads();
  float inv_[2][4];
  float lsum[2][4];
#pragma unroll
  for (int mi = 0; mi < 2; mi++)
#pragma unroll
    for (int r = 0; r < 4; r++){
      int row = mi*16 + quad*4 + r;
      float m0 = fmaxf(fmaxf(mbuf[row*4+0], mbuf[row*4+1]),
                       fmaxf(mbuf[row*4+2], mbuf[row*4+3]));
      float s = 0.f;
#pragma unroll
      for (int nj = 0; nj < 8; nj++){
        float e = __expf(acc[mi][nj][r] - m0);
        acc[mi][nj][r] = e;
        s += e;
      }
      lsum[mi][r] = s;
    }
#pragma unroll
  for (int m = 1; m < 16; m <<= 1)
#pragma unroll
    for (int mi = 0; mi < 2; mi++)
#pragma unroll
      for (int r = 0; r < 4; r++)
        lsum[mi][r] += __shfl_xor(lsum[mi][r], m, 64);
  if (ml == 0){
#pragma unroll
    for (int mi = 0; mi < 2; mi++)
#pragma unroll
      for (int r = 0; r < 4; r++)
        sbuf[(mi*16 + quad*4 + r)*4 + wv] = lsum[mi][r];
  }
  __syncthreads();
#pragma unroll
  for (int mi = 0; mi < 2; mi++)
#pragma unroll
    for (int r = 0; r < 4; r++){
      int row = mi*16 + quad*4 + r;
      inv_[mi][r] = 1.0f / (sbuf[row*4+0]+sbuf[row*4+1]+sbuf[row*4+2]+sbuf[row*4+3]);
    }

  int mi2 = wv >> 1, ni = wv & 1;
  f32x4 acc2 = {0.f,0.f,0.f,0.f};
  for (int half = 0; half < 2; half++){
    __syncthreads();
    if ((wv >> 1) == half){
      int cbase = (wv & 1) * 128;
#pragma unroll
      for (int mi = 0; mi < 2; mi++)
#pragma unroll
        for (int nj = 0; nj < 8; nj++)
#pragma unroll
          for (int r = 0; r < 4; r++)
            P[(mi*16 + quad*4 + r)*PST + cbase + nj*16 + ml] = f2bf(acc[mi][nj][r]);
    }
    for (int i = t; i < 2048; i += 256){
      int j = i >> 3, d4 = (i & 7) * 4;
      const u16* src = v2 + ((long)b*NPQ + half*256 + j)*DIM + h*HD + d4;
      u16 v0 = src[0], v1 = src[1], v2e = src[2], v3 = src[3];
      Vt[(d4+0)*PST + j] = v0;
      Vt[(d4+1)*PST + j] = v1;
      Vt[(d4+2)*PST + j] = v2e;
      Vt[(d4+3)*PST + j] = v3;
    }
    __syncthreads();
#pragma unroll
    for (int k0 = 0; k0 < 256; k0 += 32){
      bf16x8 ap = *(const bf16x8*)(P  + (mi2*16 + ml)*PST + k0 + quad*8);
      bf16x8 bv = *(const bf16x8*)(Vt + (ni*16  + ml)*PST + k0 + quad*8);
      acc2 = __builtin_amdgcn_mfma_f32_16x16x32_bf16(ap, bv, acc2, 0, 0, 0);
    }
  }
#pragma unroll
  for (int r = 0; r < 4; r++){
    int row = mi2*16 + quad*4 + r;
    sa_pre[((long)b*NPQ + n0 + row)*DIM + h*HD + ni*16 + ml] =
        f2bf(acc2[r] * inv_[mi2][r]);
  }
}

// =====================================================================
extern "C" void kernel_launch(void* const* d_in, const int* in_sizes, int n_in,
                              void* d_out, int out_size, void* d_ws, size_t ws_size,
                              hipStream_t stream){
  (void)in_sizes; (void)n_in; (void)out_size; (void)ws_size;
  const float* tgt  = (const float*)d_in[0];
  const float* mem  = (const float*)d_in[1];
  const float* qpos = (const float*)d_in[2];
  const float* kpos = (const float*)d_in[3];
  const float* cw1  = (const float*)d_in[4];  const float* cb1 = (const float*)d_in[5];
  const float* cw2  = (const float*)d_in[6];  const float* cb2 = (const float*)d_in[7];
  const float* cw3  = (const float*)d_in[8];  const float* cb3 = (const float*)d_in[9];
  const float* saw  = (const float*)d_in[10]; const float* sab = (const float*)d_in[11];
  const float* sow  = (const float*)d_in[12]; const float* sob = (const float*)d_in[13];
  const float* ln1w = (const float*)d_in[14]; const float* ln1b = (const float*)d_in[15];
  const float* ln2w = (const float*)d_in[16]; const float* ln2b = (const float*)d_in[17];
  const float* ln3w = (const float*)d_in[18]; const float* ln3b = (const float*)d_in[19];
  const float* f1w  = (const float*)d_in[20]; const float* f1bs = (const float*)d_in[21];
  const float* f2w  = (const float*)d_in[22]; const float* f2bs = (const float*)d_in[23];

  char* base = (char*)d_ws;
  size_t off = 0;
  auto alloc = [&](size_t bytes) -> char* {
    char* p = base + off;
    off += (bytes + 255) & ~(size_t)255;
    return p;
  };
  u16* cw1b = (u16*)alloc(65536u*2);
  u16* cw2b = (u16*)alloc(65536u*2);
  u16* cw3b = (u16*)alloc(65536u*2);
  u16* sawb = (u16*)alloc(196608u*2);
  u16* sowb = (u16*)alloc(65536u*2);
  u16* f1wb = (u16*)alloc(524288u*2);
  u16* f2wb = (u16*)alloc(524288u*2);
  int* rns  = (int*)alloc(4096u*32*4);
  size_t offB = off;
  u16* xnh = (u16*)alloc((size_t)4096*256*2);
  u16* xnl = (u16*)alloc((size_t)4096*256*2);
  u16* mnh = (u16*)alloc((size_t)32768*256*2);
  u16* mnl = (u16*)alloc((size_t)32768*256*2);
  u16* qc  = (u16*)alloc((size_t)4096*256*2);
  u16* kc  = (u16*)alloc((size_t)32768*256*2);
  u16* vc  = (u16*)alloc((size_t)32768*256*2);
  float* sim = (float*)alloc((size_t)8*512*4096*4);

  char* regC = (char*)sim;
  u16* qh = (u16*)regC;
  u16* kh = (u16*)(regC + 2097152);
  u16* vh = (u16*)(regC + 2097152 + 16777216);
  char* regB = base + offB;
  size_t ob = 0;
  auto allocB = [&](size_t bytes) -> char* {
    char* p = regB + ob;
    ob += (bytes + 255) & ~(size_t)255;
    return p;
  };
  float* cross = (float*)allocB((size_t)4096*256*4);
  float* t1    = (float*)allocB((size_t)4096*256*4);
  u16*   t1b   = (u16*)allocB((size_t)4096*256*2);
  u16*   qkb   = (u16*)allocB((size_t)4096*256*2);
  u16*   q2    = (u16*)allocB((size_t)4096*256*2);
  u16*   k2    = (u16*)allocB((size_t)4096*256*2);
  u16*   v2    = (u16*)allocB((size_t)4096*256*2);
  u16*   sa_pre= (u16*)allocB((size_t)4096*256*2);
  float* sa    = (float*)allocB((size_t)4096*256*4);
  float* t2    = (float*)allocB((size_t)4096*256*4);
  u16*   t2b   = (u16*)allocB((size_t)4096*256*2);
  u16*   h1    = (u16*)allocB((size_t)4096*2048*2);
  float* ff    = (float*)allocB((size_t)4096*256*4);

  dim3 blk(256);
  cvt_bf16<<<dim3(256), blk, 0, stream>>>(cw1, cw1b, 65536);
  cvt_bf16<<<dim3(256), blk, 0, stream>>>(cw2, cw2b, 65536);
  cvt_bf16<<<dim3(256), blk, 0, stream>>>(cw3, cw3b, 65536);
  cvt_bf16<<<dim3(256), blk, 0, stream>>>(saw, sawb, 196608);
  cvt_bf16<<<dim3(256), blk, 0, stream>>>(sow, sowb, 65536);
  cvt_bf16<<<dim3(256), blk, 0, stream>>>(f1w, f1wb, 524288);
  cvt_bf16<<<dim3(256), blk, 0, stream>>>(f2w, f2wb, 524288);
  prep_tgt<<<dim3(4096), blk, 0, stream>>>(tgt, qpos, xnh, xnl, qc);
  prep_mem<<<dim3(32768), blk, 0, stream>>>(mem, kpos, mnh, mnl, kc, vc);
  gemm_bt<0,0,1><<<dim3(4,32,8), blk, 0, stream>>>(xnh, xnl, mnh, mnl, nullptr, sim,
      512, 4096, 256, (long)512*256, (long)4096*256, (long)512*4096);
  topk_k<<<dim3(4096), blk, 0, stream>>>(sim, rns);
  gemm_bt<1,0,0><<<dim3(32,2,1), blk, 0, stream>>>(qc, nullptr, cw1b, nullptr, cb1, qh,
      4096, 256, 256, 0, 0, 0);
  gemm_bt<1,0,0><<<dim3(256,2,1), blk, 0, stream>>>(kc, nullptr, cw2b, nullptr, cb2, kh,
      32768, 256, 256, 0, 0, 0);
  gemm_bt<1,0,0><<<dim3(256,2,1), blk, 0, stream>>>(vc, nullptr, cw3b, nullptr, cb3, vh,
      32768, 256, 256, 0, 0, 0);
  cross_attn<<<dim3(4096), blk, 0, stream>>>(qh, kh, vh, rns, cross);
  ln_k<1><<<dim3(4096), blk, 0, stream>>>(tgt, cross, qpos, ln1w, ln1b, t1, t1b, qkb);
  gemm_bt<1,0,0><<<dim3(32,2,1), blk, 0, stream>>>(qkb, nullptr, sawb, nullptr, sab, q2,
      4096, 256, 256, 0, 0, 0);
  gemm_bt<1,0,0><<<dim3(32,2,1), blk, 0, stream>>>(qkb, nullptr, sawb + 65536, nullptr, sab + 256, k2,
      4096, 256, 256, 0, 0, 0);
  gemm_bt<1,0,0><<<dim3(32,2,1), blk, 0, stream>>>(t1b, nullptr, sawb + 131072, nullptr, sab + 512, v2,
      4096, 256, 256, 0, 0, 0);
  self_attn<<<dim3(16,8,8), blk, 0, stream>>>(q2, k2, v2, sa_pre);
  gemm_bt<0,0,0><<<dim3(32,2,1), blk, 0, stream>>>(sa_pre, nullptr, sowb, nullptr, sob, sa,
      4096, 256, 256, 0, 0, 0);
  ln_k<2><<<dim3(4096), blk, 0, stream>>>(t1, sa, nullptr, ln2w, ln2b, t2, t2b, nullptr);
  gemm_bt<1,1,0><<<dim3(32,16,1), blk, 0, stream>>>(t2b, nullptr, f1wb, nullptr, f1bs, h1,
      4096, 2048, 256, 0, 0, 0);
  gemm_bt<0,0,0><<<dim3(32,2,1), blk, 0, stream>>>(h1, nullptr, f2wb, nullptr, f2bs, ff,
      4096, 256, 2048, 0, 0, 0);
  ln_k<3><<<dim3(4096), blk, 0, stream>>>(t2, ff, nullptr, ln3w, ln3b, (float*)d_out, nullptr, nullptr);
}

// Round 5
// 554.430 us; speedup vs baseline: 1.5181x; 1.1270x over previous
//
#include <hip/hip_runtime.h>
#include <math.h>

typedef unsigned short u16;
typedef unsigned int u32;
typedef __bf16 bf16x8 __attribute__((ext_vector_type(8)));
typedef float f32x4 __attribute__((ext_vector_type(4)));

#define NPQ 512
#define MNP 4096
#define BSZ 8
#define DIM 256
#define NH 8
#define HD 32
#define TOPK 32
#define FFD 2048
#define SCALE 0.17677669529663687f  // 1/sqrt(32)

__device__ __forceinline__ u16 f2bf(float f){
  u32 u = __builtin_bit_cast(u32, f);
  u = (u + 0x7FFFu + ((u >> 16) & 1u)) >> 16;
  return (u16)u;
}
__device__ __forceinline__ float bf2f(u16 h){
  u32 u = ((u32)h) << 16;
  return __builtin_bit_cast(float, u);
}
__device__ __forceinline__ float wredsum(float v){
#pragma unroll
  for (int m = 32; m; m >>= 1) v += __shfl_xor(v, m, 64);
  return v;
}
__device__ __forceinline__ int wredsumi(int v){
#pragma unroll
  for (int m = 32; m; m >>= 1) v += __shfl_xor(v, m, 64);
  return v;
}
__device__ __forceinline__ float gelu_exact(float x){
  return 0.5f * x * (1.0f + erff(x * 0.70710678118654752f));
}

// ---------------- fp32 -> bf16 convert, all weights in one launch --------
// dst = base of contiguous bf16 arena (cw1b..f2wb, offsets in elements).
__global__ __launch_bounds__(256)
void cvt_all(const float* __restrict__ s0, const float* __restrict__ s1,
             const float* __restrict__ s2, const float* __restrict__ s3,
             const float* __restrict__ s4, const float* __restrict__ s5,
             const float* __restrict__ s6, u16* __restrict__ dst){
  int i = blockIdx.x*256 + threadIdx.x;
  if (i >= 1507328) return;
  const float* s; int base;
  if      (i <  65536){ s = s0; base = 0; }
  else if (i < 131072){ s = s1; base = 65536; }
  else if (i < 196608){ s = s2; base = 131072; }
  else if (i < 393216){ s = s3; base = 196608; }
  else if (i < 458752){ s = s4; base = 393216; }
  else if (i < 983040){ s = s5; base = 458752; }
  else                { s = s6; base = 983040; }
  dst[i] = f2bf(s[i - base]);
}

// ---------------- prep: normalize + split + pos-add ----------------
__global__ __launch_bounds__(256)
void prep_tgt(const float* __restrict__ tgt, const float* __restrict__ qpos,
              u16* __restrict__ xnh, u16* __restrict__ xnl, u16* __restrict__ qc){
  __shared__ float sc[4];
  int r = blockIdx.x, t = threadIdx.x;
  int b = r >> 9, n = r & 511;
  long src = ((long)n*BSZ + b)*DIM + t;
  float x = tgt[src];
  float s = wredsum(x*x);
  if ((t & 63) == 0) sc[t >> 6] = s;
  __syncthreads();
  float tot = sc[0]+sc[1]+sc[2]+sc[3];
  float xn = x / sqrtf(tot);
  u16 hi = f2bf(xn);
  long dst = (long)r*DIM + t;
  xnh[dst] = hi;
  xnl[dst] = f2bf(xn - bf2f(hi));
  qc[dst]  = f2bf(x + qpos[src]);
}

__global__ __launch_bounds__(256)
void prep_mem(const float* __restrict__ mem, const float* __restrict__ kpos,
              u16* __restrict__ mnh, u16* __restrict__ mnl,
              u16* __restrict__ kc, u16* __restrict__ vc){
  __shared__ float sc[4];
  int r = blockIdx.x, t = threadIdx.x;
  int b = r >> 12, mp = r & 4095;
  long src = ((long)mp*BSZ + b)*DIM + t;
  float x = mem[src];
  float s = wredsum(x*x);
  if ((t & 63) == 0) sc[t >> 6] = s;
  __syncthreads();
  float tot = sc[0]+sc[1]+sc[2]+sc[3];
  float xn = x / sqrtf(tot);
  u16 hi = f2bf(xn);
  long dst = (long)r*DIM + t;
  mnh[dst] = hi;
  mnl[dst] = f2bf(xn - bf2f(hi));
  kc[dst]  = f2bf(x + kpos[src]);
  vc[dst]  = f2bf(x);
}

// ---------------- sim GEMM (split bf16, LDS-staged B) ----------------
// C[b][512][4096] = (Ah+Al)(Bh+Bl)^T dropping Al*Bl.
// grid (4, 32, 8); per block: 128x128 tile, K=256 in two halves of 128.
// LDS: Bh/Bl [128][136] u16 (stride 136 -> 16B-aligned rows, <=2-way bank).
#define BST 136
__global__ __launch_bounds__(256, 2)
void sim_gemm(const u16* __restrict__ xnh, const u16* __restrict__ xnl,
              const u16* __restrict__ mnh, const u16* __restrict__ mnl,
              float* __restrict__ sim){
  __shared__ __align__(16) u16 Bh[128*BST];
  __shared__ __align__(16) u16 Bl[128*BST];
  int t = threadIdx.x, lane = t & 63, wv = t >> 6;
  int ml = lane & 15, quad = lane >> 4;
  int b = blockIdx.z;
  int tM = blockIdx.x * 128 + (wv & 1) * 64;
  int tN = blockIdx.y * 128;
  int nloc = (wv >> 1) * 64;   // wave's N-offset within the 128 tile
  const u16* Ah = xnh + ((long)b*NPQ + tM + ml)*DIM;
  const u16* Al = xnl + ((long)b*NPQ + tM + ml)*DIM;
  f32x4 acc[4][4];
  f32x4 zer = {0.f,0.f,0.f,0.f};
#pragma unroll
  for (int i = 0; i < 4; i++)
#pragma unroll
    for (int j = 0; j < 4; j++) acc[i][j] = zer;

  int srow = t >> 4, scg = t & 15;   // staging: 16 rows/pass, 16B per thread
  for (int half = 0; half < 2; half++){
    int k0 = half * 128;
    if (half) __syncthreads();
#pragma unroll
    for (int p = 0; p < 8; p++){
      int r = p*16 + srow;
      long g = ((long)b*MNP + tN + r)*DIM + k0 + scg*8;
      *(uint4*)(&Bh[r*BST + scg*8]) = *(const uint4*)(mnh + g);
      *(uint4*)(&Bl[r*BST + scg*8]) = *(const uint4*)(mnl + g);
    }
    __syncthreads();
#pragma unroll
    for (int kk = 0; kk < 128; kk += 32){
      bf16x8 a[4], a2[4], bh[4], bl[4];
#pragma unroll
      for (int i = 0; i < 4; i++){
        a[i]  = *(const bf16x8*)(Ah + (long)i*16*DIM + k0 + kk + quad*8);
        a2[i] = *(const bf16x8*)(Al + (long)i*16*DIM + k0 + kk + quad*8);
      }
#pragma unroll
      for (int j = 0; j < 4; j++){
        int nr = nloc + j*16 + ml;
        bh[j] = *(const bf16x8*)(&Bh[nr*BST + kk + quad*8]);
        bl[j] = *(const bf16x8*)(&Bl[nr*BST + kk + quad*8]);
      }
#pragma unroll
      for (int i = 0; i < 4; i++)
#pragma unroll
        for (int j = 0; j < 4; j++){
          acc[i][j] = __builtin_amdgcn_mfma_f32_16x16x32_bf16(a[i],  bh[j], acc[i][j], 0, 0, 0);
          acc[i][j] = __builtin_amdgcn_mfma_f32_16x16x32_bf16(a[i],  bl[j], acc[i][j], 0, 0, 0);
          acc[i][j] = __builtin_amdgcn_mfma_f32_16x16x32_bf16(a2[i], bh[j], acc[i][j], 0, 0, 0);
        }
    }
  }
  long zC = (long)b * NPQ * MNP;
#pragma unroll
  for (int i = 0; i < 4; i++)
#pragma unroll
    for (int r = 0; r < 4; r++){
      int row = tM + i*16 + quad*4 + r;
#pragma unroll
      for (int j = 0; j < 4; j++){
        int col = tN + nloc + j*16 + ml;
        sim[zC + (long)row*MNP + col] = acc[i][j][r];
      }
    }
}

// ---------------- MFMA GEMM: C[M,N] = A[M,K] * B[N,K]^T (+bias, act) ----
template<int OUT_BF16, int ACT>
__global__ __launch_bounds__(256)
void gemm_bt(const u16* __restrict__ A, const u16* __restrict__ B,
             const float* __restrict__ bias, void* __restrict__ Cv,
             int M, int N, int K, long sA, long sB, long sC){
  int lane = threadIdx.x & 63, wv = threadIdx.x >> 6;
  int ml = lane & 15, quad = lane >> 4;
  int tM = blockIdx.x * 128 + (wv & 1) * 64;
  int tN = blockIdx.y * 128 + (wv >> 1) * 64;
  const u16* Ap  = A + (long)blockIdx.z*sA + (long)(tM + ml)*K + quad*8;
  const u16* Bp  = B + (long)blockIdx.z*sB + (long)(tN + ml)*K + quad*8;
  f32x4 acc[4][4];
  f32x4 zer = {0.f, 0.f, 0.f, 0.f};
#pragma unroll
  for (int i = 0; i < 4; i++)
#pragma unroll
    for (int j = 0; j < 4; j++) acc[i][j] = zer;
  long rs = (long)16 * K;
  for (int k0 = 0; k0 < K; k0 += 32){
    bf16x8 a[4], b[4];
#pragma unroll
    for (int i = 0; i < 4; i++) a[i] = *(const bf16x8*)(Ap + i*rs + k0);
#pragma unroll
    for (int j = 0; j < 4; j++) b[j] = *(const bf16x8*)(Bp + j*rs + k0);
#pragma unroll
    for (int i = 0; i < 4; i++)
#pragma unroll
      for (int j = 0; j < 4; j++)
        acc[i][j] = __builtin_amdgcn_mfma_f32_16x16x32_bf16(a[i], b[j], acc[i][j], 0, 0, 0);
  }
  long zC = (long)blockIdx.z * sC;
#pragma unroll
  for (int j = 0; j < 4; j++){
    int col = tN + j*16 + ml;
    float bv = bias ? bias[col] : 0.0f;
#pragma unroll
    for (int i = 0; i < 4; i++){
#pragma unroll
      for (int r = 0; r < 4; r++){
        int row = tM + i*16 + quad*4 + r;
        float v = acc[i][j][r] + bv;
        if (ACT == 1) v = gelu_exact(v);
        long idx = zC + (long)row * N + col;
        if (OUT_BF16) ((u16*)Cv)[idx] = f2bf(v);
        else ((float*)Cv)[idx] = v;
      }
    }
  }
}

// ---------------- top-k via atomic-free bit-descent select ----------------
__global__ __launch_bounds__(256)
void topk_k(const float* __restrict__ sim, int* __restrict__ rns){
  __shared__ int red[2][4];
  __shared__ int ties[64];
  __shared__ int tcnt, ocnt;
  int r = blockIdx.x, t = threadIdx.x;
  int lane = t & 63, wv = t >> 6;
  const float* row = sim + (long)r * 4096;
  u32 key[16];
#pragma unroll
  for (int i = 0; i < 16; i++){
    u32 u = __builtin_bit_cast(u32, row[i*256 + t]);
    key[i] = u ^ (((u32)((int)u >> 31)) | 0x80000000u);
  }
  if (t == 0){ tcnt = 0; ocnt = 0; }
  u32 pref = 0;
  for (int bit = 31; bit >= 0; bit--){
    u32 cand = pref | (1u << bit);
    int c = 0;
#pragma unroll
    for (int i = 0; i < 16; i++) c += (key[i] >= cand) ? 1 : 0;
    c = wredsumi(c);
    int p = bit & 1;
    if (lane == 0) red[p][wv] = c;
    __syncthreads();
    int tot = red[p][0] + red[p][1] + red[p][2] + red[p][3];
    if (tot >= TOPK) pref = cand;
  }
  int cg = 0;
#pragma unroll
  for (int i = 0; i < 16; i++) cg += (key[i] > pref) ? 1 : 0;
  cg = wredsumi(cg);
  if (lane == 0) red[0][wv] = cg;
  __syncthreads();
  int ngt = red[0][0] + red[0][1] + red[0][2] + red[0][3];
  int k_rem = TOPK - ngt;
  int* out = rns + (long)r * 32;
#pragma unroll
  for (int i = 0; i < 16; i++){
    if (key[i] > pref){
      int p = atomicAdd(&ocnt, 1);
      out[p] = i*256 + t;
    } else if (key[i] == pref){
      int p = atomicAdd(&tcnt, 1);
      if (p < 64) ties[p] = i*256 + t;
    }
  }
  __syncthreads();
  if (t == 0){
    int n = tcnt < 64 ? tcnt : 64;
    for (int s = 0; s < k_rem; s++){
      int mb = 0;
      for (int j = 1; j < n; j++) if (ties[j] < ties[mb]) mb = j;
      out[ngt + s] = ties[mb];
      ties[mb] = 0x7FFFFFFF;
    }
  }
}

// ---------------- sparse gathered cross-attention ----------------
#define CAS 270
__global__ __launch_bounds__(256)
void cross_attn(const u16* __restrict__ qh, const u16* __restrict__ kh,
                const u16* __restrict__ vh, const int* __restrict__ rns,
                float* __restrict__ crossO){
  __shared__ u16 Kg[32*CAS];
  __shared__ u16 Vg[32*CAS];
  __shared__ float qv[256];
  __shared__ int idxs[32];
  __shared__ float L[256];
  __shared__ float pm[8], ps[8];
  int r = blockIdx.x, t = threadIdx.x;
  int b = r >> 9;
  if (t < 32) idxs[t] = rns[(long)r*32 + t];
  qv[t] = bf2f(qh[(long)r*DIM + t]);
  __syncthreads();
  for (int i = t; i < 32*DIM; i += 256){
    int k = i >> 8, d = i & 255;
    long src = ((long)b*MNP + idxs[k])*DIM + d;
    Kg[k*CAS + d] = kh[src];
    Vg[k*CAS + d] = vh[src];
  }
  __syncthreads();
  {
    int h = t >> 5, k = t & 31;
    float acc = 0.f;
#pragma unroll
    for (int d = 0; d < 32; d++) acc += qv[h*HD + d] * bf2f(Kg[k*CAS + h*HD + d]);
    L[t] = acc * SCALE;
  }
  __syncthreads();
  if (t < 8){
    float m = L[t*32];
    for (int k = 1; k < 32; k++) m = fmaxf(m, L[t*32 + k]);
    float s = 0.f;
    for (int k = 0; k < 32; k++) s += expf(L[t*32 + k] - m);
    pm[t] = m; ps[t] = s;
  }
  __syncthreads();
  {
    int h = t >> 5, dd = t & 31;
    float m = pm[h], inv = 1.0f/ps[h], acc = 0.f;
#pragma unroll
    for (int k = 0; k < 32; k++) acc += expf(L[h*32 + k] - m) * bf2f(Vg[k*CAS + h*HD + dd]);
    crossO[(long)r*DIM + t] = acc * inv;
  }
}

// ---------------- fused layernorms ----------------
template<int MODE>
__global__ __launch_bounds__(256)
void ln_k(const float* __restrict__ xa, const float* __restrict__ xb,
          const float* __restrict__ qpos,
          const float* __restrict__ w, const float* __restrict__ bsh,
          float* __restrict__ yf, u16* __restrict__ yb, u16* __restrict__ qkb){
  __shared__ float sc[8];
  int r = blockIdx.x, t = threadIdx.x;
  int b = r >> 9, n = r & 511;
  long bidx = (long)r*DIM + t;
  long nidx = ((long)n*BSZ + b)*DIM + t;
  float x = (MODE == 1 ? xa[nidx] : xa[bidx]) + xb[bidx];
  float s  = wredsum(x);
  float s2 = wredsum(x*x);
  int wv = t >> 6;
  if ((t & 63) == 0){ sc[wv] = s; sc[4 + wv] = s2; }
  __syncthreads();
  float S  = sc[0]+sc[1]+sc[2]+sc[3];
  float S2 = sc[4]+sc[5]+sc[6]+sc[7];
  float mu  = S * (1.f/256.f);
  float var = S2 * (1.f/256.f) - mu*mu;
  float y = (x - mu) * (1.0f / sqrtf(var + 1e-5f)) * w[t] + bsh[t];
  if (MODE == 3){
    yf[nidx] = y;
  } else {
    yf[bidx] = y;
    yb[bidx] = f2bf(y);
    if (MODE == 1) qkb[bidx] = f2bf(y + qpos[nidx]);
  }
}

// ---------------- fused dense self-attention (MFMA) ----------------
#define KST 40
#define PST 264
__global__ __launch_bounds__(256)
void self_attn(const u16* __restrict__ q2, const u16* __restrict__ k2,
               const u16* __restrict__ v2, u16* __restrict__ sa_pre){
  __shared__ __align__(16) u16 KS[512*KST];
  __shared__ __align__(16) u16 QS[32*KST];
  __shared__ float mbuf[128];
  __shared__ float sbuf[128];
  u16* P  = KS;
  u16* Vt = KS + 32*PST;

  int qt = blockIdx.x, h = blockIdx.y, b = blockIdx.z;
  int t = threadIdx.x, lane = t & 63, wv = t >> 6;
  int ml = lane & 15, quad = lane >> 4;
  int n0 = qt * 32;

  {
    int q = t >> 3, d4 = (t & 7) * 4;
    const u16* src = q2 + ((long)b*NPQ + n0 + q)*DIM + h*HD + d4;
    *(ushort2*)(QS + q*KST + d4)     = *(const ushort2*)(src);
    *(ushort2*)(QS + q*KST + d4 + 2) = *(const ushort2*)(src + 2);
  }
  for (int i = t; i < 512*8; i += 256){
    int j = i >> 3, d4 = (i & 7) * 4;
    const u16* src = k2 + ((long)b*NPQ + j)*DIM + h*HD + d4;
    *(ushort2*)(KS + j*KST + d4)     = *(const ushort2*)(src);
    *(ushort2*)(KS + j*KST + d4 + 2) = *(const ushort2*)(src + 2);
  }
  __syncthreads();

  f32x4 acc[2][8];
  {
    bf16x8 aq[2];
#pragma unroll
    for (int mi = 0; mi < 2; mi++)
      aq[mi] = *(const bf16x8*)(QS + (mi*16 + ml)*KST + quad*8);
#pragma unroll
    for (int nj = 0; nj < 8; nj++){
      bf16x8 bk = *(const bf16x8*)(KS + (wv*128 + nj*16 + ml)*KST + quad*8);
      f32x4 z = {0.f,0.f,0.f,0.f};
#pragma unroll
      for (int mi = 0; mi < 2; mi++)
        acc[mi][nj] = __builtin_amdgcn_mfma_f32_16x16x32_bf16(aq[mi], bk, z, 0, 0, 0);
    }
  }
  float lmax[2][4];
#pragma unroll
  for (int mi = 0; mi < 2; mi++)
#pragma unroll
    for (int r = 0; r < 4; r++) lmax[mi][r] = -3.4e38f;
#pragma unroll
  for (int mi = 0; mi < 2; mi++)
#pragma unroll
    for (int nj = 0; nj < 8; nj++)
#pragma unroll
      for (int r = 0; r < 4; r++){
        float v = acc[mi][nj][r] * SCALE;
        acc[mi][nj][r] = v;
        lmax[mi][r] = fmaxf(lmax[mi][r], v);
      }
#pragma unroll
  for (int m = 1; m < 16; m <<= 1)
#pragma unroll
    for (int mi = 0; mi < 2; mi++)
#pragma unroll
      for (int r = 0; r < 4; r++)
        lmax[mi][r] = fmaxf(lmax[mi][r], __shfl_xor(lmax[mi][r], m, 64));
  if (ml == 0){
#pragma unroll
    for (int mi = 0; mi < 2; mi++)
#pragma unroll
      for (int r = 0; r < 4; r++)
        mbuf[(mi*16 + quad*4 + r)*4 + wv] = lmax[mi][r];
  }
  __syncthreads();
  float inv_[2][4];
  float lsum[2][4];
#pragma unroll
  for (int mi = 0; mi < 2; mi++)
#pragma unroll
    for (int r = 0; r < 4; r++){
      int row = mi*16 + quad*4 + r;
      float m0 = fmaxf(fmaxf(mbuf[row*4+0], mbuf[row*4+1]),
                       fmaxf(mbuf[row*4+2], mbuf[row*4+3]));
      float s = 0.f;
#pragma unroll
      for (int nj = 0; nj < 8; nj++){
        float e = __expf(acc[mi][nj][r] - m0);
        acc[mi][nj][r] = e;
        s += e;
      }
      lsum[mi][r] = s;
    }
#pragma unroll
  for (int m = 1; m < 16; m <<= 1)
#pragma unroll
    for (int mi = 0; mi < 2; mi++)
#pragma unroll
      for (int r = 0; r < 4; r++)
        lsum[mi][r] += __shfl_xor(lsum[mi][r], m, 64);
  if (ml == 0){
#pragma unroll
    for (int mi = 0; mi < 2; mi++)
#pragma unroll
      for (int r = 0; r < 4; r++)
        sbuf[(mi*16 + quad*4 + r)*4 + wv] = lsum[mi][r];
  }
  __syncthreads();
#pragma unroll
  for (int mi = 0; mi < 2; mi++)
#pragma unroll
    for (int r = 0; r < 4; r++){
      int row = mi*16 + quad*4 + r;
      inv_[mi][r] = 1.0f / (sbuf[row*4+0]+sbuf[row*4+1]+sbuf[row*4+2]+sbuf[row*4+3]);
    }

  int mi2 = wv >> 1, ni = wv & 1;
  f32x4 acc2 = {0.f,0.f,0.f,0.f};
  for (int half = 0; half < 2; half++){
    __syncthreads();
    if ((wv >> 1) == half){
      int cbase = (wv & 1) * 128;
#pragma unroll
      for (int mi = 0; mi < 2; mi++)
#pragma unroll
        for (int nj = 0; nj < 8; nj++)
#pragma unroll
          for (int r = 0; r < 4; r++)
            P[(mi*16 + quad*4 + r)*PST + cbase + nj*16 + ml] = f2bf(acc[mi][nj][r]);
    }
    for (int i = t; i < 2048; i += 256){
      int j = i >> 3, d4 = (i & 7) * 4;
      const u16* src = v2 + ((long)b*NPQ + half*256 + j)*DIM + h*HD + d4;
      u16 v0 = src[0], v1 = src[1], v2e = src[2], v3 = src[3];
      Vt[(d4+0)*PST + j] = v0;
      Vt[(d4+1)*PST + j] = v1;
      Vt[(d4+2)*PST + j] = v2e;
      Vt[(d4+3)*PST + j] = v3;
    }
    __syncthreads();
#pragma unroll
    for (int k0 = 0; k0 < 256; k0 += 32){
      bf16x8 ap = *(const bf16x8*)(P  + (mi2*16 + ml)*PST + k0 + quad*8);
      bf16x8 bv = *(const bf16x8*)(Vt + (ni*16  + ml)*PST + k0 + quad*8);
      acc2 = __builtin_amdgcn_mfma_f32_16x16x32_bf16(ap, bv, acc2, 0, 0, 0);
    }
  }
#pragma unroll
  for (int r = 0; r < 4; r++){
    int row = mi2*16 + quad*4 + r;
    sa_pre[((long)b*NPQ + n0 + row)*DIM + h*HD + ni*16 + ml] =
        f2bf(acc2[r] * inv_[mi2][r]);
  }
}

// =====================================================================
extern "C" void kernel_launch(void* const* d_in, const int* in_sizes, int n_in,
                              void* d_out, int out_size, void* d_ws, size_t ws_size,
                              hipStream_t stream){
  (void)in_sizes; (void)n_in; (void)out_size; (void)ws_size;
  const float* tgt  = (const float*)d_in[0];
  const float* mem  = (const float*)d_in[1];
  const float* qpos = (const float*)d_in[2];
  const float* kpos = (const float*)d_in[3];
  const float* cw1  = (const float*)d_in[4];  const float* cb1 = (const float*)d_in[5];
  const float* cw2  = (const float*)d_in[6];  const float* cb2 = (const float*)d_in[7];
  const float* cw3  = (const float*)d_in[8];  const float* cb3 = (const float*)d_in[9];
  const float* saw  = (const float*)d_in[10]; const float* sab = (const float*)d_in[11];
  const float* sow  = (const float*)d_in[12]; const float* sob = (const float*)d_in[13];
  const float* ln1w = (const float*)d_in[14]; const float* ln1b = (const float*)d_in[15];
  const float* ln2w = (const float*)d_in[16]; const float* ln2b = (const float*)d_in[17];
  const float* ln3w = (const float*)d_in[18]; const float* ln3b = (const float*)d_in[19];
  const float* f1w  = (const float*)d_in[20]; const float* f1bs = (const float*)d_in[21];
  const float* f2w  = (const float*)d_in[22]; const float* f2bs = (const float*)d_in[23];

  char* base = (char*)d_ws;
  size_t off = 0;
  auto alloc = [&](size_t bytes) -> char* {
    char* p = base + off;
    off += (bytes + 255) & ~(size_t)255;
    return p;
  };
  // persistent bf16 weight arena — contiguous (all sizes multiple of 256 B)
  u16* cw1b = (u16*)alloc(65536u*2);
  u16* cw2b = (u16*)alloc(65536u*2);
  u16* cw3b = (u16*)alloc(65536u*2);
  u16* sawb = (u16*)alloc(196608u*2);
  u16* sowb = (u16*)alloc(65536u*2);
  u16* f1wb = (u16*)alloc(524288u*2);
  u16* f2wb = (u16*)alloc(524288u*2);
  int* rns  = (int*)alloc(4096u*32*4);
  size_t offB = off;
  u16* xnh = (u16*)alloc((size_t)4096*256*2);
  u16* xnl = (u16*)alloc((size_t)4096*256*2);
  u16* mnh = (u16*)alloc((size_t)32768*256*2);
  u16* mnl = (u16*)alloc((size_t)32768*256*2);
  u16* qc  = (u16*)alloc((size_t)4096*256*2);
  u16* kc  = (u16*)alloc((size_t)32768*256*2);
  u16* vc  = (u16*)alloc((size_t)32768*256*2);
  float* sim = (float*)alloc((size_t)8*512*4096*4);

  char* regC = (char*)sim;
  u16* qh = (u16*)regC;
  u16* kh = (u16*)(regC + 2097152);
  u16* vh = (u16*)(regC + 2097152 + 16777216);
  char* regB = base + offB;
  size_t ob = 0;
  auto allocB = [&](size_t bytes) -> char* {
    char* p = regB + ob;
    ob += (bytes + 255) & ~(size_t)255;
    return p;
  };
  float* cross = (float*)allocB((size_t)4096*256*4);
  float* t1    = (float*)allocB((size_t)4096*256*4);
  u16*   t1b   = (u16*)allocB((size_t)4096*256*2);
  u16*   qkb   = (u16*)allocB((size_t)4096*256*2);
  u16*   q2    = (u16*)allocB((size_t)4096*256*2);
  u16*   k2    = (u16*)allocB((size_t)4096*256*2);
  u16*   v2    = (u16*)allocB((size_t)4096*256*2);
  u16*   sa_pre= (u16*)allocB((size_t)4096*256*2);
  float* sa    = (float*)allocB((size_t)4096*256*4);
  float* t2    = (float*)allocB((size_t)4096*256*4);
  u16*   t2b   = (u16*)allocB((size_t)4096*256*2);
  u16*   h1    = (u16*)allocB((size_t)4096*2048*2);
  float* ff    = (float*)allocB((size_t)4096*256*4);

  dim3 blk(256);
  // 1) all weights -> bf16 in one launch (dst arena is contiguous)
  cvt_all<<<dim3((1507328 + 255)/256), blk, 0, stream>>>(
      cw1, cw2, cw3, saw, sow, f1w, f2w, cw1b);
  // 2) activation prep
  prep_tgt<<<dim3(4096), blk, 0, stream>>>(tgt, qpos, xnh, xnl, qc);
  prep_mem<<<dim3(32768), blk, 0, stream>>>(mem, kpos, mnh, mnl, kc, vc);
  // 3) sim (split bf16, LDS-staged)
  sim_gemm<<<dim3(4,32,8), blk, 0, stream>>>(xnh, xnl, mnh, mnl, sim);
  // 4) exact top-32
  topk_k<<<dim3(4096), blk, 0, stream>>>(sim, rns);
  // 5) q/k/v cross projections (overwrite sim region)
  gemm_bt<1,0><<<dim3(32,2,1), blk, 0, stream>>>(qc, cw1b, cb1, qh,
      4096, 256, 256, 0, 0, 0);
  gemm_bt<1,0><<<dim3(256,2,1), blk, 0, stream>>>(kc, cw2b, cb2, kh,
      32768, 256, 256, 0, 0, 0);
  gemm_bt<1,0><<<dim3(256,2,1), blk, 0, stream>>>(vc, cw3b, cb3, vh,
      32768, 256, 256, 0, 0, 0);
  // 6) sparse cross-attention
  cross_attn<<<dim3(4096), blk, 0, stream>>>(qh, kh, vh, rns, cross);
  // 7) LN1 (+ qk staging)
  ln_k<1><<<dim3(4096), blk, 0, stream>>>(tgt, cross, qpos, ln1w, ln1b, t1, t1b, qkb);
  // 8) self-attn projections
  gemm_bt<1,0><<<dim3(32,2,1), blk, 0, stream>>>(qkb, sawb, sab, q2,
      4096, 256, 256, 0, 0, 0);
  gemm_bt<1,0><<<dim3(32,2,1), blk, 0, stream>>>(qkb, sawb + 65536, sab + 256, k2,
      4096, 256, 256, 0, 0, 0);
  gemm_bt<1,0><<<dim3(32,2,1), blk, 0, stream>>>(t1b, sawb + 131072, sab + 512, v2,
      4096, 256, 256, 0, 0, 0);
  // 9) fused dense self-attention
  self_attn<<<dim3(16,8,8), blk, 0, stream>>>(q2, k2, v2, sa_pre);
  // 10) output projection
  gemm_bt<0,0><<<dim3(32,2,1), blk, 0, stream>>>(sa_pre, sowb, sob, sa,
      4096, 256, 256, 0, 0, 0);
  // 11) LN2
  ln_k<2><<<dim3(4096), blk, 0, stream>>>(t1, sa, nullptr, ln2w, ln2b, t2, t2b, nullptr);
  // 12) FFN
  gemm_bt<1,1><<<dim3(32,16,1), blk, 0, stream>>>(t2b, f1wb, f1bs, h1,
      4096, 2048, 256, 0, 0, 0);
  gemm_bt<0,0><<<dim3(32,2,1), blk, 0, stream>>>(h1, f2wb, f2bs, ff,
      4096, 256, 2048, 0, 0, 0);
  // 13) LN3 -> output (n-major)
  ln_k<3><<<dim3(4096), blk, 0, stream>>>(t2, ff, nullptr, ln3w, ln3b, (float*)d_out, nullptr, nullptr);
}

// Round 6
// 452.947 us; speedup vs baseline: 1.8582x; 1.2241x over previous
//
#include <hip/hip_runtime.h>
#include <math.h>

typedef unsigned short u16;
typedef unsigned int u32;
typedef __bf16 bf16x8 __attribute__((ext_vector_type(8)));
typedef float f32x4 __attribute__((ext_vector_type(4)));

#define NPQ 512
#define MNP 4096
#define BSZ 8
#define DIM 256
#define NH 8
#define HD 32
#define TOPK 32
#define FFD 2048
#define SCALE 0.17677669529663687f  // 1/sqrt(32)

__device__ __forceinline__ u16 f2bf(float f){
  u32 u = __builtin_bit_cast(u32, f);
  u = (u + 0x7FFFu + ((u >> 16) & 1u)) >> 16;
  return (u16)u;
}
__device__ __forceinline__ float bf2f(u16 h){
  u32 u = ((u32)h) << 16;
  return __builtin_bit_cast(float, u);
}
__device__ __forceinline__ float wredsum(float v){
#pragma unroll
  for (int m = 32; m; m >>= 1) v += __shfl_xor(v, m, 64);
  return v;
}
__device__ __forceinline__ int wredsumi(int v){
#pragma unroll
  for (int m = 32; m; m >>= 1) v += __shfl_xor(v, m, 64);
  return v;
}
__device__ __forceinline__ float gelu_exact(float x){
  return 0.5f * x * (1.0f + erff(x * 0.70710678118654752f));
}

// ---------------- fp32 -> bf16 convert, all weights in one launch --------
__global__ __launch_bounds__(256)
void cvt_all(const float* __restrict__ s0, const float* __restrict__ s1,
             const float* __restrict__ s2, const float* __restrict__ s3,
             const float* __restrict__ s4, const float* __restrict__ s5,
             const float* __restrict__ s6, u16* __restrict__ dst){
  int i = blockIdx.x*256 + threadIdx.x;
  if (i >= 1507328) return;
  const float* s; int base;
  if      (i <  65536){ s = s0; base = 0; }
  else if (i < 131072){ s = s1; base = 65536; }
  else if (i < 196608){ s = s2; base = 131072; }
  else if (i < 393216){ s = s3; base = 196608; }
  else if (i < 458752){ s = s4; base = 393216; }
  else if (i < 983040){ s = s5; base = 458752; }
  else                { s = s6; base = 983040; }
  dst[i] = f2bf(s[i - base]);
}

// ---------------- prep: normalize + split + pos-add ----------------
__global__ __launch_bounds__(256)
void prep_tgt(const float* __restrict__ tgt, const float* __restrict__ qpos,
              u16* __restrict__ xnh, u16* __restrict__ xnl, u16* __restrict__ qc,
              const float* __restrict__ cb2, const float* __restrict__ cb3,
              float* __restrict__ cbKV){
  __shared__ float sc[4];
  int r = blockIdx.x, t = threadIdx.x;
  if (r == 0){ cbKV[t] = cb2[t]; cbKV[256 + t] = cb3[t]; }
  int b = r >> 9, n = r & 511;
  long src = ((long)n*BSZ + b)*DIM + t;
  float x = tgt[src];
  float s = wredsum(x*x);
  if ((t & 63) == 0) sc[t >> 6] = s;
  __syncthreads();
  float tot = sc[0]+sc[1]+sc[2]+sc[3];
  float xn = x / sqrtf(tot);
  u16 hi = f2bf(xn);
  long dst = (long)r*DIM + t;
  xnh[dst] = hi;
  xnl[dst] = f2bf(xn - bf2f(hi));
  qc[dst]  = f2bf(x + qpos[src]);
}

__global__ __launch_bounds__(256)
void prep_mem(const float* __restrict__ mem, const float* __restrict__ kpos,
              u16* __restrict__ mnh, u16* __restrict__ mnl,
              u16* __restrict__ kc, u16* __restrict__ vc){
  __shared__ float sc[4];
  int r = blockIdx.x, t = threadIdx.x;
  int b = r >> 12, mp = r & 4095;
  long src = ((long)mp*BSZ + b)*DIM + t;
  float x = mem[src];
  float s = wredsum(x*x);
  if ((t & 63) == 0) sc[t >> 6] = s;
  __syncthreads();
  float tot = sc[0]+sc[1]+sc[2]+sc[3];
  float xn = x / sqrtf(tot);
  u16 hi = f2bf(xn);
  long dst = (long)r*DIM + t;
  mnh[dst] = hi;
  mnl[dst] = f2bf(xn - bf2f(hi));
  kc[dst]  = f2bf(x + kpos[src]);
  vc[dst]  = f2bf(x);
}

// ---------------- sim GEMM (split bf16, LDS-staged B) ----------------
#define BST 136
__global__ __launch_bounds__(256, 2)
void sim_gemm(const u16* __restrict__ xnh, const u16* __restrict__ xnl,
              const u16* __restrict__ mnh, const u16* __restrict__ mnl,
              float* __restrict__ sim){
  __shared__ __align__(16) u16 Bh[128*BST];
  __shared__ __align__(16) u16 Bl[128*BST];
  int t = threadIdx.x, lane = t & 63, wv = t >> 6;
  int ml = lane & 15, quad = lane >> 4;
  int b = blockIdx.z;
  int tM = blockIdx.x * 128 + (wv & 1) * 64;
  int tN = blockIdx.y * 128;
  int nloc = (wv >> 1) * 64;
  const u16* Ah = xnh + ((long)b*NPQ + tM + ml)*DIM;
  const u16* Al = xnl + ((long)b*NPQ + tM + ml)*DIM;
  f32x4 acc[4][4];
  f32x4 zer = {0.f,0.f,0.f,0.f};
#pragma unroll
  for (int i = 0; i < 4; i++)
#pragma unroll
    for (int j = 0; j < 4; j++) acc[i][j] = zer;

  int srow = t >> 4, scg = t & 15;
  for (int half = 0; half < 2; half++){
    int k0 = half * 128;
    if (half) __syncthreads();
#pragma unroll
    for (int p = 0; p < 8; p++){
      int r = p*16 + srow;
      long g = ((long)b*MNP + tN + r)*DIM + k0 + scg*8;
      *(uint4*)(&Bh[r*BST + scg*8]) = *(const uint4*)(mnh + g);
      *(uint4*)(&Bl[r*BST + scg*8]) = *(const uint4*)(mnl + g);
    }
    __syncthreads();
#pragma unroll
    for (int kk = 0; kk < 128; kk += 32){
      bf16x8 a[4], a2[4], bh[4], bl[4];
#pragma unroll
      for (int i = 0; i < 4; i++){
        a[i]  = *(const bf16x8*)(Ah + (long)i*16*DIM + k0 + kk + quad*8);
        a2[i] = *(const bf16x8*)(Al + (long)i*16*DIM + k0 + kk + quad*8);
      }
#pragma unroll
      for (int j = 0; j < 4; j++){
        int nr = nloc + j*16 + ml;
        bh[j] = *(const bf16x8*)(&Bh[nr*BST + kk + quad*8]);
        bl[j] = *(const bf16x8*)(&Bl[nr*BST + kk + quad*8]);
      }
#pragma unroll
      for (int i = 0; i < 4; i++)
#pragma unroll
        for (int j = 0; j < 4; j++){
          acc[i][j] = __builtin_amdgcn_mfma_f32_16x16x32_bf16(a[i],  bh[j], acc[i][j], 0, 0, 0);
          acc[i][j] = __builtin_amdgcn_mfma_f32_16x16x32_bf16(a[i],  bl[j], acc[i][j], 0, 0, 0);
          acc[i][j] = __builtin_amdgcn_mfma_f32_16x16x32_bf16(a2[i], bh[j], acc[i][j], 0, 0, 0);
        }
    }
  }
  long zC = (long)b * NPQ * MNP;
#pragma unroll
  for (int i = 0; i < 4; i++)
#pragma unroll
    for (int r = 0; r < 4; r++){
      int row = tM + i*16 + quad*4 + r;
#pragma unroll
      for (int j = 0; j < 4; j++){
        int col = tN + nloc + j*16 + ml;
        sim[zC + (long)row*MNP + col] = acc[i][j][r];
      }
    }
}

// ---------------- projection GEMM (latency-optimized skinny shapes) ----
// C[M,N] = A[M,K] * B[N,K]^T + bias, K = KGROUPS*256.
// grid (M/64, N/64); block 256 = 4 waves, wave = 16 rows x 64 cols.
// B-tile (64 x 256-group) staged in LDS; A loads fully unrolled per group.
// selCol: A for output cols < selCol, A2 for cols >= selCol (fused GEMMs).
#define PBST 264
template<int KGROUPS, int OUT_BF16, int ACT>
__global__ __launch_bounds__(256)
void pgemm(const u16* __restrict__ A, const u16* __restrict__ A2, int selCol,
           const u16* __restrict__ B, const float* __restrict__ bias,
           void* __restrict__ Cv, int N){
  __shared__ __align__(16) u16 Bs[64*PBST];
  const int K = KGROUPS*256;
  int t = threadIdx.x, lane = t & 63, wv = t >> 6;
  int ml = lane & 15, quad = lane >> 4;
  int tM = blockIdx.x*64;
  int tN = blockIdx.y*64;
  const u16* Ab = (tN < selCol) ? A : A2;
  const u16* Arow = Ab + (long)(tM + wv*16 + ml)*K;
  f32x4 acc[4];
  f32x4 zer = {0.f,0.f,0.f,0.f};
#pragma unroll
  for (int nj = 0; nj < 4; nj++) acc[nj] = zer;
  int srow = t >> 5, scol = (t & 31)*8;
  for (int g = 0; g < KGROUPS; g++){
    if (g) __syncthreads();
#pragma unroll
    for (int p = 0; p < 8; p++){
      int r = p*8 + srow;
      *(uint4*)(&Bs[r*PBST + scol]) = *(const uint4*)(B + (long)(tN + r)*K + g*256 + scol);
    }
    bf16x8 a[8];
#pragma unroll
    for (int kk = 0; kk < 8; kk++)
      a[kk] = *(const bf16x8*)(Arow + g*256 + kk*32 + quad*8);
    __syncthreads();
#pragma unroll
    for (int kk = 0; kk < 8; kk++){
#pragma unroll
      for (int nj = 0; nj < 4; nj++){
        bf16x8 bv = *(const bf16x8*)(&Bs[(nj*16 + ml)*PBST + kk*32 + quad*8]);
        acc[nj] = __builtin_amdgcn_mfma_f32_16x16x32_bf16(a[kk], bv, acc[nj], 0, 0, 0);
      }
    }
  }
#pragma unroll
  for (int nj = 0; nj < 4; nj++){
    int col = tN + nj*16 + ml;
    float bv = bias[col];
#pragma unroll
    for (int r = 0; r < 4; r++){
      int row = tM + wv*16 + quad*4 + r;
      float v = acc[nj][r] + bv;
      if (ACT == 1) v = gelu_exact(v);
      long idx = (long)row * N + col;
      if (OUT_BF16) ((u16*)Cv)[idx] = f2bf(v);
      else ((float*)Cv)[idx] = v;
    }
  }
}

// ---------------- top-k via atomic-free bit-descent select ----------------
__global__ __launch_bounds__(256)
void topk_k(const float* __restrict__ sim, int* __restrict__ rns){
  __shared__ int red[2][4];
  __shared__ int ties[64];
  __shared__ int tcnt, ocnt;
  int r = blockIdx.x, t = threadIdx.x;
  int lane = t & 63, wv = t >> 6;
  const float* row = sim + (long)r * 4096;
  u32 key[16];
#pragma unroll
  for (int i = 0; i < 16; i++){
    u32 u = __builtin_bit_cast(u32, row[i*256 + t]);
    key[i] = u ^ (((u32)((int)u >> 31)) | 0x80000000u);
  }
  if (t == 0){ tcnt = 0; ocnt = 0; }
  u32 pref = 0;
  for (int bit = 31; bit >= 0; bit--){
    u32 cand = pref | (1u << bit);
    int c = 0;
#pragma unroll
    for (int i = 0; i < 16; i++) c += (key[i] >= cand) ? 1 : 0;
    c = wredsumi(c);
    int p = bit & 1;
    if (lane == 0) red[p][wv] = c;
    __syncthreads();
    int tot = red[p][0] + red[p][1] + red[p][2] + red[p][3];
    if (tot >= TOPK) pref = cand;
  }
  int cg = 0;
#pragma unroll
  for (int i = 0; i < 16; i++) cg += (key[i] > pref) ? 1 : 0;
  cg = wredsumi(cg);
  if (lane == 0) red[0][wv] = cg;
  __syncthreads();
  int ngt = red[0][0] + red[0][1] + red[0][2] + red[0][3];
  int k_rem = TOPK - ngt;
  int* out = rns + (long)r * 32;
#pragma unroll
  for (int i = 0; i < 16; i++){
    if (key[i] > pref){
      int p = atomicAdd(&ocnt, 1);
      out[p] = i*256 + t;
    } else if (key[i] == pref){
      int p = atomicAdd(&tcnt, 1);
      if (p < 64) ties[p] = i*256 + t;
    }
  }
  __syncthreads();
  if (t == 0){
    int n = tcnt < 64 ? tcnt : 64;
    for (int s = 0; s < k_rem; s++){
      int mb = 0;
      for (int j = 1; j < n; j++) if (ties[j] < ties[mb]) mb = j;
      out[ngt + s] = ties[mb];
      ties[mb] = 0x7FFFFFFF;
    }
  }
}

// ---------------- sparse gathered cross-attention ----------------
// khvh layout: [32768][512], K at col 0..255, V at col 256..511
#define CAS 270
__global__ __launch_bounds__(256)
void cross_attn(const u16* __restrict__ qh, const u16* __restrict__ khvh,
                const int* __restrict__ rns, float* __restrict__ crossO){
  __shared__ u16 Kg[32*CAS];
  __shared__ u16 Vg[32*CAS];
  __shared__ float qv[256];
  __shared__ int idxs[32];
  __shared__ float L[256];
  __shared__ float pm[8], ps[8];
  int r = blockIdx.x, t = threadIdx.x;
  int b = r >> 9;
  if (t < 32) idxs[t] = rns[(long)r*32 + t];
  qv[t] = bf2f(qh[(long)r*DIM + t]);
  __syncthreads();
  for (int i = t; i < 32*DIM; i += 256){
    int k = i >> 8, d = i & 255;
    long src = ((long)b*MNP + idxs[k])*512 + d;
    Kg[k*CAS + d] = khvh[src];
    Vg[k*CAS + d] = khvh[src + 256];
  }
  __syncthreads();
  {
    int h = t >> 5, k = t & 31;
    float acc = 0.f;
#pragma unroll
    for (int d = 0; d < 32; d++) acc += qv[h*HD + d] * bf2f(Kg[k*CAS + h*HD + d]);
    L[t] = acc * SCALE;
  }
  __syncthreads();
  if (t < 8){
    float m = L[t*32];
    for (int k = 1; k < 32; k++) m = fmaxf(m, L[t*32 + k]);
    float s = 0.f;
    for (int k = 0; k < 32; k++) s += expf(L[t*32 + k] - m);
    pm[t] = m; ps[t] = s;
  }
  __syncthreads();
  {
    int h = t >> 5, dd = t & 31;
    float m = pm[h], inv = 1.0f/ps[h], acc = 0.f;
#pragma unroll
    for (int k = 0; k < 32; k++) acc += expf(L[h*32 + k] - m) * bf2f(Vg[k*CAS + h*HD + dd]);
    crossO[(long)r*DIM + t] = acc * inv;
  }
}

// ---------------- fused layernorms ----------------
template<int MODE>
__global__ __launch_bounds__(256)
void ln_k(const float* __restrict__ xa, const float* __restrict__ xb,
          const float* __restrict__ qpos,
          const float* __restrict__ w, const float* __restrict__ bsh,
          float* __restrict__ yf, u16* __restrict__ yb, u16* __restrict__ qkb){
  __shared__ float sc[8];
  int r = blockIdx.x, t = threadIdx.x;
  int b = r >> 9, n = r & 511;
  long bidx = (long)r*DIM + t;
  long nidx = ((long)n*BSZ + b)*DIM + t;
  float x = (MODE == 1 ? xa[nidx] : xa[bidx]) + xb[bidx];
  float s  = wredsum(x);
  float s2 = wredsum(x*x);
  int wv = t >> 6;
  if ((t & 63) == 0){ sc[wv] = s; sc[4 + wv] = s2; }
  __syncthreads();
  float S  = sc[0]+sc[1]+sc[2]+sc[3];
  float S2 = sc[4]+sc[5]+sc[6]+sc[7];
  float mu  = S * (1.f/256.f);
  float var = S2 * (1.f/256.f) - mu*mu;
  float y = (x - mu) * (1.0f / sqrtf(var + 1e-5f)) * w[t] + bsh[t];
  if (MODE == 3){
    yf[nidx] = y;
  } else {
    yf[bidx] = y;
    yb[bidx] = f2bf(y);
    if (MODE == 1) qkb[bidx] = f2bf(y + qpos[nidx]);
  }
}

// ---------------- fused dense self-attention (MFMA) ----------------
// qkv layout: [4096][768], q at 0, k at 256, v at 512.
#define KST 40
#define PST 264
__global__ __launch_bounds__(256)
void self_attn(const u16* __restrict__ qkv, u16* __restrict__ sa_pre){
  __shared__ __align__(16) u16 KS[512*KST];
  __shared__ __align__(16) u16 QS[32*KST];
  __shared__ float mbuf[128];
  __shared__ float sbuf[128];
  u16* P  = KS;
  u16* Vt = KS + 32*PST;

  int qt = blockIdx.x, h = blockIdx.y, b = blockIdx.z;
  int t = threadIdx.x, lane = t & 63, wv = t >> 6;
  int ml = lane & 15, quad = lane >> 4;
  int n0 = qt * 32;

  {
    int q = t >> 3, d4 = (t & 7) * 4;
    const u16* src = qkv + ((long)b*NPQ + n0 + q)*768 + h*HD + d4;
    *(ushort2*)(QS + q*KST + d4)     = *(const ushort2*)(src);
    *(ushort2*)(QS + q*KST + d4 + 2) = *(const ushort2*)(src + 2);
  }
  for (int i = t; i < 512*8; i += 256){
    int j = i >> 3, d4 = (i & 7) * 4;
    const u16* src = qkv + ((long)b*NPQ + j)*768 + 256 + h*HD + d4;
    *(ushort2*)(KS + j*KST + d4)     = *(const ushort2*)(src);
    *(ushort2*)(KS + j*KST + d4 + 2) = *(const ushort2*)(src + 2);
  }
  __syncthreads();

  f32x4 acc[2][8];
  {
    bf16x8 aq[2];
#pragma unroll
    for (int mi = 0; mi < 2; mi++)
      aq[mi] = *(const bf16x8*)(QS + (mi*16 + ml)*KST + quad*8);
#pragma unroll
    for (int nj = 0; nj < 8; nj++){
      bf16x8 bk = *(const bf16x8*)(KS + (wv*128 + nj*16 + ml)*KST + quad*8);
      f32x4 z = {0.f,0.f,0.f,0.f};
#pragma unroll
      for (int mi = 0; mi < 2; mi++)
        acc[mi][nj] = __builtin_amdgcn_mfma_f32_16x16x32_bf16(aq[mi], bk, z, 0, 0, 0);
    }
  }
  float lmax[2][4];
#pragma unroll
  for (int mi = 0; mi < 2; mi++)
#pragma unroll
    for (int r = 0; r < 4; r++) lmax[mi][r] = -3.4e38f;
#pragma unroll
  for (int mi = 0; mi < 2; mi++)
#pragma unroll
    for (int nj = 0; nj < 8; nj++)
#pragma unroll
      for (int r = 0; r < 4; r++){
        float v = acc[mi][nj][r] * SCALE;
        acc[mi][nj][r] = v;
        lmax[mi][r] = fmaxf(lmax[mi][r], v);
      }
#pragma unroll
  for (int m = 1; m < 16; m <<= 1)
#pragma unroll
    for (int mi = 0; mi < 2; mi++)
#pragma unroll
      for (int r = 0; r < 4; r++)
        lmax[mi][r] = fmaxf(lmax[mi][r], __shfl_xor(lmax[mi][r], m, 64));
  if (ml == 0){
#pragma unroll
    for (int mi = 0; mi < 2; mi++)
#pragma unroll
      for (int r = 0; r < 4; r++)
        mbuf[(mi*16 + quad*4 + r)*4 + wv] = lmax[mi][r];
  }
  __syncthreads();
  float inv_[2][4];
  float lsum[2][4];
#pragma unroll
  for (int mi = 0; mi < 2; mi++)
#pragma unroll
    for (int r = 0; r < 4; r++){
      int row = mi*16 + quad*4 + r;
      float m0 = fmaxf(fmaxf(mbuf[row*4+0], mbuf[row*4+1]),
                       fmaxf(mbuf[row*4+2], mbuf[row*4+3]));
      float s = 0.f;
#pragma unroll
      for (int nj = 0; nj < 8; nj++){
        float e = __expf(acc[mi][nj][r] - m0);
        acc[mi][nj][r] = e;
        s += e;
      }
      lsum[mi][r] = s;
    }
#pragma unroll
  for (int m = 1; m < 16; m <<= 1)
#pragma unroll
    for (int mi = 0; mi < 2; mi++)
#pragma unroll
      for (int r = 0; r < 4; r++)
        lsum[mi][r] += __shfl_xor(lsum[mi][r], m, 64);
  if (ml == 0){
#pragma unroll
    for (int mi = 0; mi < 2; mi++)
#pragma unroll
      for (int r = 0; r < 4; r++)
        sbuf[(mi*16 + quad*4 + r)*4 + wv] = lsum[mi][r];
  }
  __syncthreads();
#pragma unroll
  for (int mi = 0; mi < 2; mi++)
#pragma unroll
    for (int r = 0; r < 4; r++){
      int row = mi*16 + quad*4 + r;
      inv_[mi][r] = 1.0f / (sbuf[row*4+0]+sbuf[row*4+1]+sbuf[row*4+2]+sbuf[row*4+3]);
    }

  int mi2 = wv >> 1, ni = wv & 1;
  f32x4 acc2 = {0.f,0.f,0.f,0.f};
  for (int half = 0; half < 2; half++){
    __syncthreads();
    if ((wv >> 1) == half){
      int cbase = (wv & 1) * 128;
#pragma unroll
      for (int mi = 0; mi < 2; mi++)
#pragma unroll
        for (int nj = 0; nj < 8; nj++)
#pragma unroll
          for (int r = 0; r < 4; r++)
            P[(mi*16 + quad*4 + r)*PST + cbase + nj*16 + ml] = f2bf(acc[mi][nj][r]);
    }
    for (int i = t; i < 2048; i += 256){
      int j = i >> 3, d4 = (i & 7) * 4;
      const u16* src = qkv + ((long)b*NPQ + half*256 + j)*768 + 512 + h*HD + d4;
      u16 v0 = src[0], v1 = src[1], v2e = src[2], v3 = src[3];
      Vt[(d4+0)*PST + j] = v0;
      Vt[(d4+1)*PST + j] = v1;
      Vt[(d4+2)*PST + j] = v2e;
      Vt[(d4+3)*PST + j] = v3;
    }
    __syncthreads();
#pragma unroll
    for (int k0 = 0; k0 < 256; k0 += 32){
      bf16x8 ap = *(const bf16x8*)(P  + (mi2*16 + ml)*PST + k0 + quad*8);
      bf16x8 bv = *(const bf16x8*)(Vt + (ni*16  + ml)*PST + k0 + quad*8);
      acc2 = __builtin_amdgcn_mfma_f32_16x16x32_bf16(ap, bv, acc2, 0, 0, 0);
    }
  }
#pragma unroll
  for (int r = 0; r < 4; r++){
    int row = mi2*16 + quad*4 + r;
    sa_pre[((long)b*NPQ + n0 + row)*DIM + h*HD + ni*16 + ml] =
        f2bf(acc2[r] * inv_[mi2][r]);
  }
}

// =====================================================================
extern "C" void kernel_launch(void* const* d_in, const int* in_sizes, int n_in,
                              void* d_out, int out_size, void* d_ws, size_t ws_size,
                              hipStream_t stream){
  (void)in_sizes; (void)n_in; (void)out_size; (void)ws_size;
  const float* tgt  = (const float*)d_in[0];
  const float* mem  = (const float*)d_in[1];
  const float* qpos = (const float*)d_in[2];
  const float* kpos = (const float*)d_in[3];
  const float* cw1  = (const float*)d_in[4];  const float* cb1 = (const float*)d_in[5];
  const float* cw2  = (const float*)d_in[6];  const float* cb2 = (const float*)d_in[7];
  const float* cw3  = (const float*)d_in[8];  const float* cb3 = (const float*)d_in[9];
  const float* saw  = (const float*)d_in[10]; const float* sab = (const float*)d_in[11];
  const float* sow  = (const float*)d_in[12]; const float* sob = (const float*)d_in[13];
  const float* ln1w = (const float*)d_in[14]; const float* ln1b = (const float*)d_in[15];
  const float* ln2w = (const float*)d_in[16]; const float* ln2b = (const float*)d_in[17];
  const float* ln3w = (const float*)d_in[18]; const float* ln3b = (const float*)d_in[19];
  const float* f1w  = (const float*)d_in[20]; const float* f1bs = (const float*)d_in[21];
  const float* f2w  = (const float*)d_in[22]; const float* f2bs = (const float*)d_in[23];

  char* base = (char*)d_ws;
  size_t off = 0;
  auto alloc = [&](size_t bytes) -> char* {
    char* p = base + off;
    off += (bytes + 255) & ~(size_t)255;
    return p;
  };
  // persistent bf16 weight arena — contiguous (order matters: cw2b||cw3b fused)
  u16* cw1b = (u16*)alloc(65536u*2);
  u16* cw2b = (u16*)alloc(65536u*2);
  u16* cw3b = (u16*)alloc(65536u*2);   (void)cw3b;
  u16* sawb = (u16*)alloc(196608u*2);
  u16* sowb = (u16*)alloc(65536u*2);
  u16* f1wb = (u16*)alloc(524288u*2);
  u16* f2wb = (u16*)alloc(524288u*2);
  int* rns  = (int*)alloc(4096u*32*4);
  float* cbKV = (float*)alloc(512*4);
  size_t offB = off;
  u16* xnh = (u16*)alloc((size_t)4096*256*2);
  u16* xnl = (u16*)alloc((size_t)4096*256*2);
  u16* mnh = (u16*)alloc((size_t)32768*256*2);
  u16* mnl = (u16*)alloc((size_t)32768*256*2);
  u16* qc  = (u16*)alloc((size_t)4096*256*2);
  u16* kc  = (u16*)alloc((size_t)32768*256*2);
  u16* vc  = (u16*)alloc((size_t)32768*256*2);
  float* sim = (float*)alloc((size_t)8*512*4096*4);

  // region C overlay (after topk): qh + fused khvh
  char* regC = (char*)sim;
  u16* qh   = (u16*)regC;                      // [4096][256]  2 MB
  u16* khvh = (u16*)(regC + 2097152);          // [32768][512] 32 MB
  // region B overlay (after projections consume staging)
  char* regB = base + offB;
  size_t ob = 0;
  auto allocB = [&](size_t bytes) -> char* {
    char* p = regB + ob;
    ob += (bytes + 255) & ~(size_t)255;
    return p;
  };
  float* cross = (float*)allocB((size_t)4096*256*4);
  float* t1    = (float*)allocB((size_t)4096*256*4);
  u16*   t1b   = (u16*)allocB((size_t)4096*256*2);
  u16*   qkb   = (u16*)allocB((size_t)4096*256*2);
  u16*   qkv   = (u16*)allocB((size_t)4096*768*2);
  u16*   sa_pre= (u16*)allocB((size_t)4096*256*2);
  float* sa    = (float*)allocB((size_t)4096*256*4);
  float* t2    = (float*)allocB((size_t)4096*256*4);
  u16*   t2b   = (u16*)allocB((size_t)4096*256*2);
  u16*   h1    = (u16*)allocB((size_t)4096*2048*2);
  float* ff    = (float*)allocB((size_t)4096*256*4);

  const int BIG = 1 << 30;
  dim3 blk(256);
  // 1) weights -> bf16 (one launch)
  cvt_all<<<dim3((1507328 + 255)/256), blk, 0, stream>>>(
      cw1, cw2, cw3, saw, sow, f1w, f2w, cw1b);
  // 2) activation prep (+ cbKV concat in block 0)
  prep_tgt<<<dim3(4096), blk, 0, stream>>>(tgt, qpos, xnh, xnl, qc, cb2, cb3, cbKV);
  prep_mem<<<dim3(32768), blk, 0, stream>>>(mem, kpos, mnh, mnl, kc, vc);
  // 3) sim (split bf16)
  sim_gemm<<<dim3(4,32,8), blk, 0, stream>>>(xnh, xnl, mnh, mnl, sim);
  // 4) exact top-32
  topk_k<<<dim3(4096), blk, 0, stream>>>(sim, rns);
  // 5) cross projections: qh, fused kh||vh
  pgemm<1,1,0><<<dim3(64,4), blk, 0, stream>>>(qc, qc, BIG, cw1b, cb1, qh, 256);
  pgemm<1,1,0><<<dim3(512,8), blk, 0, stream>>>(kc, vc, 256, cw2b, cbKV, khvh, 512);
  // 6) sparse cross-attention
  cross_attn<<<dim3(4096), blk, 0, stream>>>(qh, khvh, rns, cross);
  // 7) LN1 (+ qk staging)
  ln_k<1><<<dim3(4096), blk, 0, stream>>>(tgt, cross, qpos, ln1w, ln1b, t1, t1b, qkb);
  // 8) fused q2||k2||v2 projection
  pgemm<1,1,0><<<dim3(64,12), blk, 0, stream>>>(qkb, t1b, 512, sawb, sab, qkv, 768);
  // 9) fused dense self-attention
  self_attn<<<dim3(16,8,8), blk, 0, stream>>>(qkv, sa_pre);
  // 10) output projection
  pgemm<1,0,0><<<dim3(64,4), blk, 0, stream>>>(sa_pre, sa_pre, BIG, sowb, sob, sa, 256);
  // 11) LN2
  ln_k<2><<<dim3(4096), blk, 0, stream>>>(t1, sa, nullptr, ln2w, ln2b, t2, t2b, nullptr);
  // 12) FFN
  pgemm<1,1,1><<<dim3(64,32), blk, 0, stream>>>(t2b, t2b, BIG, f1wb, f1bs, h1, 2048);
  pgemm<8,0,0><<<dim3(64,4), blk, 0, stream>>>(h1, h1, BIG, f2wb, f2bs, ff, 256);
  // 13) LN3 -> output (n-major)
  ln_k<3><<<dim3(4096), blk, 0, stream>>>(t2, ff, nullptr, ln3w, ln3b, (float*)d_out, nullptr, nullptr);
}

// Round 7
// 447.143 us; speedup vs baseline: 1.8823x; 1.0130x over previous
//
#include <hip/hip_runtime.h>
#include <math.h>

typedef unsigned short u16;
typedef unsigned int u32;
typedef __bf16 bf16x8 __attribute__((ext_vector_type(8)));
typedef float f32x4 __attribute__((ext_vector_type(4)));

#define NPQ 512
#define MNP 4096
#define BSZ 8
#define DIM 256
#define NH 8
#define HD 32
#define TOPK 32
#define FFD 2048
#define SCALE 0.17677669529663687f  // 1/sqrt(32)

__device__ __forceinline__ u16 f2bf(float f){
  u32 u = __builtin_bit_cast(u32, f);
  u = (u + 0x7FFFu + ((u >> 16) & 1u)) >> 16;
  return (u16)u;
}
__device__ __forceinline__ float bf2f(u16 h){
  u32 u = ((u32)h) << 16;
  return __builtin_bit_cast(float, u);
}
__device__ __forceinline__ float wredsum(float v){
#pragma unroll
  for (int m = 32; m; m >>= 1) v += __shfl_xor(v, m, 64);
  return v;
}
__device__ __forceinline__ float gelu_exact(float x){
  return 0.5f * x * (1.0f + erff(x * 0.70710678118654752f));
}
__device__ __forceinline__ u32 keytr(u32 u){
  return u ^ (((u32)((int)u >> 31)) | 0x80000000u);
}

// ---------------- fp32 -> bf16 convert, all weights in one launch --------
__global__ __launch_bounds__(256)
void cvt_all(const float* __restrict__ s0, const float* __restrict__ s1,
             const float* __restrict__ s2, const float* __restrict__ s3,
             const float* __restrict__ s4, const float* __restrict__ s5,
             const float* __restrict__ s6, u16* __restrict__ dst){
  int i = blockIdx.x*256 + threadIdx.x;
  if (i >= 1507328) return;
  const float* s; int base;
  if      (i <  65536){ s = s0; base = 0; }
  else if (i < 131072){ s = s1; base = 65536; }
  else if (i < 196608){ s = s2; base = 131072; }
  else if (i < 393216){ s = s3; base = 196608; }
  else if (i < 458752){ s = s4; base = 393216; }
  else if (i < 983040){ s = s5; base = 458752; }
  else                { s = s6; base = 983040; }
  dst[i] = f2bf(s[i - base]);
}

// ---------------- prep: normalize + split + pos-add ----------------
__global__ __launch_bounds__(256)
void prep_tgt(const float* __restrict__ tgt, const float* __restrict__ qpos,
              u16* __restrict__ xnh, u16* __restrict__ xnl, u16* __restrict__ qc,
              const float* __restrict__ cb2, const float* __restrict__ cb3,
              float* __restrict__ cbKV){
  __shared__ float sc[4];
  int r = blockIdx.x, t = threadIdx.x;
  if (r == 0){ cbKV[t] = cb2[t]; cbKV[256 + t] = cb3[t]; }
  int b = r >> 9, n = r & 511;
  long src = ((long)n*BSZ + b)*DIM + t;
  float x = tgt[src];
  float s = wredsum(x*x);
  if ((t & 63) == 0) sc[t >> 6] = s;
  __syncthreads();
  float tot = sc[0]+sc[1]+sc[2]+sc[3];
  float xn = x / sqrtf(tot);
  u16 hi = f2bf(xn);
  long dst = (long)r*DIM + t;
  xnh[dst] = hi;
  xnl[dst] = f2bf(xn - bf2f(hi));
  qc[dst]  = f2bf(x + qpos[src]);
}

__global__ __launch_bounds__(256)
void prep_mem(const float* __restrict__ mem, const float* __restrict__ kpos,
              u16* __restrict__ mnh, u16* __restrict__ mnl,
              u16* __restrict__ kc, u16* __restrict__ vc){
  __shared__ float sc[4];
  int r = blockIdx.x, t = threadIdx.x;
  int b = r >> 12, mp = r & 4095;
  long src = ((long)mp*BSZ + b)*DIM + t;
  float x = mem[src];
  float s = wredsum(x*x);
  if ((t & 63) == 0) sc[t >> 6] = s;
  __syncthreads();
  float tot = sc[0]+sc[1]+sc[2]+sc[3];
  float xn = x / sqrtf(tot);
  u16 hi = f2bf(xn);
  long dst = (long)r*DIM + t;
  mnh[dst] = hi;
  mnl[dst] = f2bf(xn - bf2f(hi));
  kc[dst]  = f2bf(x + kpos[src]);
  vc[dst]  = f2bf(x);
}

// ---------------- sim GEMM (split bf16, LDS-staged B) ----------------
// grid (32, 4, 8): x = N-tile, y = M-tile so the 4 blocks sharing a B-tile
// (y=0..3, linear stride 32 == 0 mod 8) land on the SAME XCD -> L2 reuse.
#define BST 136
__global__ __launch_bounds__(256, 2)
void sim_gemm(const u16* __restrict__ xnh, const u16* __restrict__ xnl,
              const u16* __restrict__ mnh, const u16* __restrict__ mnl,
              float* __restrict__ sim){
  __shared__ __align__(16) u16 Bh[128*BST];
  __shared__ __align__(16) u16 Bl[128*BST];
  int t = threadIdx.x, lane = t & 63, wv = t >> 6;
  int ml = lane & 15, quad = lane >> 4;
  int b = blockIdx.z;
  int tM = blockIdx.y * 128 + (wv & 1) * 64;
  int tN = blockIdx.x * 128;
  int nloc = (wv >> 1) * 64;
  const u16* Ah = xnh + ((long)b*NPQ + tM + ml)*DIM;
  const u16* Al = xnl + ((long)b*NPQ + tM + ml)*DIM;
  f32x4 acc[4][4];
  f32x4 zer = {0.f,0.f,0.f,0.f};
#pragma unroll
  for (int i = 0; i < 4; i++)
#pragma unroll
    for (int j = 0; j < 4; j++) acc[i][j] = zer;

  int srow = t >> 4, scg = t & 15;
  for (int half = 0; half < 2; half++){
    int k0 = half * 128;
    if (half) __syncthreads();
#pragma unroll
    for (int p = 0; p < 8; p++){
      int r = p*16 + srow;
      long g = ((long)b*MNP + tN + r)*DIM + k0 + scg*8;
      *(uint4*)(&Bh[r*BST + scg*8]) = *(const uint4*)(mnh + g);
      *(uint4*)(&Bl[r*BST + scg*8]) = *(const uint4*)(mnl + g);
    }
    // prefetch first A fragments while B staging lands
    bf16x8 ca[4], ca2[4], na[4], na2[4];
#pragma unroll
    for (int i = 0; i < 4; i++){
      ca[i]  = *(const bf16x8*)(Ah + (long)i*16*DIM + k0 + quad*8);
      ca2[i] = *(const bf16x8*)(Al + (long)i*16*DIM + k0 + quad*8);
    }
    __syncthreads();
#pragma unroll
    for (int kk = 0; kk < 128; kk += 32){
      if (kk < 96){
#pragma unroll
        for (int i = 0; i < 4; i++){
          na[i]  = *(const bf16x8*)(Ah + (long)i*16*DIM + k0 + kk + 32 + quad*8);
          na2[i] = *(const bf16x8*)(Al + (long)i*16*DIM + k0 + kk + 32 + quad*8);
        }
      }
      bf16x8 bh[4], bl[4];
#pragma unroll
      for (int j = 0; j < 4; j++){
        int nr = nloc + j*16 + ml;
        bh[j] = *(const bf16x8*)(&Bh[nr*BST + kk + quad*8]);
        bl[j] = *(const bf16x8*)(&Bl[nr*BST + kk + quad*8]);
      }
#pragma unroll
      for (int i = 0; i < 4; i++)
#pragma unroll
        for (int j = 0; j < 4; j++){
          acc[i][j] = __builtin_amdgcn_mfma_f32_16x16x32_bf16(ca[i],  bh[j], acc[i][j], 0, 0, 0);
          acc[i][j] = __builtin_amdgcn_mfma_f32_16x16x32_bf16(ca[i],  bl[j], acc[i][j], 0, 0, 0);
          acc[i][j] = __builtin_amdgcn_mfma_f32_16x16x32_bf16(ca2[i], bh[j], acc[i][j], 0, 0, 0);
        }
#pragma unroll
      for (int i = 0; i < 4; i++){ ca[i] = na[i]; ca2[i] = na2[i]; }
    }
  }
  long zC = (long)b * NPQ * MNP;
#pragma unroll
  for (int i = 0; i < 4; i++)
#pragma unroll
    for (int r = 0; r < 4; r++){
      int row = tM + i*16 + quad*4 + r;
#pragma unroll
      for (int j = 0; j < 4; j++){
        int col = tN + nloc + j*16 + ml;
        sim[zC + (long)row*MNP + col] = acc[i][j][r];
      }
    }
}

// ---------------- projection GEMM (latency-optimized skinny shapes) ----
#define PBST 264
template<int KGROUPS, int OUT_BF16, int ACT>
__global__ __launch_bounds__(256)
void pgemm(const u16* __restrict__ A, const u16* __restrict__ A2, int selCol,
           const u16* __restrict__ B, const float* __restrict__ bias,
           void* __restrict__ Cv, int N){
  __shared__ __align__(16) u16 Bs[64*PBST];
  const int K = KGROUPS*256;
  int t = threadIdx.x, lane = t & 63, wv = t >> 6;
  int ml = lane & 15, quad = lane >> 4;
  int tM = blockIdx.x*64;
  int tN = blockIdx.y*64;
  const u16* Ab = (tN < selCol) ? A : A2;
  const u16* Arow = Ab + (long)(tM + wv*16 + ml)*K;
  f32x4 acc[4];
  f32x4 zer = {0.f,0.f,0.f,0.f};
#pragma unroll
  for (int nj = 0; nj < 4; nj++) acc[nj] = zer;
  int srow = t >> 5, scol = (t & 31)*8;
  for (int g = 0; g < KGROUPS; g++){
    if (g) __syncthreads();
#pragma unroll
    for (int p = 0; p < 8; p++){
      int r = p*8 + srow;
      *(uint4*)(&Bs[r*PBST + scol]) = *(const uint4*)(B + (long)(tN + r)*K + g*256 + scol);
    }
    bf16x8 a[8];
#pragma unroll
    for (int kk = 0; kk < 8; kk++)
      a[kk] = *(const bf16x8*)(Arow + g*256 + kk*32 + quad*8);
    __syncthreads();
#pragma unroll
    for (int kk = 0; kk < 8; kk++){
#pragma unroll
      for (int nj = 0; nj < 4; nj++){
        bf16x8 bv = *(const bf16x8*)(&Bs[(nj*16 + ml)*PBST + kk*32 + quad*8]);
        acc[nj] = __builtin_amdgcn_mfma_f32_16x16x32_bf16(a[kk], bv, acc[nj], 0, 0, 0);
      }
    }
  }
#pragma unroll
  for (int nj = 0; nj < 4; nj++){
    int col = tN + nj*16 + ml;
    float bv = bias[col];
#pragma unroll
    for (int r = 0; r < 4; r++){
      int row = tM + wv*16 + quad*4 + r;
      float v = acc[nj][r] + bv;
      if (ACT == 1) v = gelu_exact(v);
      long idx = (long)row * N + col;
      if (OUT_BF16) ((u16*)Cv)[idx] = f2bf(v);
      else ((float*)Cv)[idx] = v;
    }
  }
}

// ---------------- top-k: per-wave ballot bit-descent (no barriers) -------
// One wave per row; 64 keys/lane in VGPRs; counts via v_cmp+ballot+s_bcnt1
// (scalar pipe). Only the SET of indices matters downstream; ties at the
// threshold resolved to smallest indices (jax.lax.top_k semantics).
__global__ __launch_bounds__(256)
void topk_k(const float* __restrict__ sim, int* __restrict__ rns){
  __shared__ int scnt[4];
  __shared__ int stcnt[4];
  __shared__ int sties[4][64];
  int t = threadIdx.x, lane = t & 63, wv = t >> 6;
  int r = blockIdx.x*4 + wv;
  const uint4* row4 = (const uint4*)(sim + (long)r * 4096);
  u32 key[64];
#pragma unroll
  for (int j = 0; j < 16; j++){
    uint4 v = row4[j*64 + lane];
    key[j*4+0] = keytr(v.x);
    key[j*4+1] = keytr(v.y);
    key[j*4+2] = keytr(v.z);
    key[j*4+3] = keytr(v.w);
  }
  if (lane == 0){ scnt[wv] = 0; stcnt[wv] = 0; }
  u32 pref = 0;
#pragma unroll 1
  for (int bit = 31; bit >= 0; bit--){
    u32 cand = pref | (1u << bit);
    int cnt = 0;
#pragma unroll
    for (int i = 0; i < 64; i++)
      cnt += (int)__popcll(__ballot(key[i] >= cand));
    if (cnt >= TOPK) pref = cand;
  }
  int cg = 0;
#pragma unroll
  for (int i = 0; i < 64; i++)
    cg += (int)__popcll(__ballot(key[i] > pref));
  int k_rem = TOPK - cg;     // >= 1 by construction
  int* out = rns + (long)r * 32;
#pragma unroll
  for (int i = 0; i < 64; i++){
    int gidx = (i >> 2)*256 + lane*4 + (i & 3);
    if (key[i] > pref){
      int p = atomicAdd(&scnt[wv], 1);
      out[p] = gidx;
    } else if (key[i] == pref){
      int p = atomicAdd(&stcnt[wv], 1);
      if (p < 64) sties[wv][p] = gidx;
    }
  }
  // wave-lockstep: all DS atomics above precede these reads in program order
  if (lane == 0){
    int n = stcnt[wv]; if (n > 64) n = 64;
    for (int s = 0; s < k_rem; s++){
      int mb = 0;
      for (int j = 1; j < n; j++) if (sties[wv][j] < sties[wv][mb]) mb = j;
      out[cg + s] = sties[wv][mb];
      sties[wv][mb] = 0x7FFFFFFF;
    }
  }
}

// ---------------- sparse gathered cross-attention ----------------
// khvh layout: [32768][512], K at col 0..255, V at col 256..511
#define CAS 272
__global__ __launch_bounds__(256)
void cross_attn(const u16* __restrict__ qh, const u16* __restrict__ khvh,
                const int* __restrict__ rns, float* __restrict__ crossO){
  __shared__ __align__(16) u16 Kg[32*CAS];
  __shared__ __align__(16) u16 Vg[32*CAS];
  __shared__ float qv[256];
  __shared__ int idxs[32];
  __shared__ float L[256];
  __shared__ float pm[8], ps[8];
  int r = blockIdx.x, t = threadIdx.x;
  int b = r >> 9;
  if (t < 32) idxs[t] = rns[(long)r*32 + t];
  qv[t] = bf2f(qh[(long)r*DIM + t]);
  __syncthreads();
  for (int i = t; i < 32*64; i += 256){
    int k = i >> 6, c = (i & 63) * 4;
    long src = ((long)b*MNP + idxs[k])*512 + c;
    *(ushort4*)(&Kg[k*CAS + c]) = *(const ushort4*)(khvh + src);
    *(ushort4*)(&Vg[k*CAS + c]) = *(const ushort4*)(khvh + src + 256);
  }
  __syncthreads();
  {
    int h = t >> 5, k = t & 31;
    float acc = 0.f;
#pragma unroll
    for (int d = 0; d < 32; d++) acc += qv[h*HD + d] * bf2f(Kg[k*CAS + h*HD + d]);
    L[t] = acc * SCALE;
  }
  __syncthreads();
  if (t < 8){
    float m = L[t*32];
    for (int k = 1; k < 32; k++) m = fmaxf(m, L[t*32 + k]);
    float s = 0.f;
    for (int k = 0; k < 32; k++) s += expf(L[t*32 + k] - m);
    pm[t] = m; ps[t] = s;
  }
  __syncthreads();
  {
    int h = t >> 5, dd = t & 31;
    float m = pm[h], inv = 1.0f/ps[h], acc = 0.f;
#pragma unroll
    for (int k = 0; k < 32; k++) acc += expf(L[h*32 + k] - m) * bf2f(Vg[k*CAS + h*HD + dd]);
    crossO[(long)r*DIM + t] = acc * inv;
  }
}

// ---------------- fused layernorms ----------------
template<int MODE>
__global__ __launch_bounds__(256)
void ln_k(const float* __restrict__ xa, const float* __restrict__ xb,
          const float* __restrict__ qpos,
          const float* __restrict__ w, const float* __restrict__ bsh,
          float* __restrict__ yf, u16* __restrict__ yb, u16* __restrict__ qkb){
  __shared__ float sc[8];
  int r = blockIdx.x, t = threadIdx.x;
  int b = r >> 9, n = r & 511;
  long bidx = (long)r*DIM + t;
  long nidx = ((long)n*BSZ + b)*DIM + t;
  float x = (MODE == 1 ? xa[nidx] : xa[bidx]) + xb[bidx];
  float s  = wredsum(x);
  float s2 = wredsum(x*x);
  int wv = t >> 6;
  if ((t & 63) == 0){ sc[wv] = s; sc[4 + wv] = s2; }
  __syncthreads();
  float S  = sc[0]+sc[1]+sc[2]+sc[3];
  float S2 = sc[4]+sc[5]+sc[6]+sc[7];
  float mu  = S * (1.f/256.f);
  float var = S2 * (1.f/256.f) - mu*mu;
  float y = (x - mu) * (1.0f / sqrtf(var + 1e-5f)) * w[t] + bsh[t];
  if (MODE == 3){
    yf[nidx] = y;
  } else {
    yf[bidx] = y;
    yb[bidx] = f2bf(y);
    if (MODE == 1) qkb[bidx] = f2bf(y + qpos[nidx]);
  }
}

// ---------------- fused dense self-attention (MFMA) ----------------
// qkv layout: [4096][768], q at 0, k at 256, v at 512.
#define KST 40
#define PST 264
__global__ __launch_bounds__(256)
void self_attn(const u16* __restrict__ qkv, u16* __restrict__ sa_pre){
  __shared__ __align__(16) u16 KS[512*KST];
  __shared__ __align__(16) u16 QS[32*KST];
  __shared__ float mbuf[128];
  __shared__ float sbuf[128];
  u16* P  = KS;
  u16* Vt = KS + 32*PST;

  int qt = blockIdx.x, h = blockIdx.y, b = blockIdx.z;
  int t = threadIdx.x, lane = t & 63, wv = t >> 6;
  int ml = lane & 15, quad = lane >> 4;
  int n0 = qt * 32;

  {
    int q = t >> 3, d4 = (t & 7) * 4;
    const u16* src = qkv + ((long)b*NPQ + n0 + q)*768 + h*HD + d4;
    *(ushort2*)(QS + q*KST + d4)     = *(const ushort2*)(src);
    *(ushort2*)(QS + q*KST + d4 + 2) = *(const ushort2*)(src + 2);
  }
  for (int i = t; i < 512*8; i += 256){
    int j = i >> 3, d4 = (i & 7) * 4;
    const u16* src = qkv + ((long)b*NPQ + j)*768 + 256 + h*HD + d4;
    *(ushort2*)(KS + j*KST + d4)     = *(const ushort2*)(src);
    *(ushort2*)(KS + j*KST + d4 + 2) = *(const ushort2*)(src + 2);
  }
  __syncthreads();

  f32x4 acc[2][8];
  {
    bf16x8 aq[2];
#pragma unroll
    for (int mi = 0; mi < 2; mi++)
      aq[mi] = *(const bf16x8*)(QS + (mi*16 + ml)*KST + quad*8);
#pragma unroll
    for (int nj = 0; nj < 8; nj++){
      bf16x8 bk = *(const bf16x8*)(KS + (wv*128 + nj*16 + ml)*KST + quad*8);
      f32x4 z = {0.f,0.f,0.f,0.f};
#pragma unroll
      for (int mi = 0; mi < 2; mi++)
        acc[mi][nj] = __builtin_amdgcn_mfma_f32_16x16x32_bf16(aq[mi], bk, z, 0, 0, 0);
    }
  }
  float lmax[2][4];
#pragma unroll
  for (int mi = 0; mi < 2; mi++)
#pragma unroll
    for (int r = 0; r < 4; r++) lmax[mi][r] = -3.4e38f;
#pragma unroll
  for (int mi = 0; mi < 2; mi++)
#pragma unroll
    for (int nj = 0; nj < 8; nj++)
#pragma unroll
      for (int r = 0; r < 4; r++){
        float v = acc[mi][nj][r] * SCALE;
        acc[mi][nj][r] = v;
        lmax[mi][r] = fmaxf(lmax[mi][r], v);
      }
#pragma unroll
  for (int m = 1; m < 16; m <<= 1)
#pragma unroll
    for (int mi = 0; mi < 2; mi++)
#pragma unroll
      for (int r = 0; r < 4; r++)
        lmax[mi][r] = fmaxf(lmax[mi][r], __shfl_xor(lmax[mi][r], m, 64));
  if (ml == 0){
#pragma unroll
    for (int mi = 0; mi < 2; mi++)
#pragma unroll
      for (int r = 0; r < 4; r++)
        mbuf[(mi*16 + quad*4 + r)*4 + wv] = lmax[mi][r];
  }
  __syncthreads();
  float inv_[2][4];
  float lsum[2][4];
#pragma unroll
  for (int mi = 0; mi < 2; mi++)
#pragma unroll
    for (int r = 0; r < 4; r++){
      int row = mi*16 + quad*4 + r;
      float m0 = fmaxf(fmaxf(mbuf[row*4+0], mbuf[row*4+1]),
                       fmaxf(mbuf[row*4+2], mbuf[row*4+3]));
      float s = 0.f;
#pragma unroll
      for (int nj = 0; nj < 8; nj++){
        float e = __expf(acc[mi][nj][r] - m0);
        acc[mi][nj][r] = e;
        s += e;
      }
      lsum[mi][r] = s;
    }
#pragma unroll
  for (int m = 1; m < 16; m <<= 1)
#pragma unroll
    for (int mi = 0; mi < 2; mi++)
#pragma unroll
      for (int r = 0; r < 4; r++)
        lsum[mi][r] += __shfl_xor(lsum[mi][r], m, 64);
  if (ml == 0){
#pragma unroll
    for (int mi = 0; mi < 2; mi++)
#pragma unroll
      for (int r = 0; r < 4; r++)
        sbuf[(mi*16 + quad*4 + r)*4 + wv] = lsum[mi][r];
  }
  __syncthreads();
#pragma unroll
  for (int mi = 0; mi < 2; mi++)
#pragma unroll
    for (int r = 0; r < 4; r++){
      int row = mi*16 + quad*4 + r;
      inv_[mi][r] = 1.0f / (sbuf[row*4+0]+sbuf[row*4+1]+sbuf[row*4+2]+sbuf[row*4+3]);
    }

  int mi2 = wv >> 1, ni = wv & 1;
  f32x4 acc2 = {0.f,0.f,0.f,0.f};
  for (int half = 0; half < 2; half++){
    __syncthreads();
    if ((wv >> 1) == half){
      int cbase = (wv & 1) * 128;
#pragma unroll
      for (int mi = 0; mi < 2; mi++)
#pragma unroll
        for (int nj = 0; nj < 8; nj++)
#pragma unroll
          for (int r = 0; r < 4; r++)
            P[(mi*16 + quad*4 + r)*PST + cbase + nj*16 + ml] = f2bf(acc[mi][nj][r]);
    }
    for (int i = t; i < 2048; i += 256){
      int j = i >> 3, d4 = (i & 7) * 4;
      const u16* src = qkv + ((long)b*NPQ + half*256 + j)*768 + 512 + h*HD + d4;
      u16 v0 = src[0], v1 = src[1], v2e = src[2], v3 = src[3];
      Vt[(d4+0)*PST + j] = v0;
      Vt[(d4+1)*PST + j] = v1;
      Vt[(d4+2)*PST + j] = v2e;
      Vt[(d4+3)*PST + j] = v3;
    }
    __syncthreads();
#pragma unroll
    for (int k0 = 0; k0 < 256; k0 += 32){
      bf16x8 ap = *(const bf16x8*)(P  + (mi2*16 + ml)*PST + k0 + quad*8);
      bf16x8 bv = *(const bf16x8*)(Vt + (ni*16  + ml)*PST + k0 + quad*8);
      acc2 = __builtin_amdgcn_mfma_f32_16x16x32_bf16(ap, bv, acc2, 0, 0, 0);
    }
  }
#pragma unroll
  for (int r = 0; r < 4; r++){
    int row = mi2*16 + quad*4 + r;
    sa_pre[((long)b*NPQ + n0 + row)*DIM + h*HD + ni*16 + ml] =
        f2bf(acc2[r] * inv_[mi2][r]);
  }
}

// =====================================================================
extern "C" void kernel_launch(void* const* d_in, const int* in_sizes, int n_in,
                              void* d_out, int out_size, void* d_ws, size_t ws_size,
                              hipStream_t stream){
  (void)in_sizes; (void)n_in; (void)out_size; (void)ws_size;
  const float* tgt  = (const float*)d_in[0];
  const float* mem  = (const float*)d_in[1];
  const float* qpos = (const float*)d_in[2];
  const float* kpos = (const float*)d_in[3];
  const float* cw1  = (const float*)d_in[4];  const float* cb1 = (const float*)d_in[5];
  const float* cw2  = (const float*)d_in[6];  const float* cb2 = (const float*)d_in[7];
  const float* cw3  = (const float*)d_in[8];  const float* cb3 = (const float*)d_in[9];
  const float* saw  = (const float*)d_in[10]; const float* sab = (const float*)d_in[11];
  const float* sow  = (const float*)d_in[12]; const float* sob = (const float*)d_in[13];
  const float* ln1w = (const float*)d_in[14]; const float* ln1b = (const float*)d_in[15];
  const float* ln2w = (const float*)d_in[16]; const float* ln2b = (const float*)d_in[17];
  const float* ln3w = (const float*)d_in[18]; const float* ln3b = (const float*)d_in[19];
  const float* f1w  = (const float*)d_in[20]; const float* f1bs = (const float*)d_in[21];
  const float* f2w  = (const float*)d_in[22]; const float* f2bs = (const float*)d_in[23];

  char* base = (char*)d_ws;
  size_t off = 0;
  auto alloc = [&](size_t bytes) -> char* {
    char* p = base + off;
    off += (bytes + 255) & ~(size_t)255;
    return p;
  };
  u16* cw1b = (u16*)alloc(65536u*2);
  u16* cw2b = (u16*)alloc(65536u*2);
  u16* cw3b = (u16*)alloc(65536u*2);   (void)cw3b;
  u16* sawb = (u16*)alloc(196608u*2);
  u16* sowb = (u16*)alloc(65536u*2);
  u16* f1wb = (u16*)alloc(524288u*2);
  u16* f2wb = (u16*)alloc(524288u*2);
  int* rns  = (int*)alloc(4096u*32*4);
  float* cbKV = (float*)alloc(512*4);
  size_t offB = off;
  u16* xnh = (u16*)alloc((size_t)4096*256*2);
  u16* xnl = (u16*)alloc((size_t)4096*256*2);
  u16* mnh = (u16*)alloc((size_t)32768*256*2);
  u16* mnl = (u16*)alloc((size_t)32768*256*2);
  u16* qc  = (u16*)alloc((size_t)4096*256*2);
  u16* kc  = (u16*)alloc((size_t)32768*256*2);
  u16* vc  = (u16*)alloc((size_t)32768*256*2);
  float* sim = (float*)alloc((size_t)8*512*4096*4);

  char* regC = (char*)sim;
  u16* qh   = (u16*)regC;                      // [4096][256]  2 MB
  u16* khvh = (u16*)(regC + 2097152);          // [32768][512] 32 MB
  char* regB = base + offB;
  size_t ob = 0;
  auto allocB = [&](size_t bytes) -> char* {
    char* p = regB + ob;
    ob += (bytes + 255) & ~(size_t)255;
    return p;
  };
  float* cross = (float*)allocB((size_t)4096*256*4);
  float* t1    = (float*)allocB((size_t)4096*256*4);
  u16*   t1b   = (u16*)allocB((size_t)4096*256*2);
  u16*   qkb   = (u16*)allocB((size_t)4096*256*2);
  u16*   qkv   = (u16*)allocB((size_t)4096*768*2);
  u16*   sa_pre= (u16*)allocB((size_t)4096*256*2);
  float* sa    = (float*)allocB((size_t)4096*256*4);
  float* t2    = (float*)allocB((size_t)4096*256*4);
  u16*   t2b   = (u16*)allocB((size_t)4096*256*2);
  u16*   h1    = (u16*)allocB((size_t)4096*2048*2);
  float* ff    = (float*)allocB((size_t)4096*256*4);

  const int BIG = 1 << 30;
  dim3 blk(256);
  cvt_all<<<dim3((1507328 + 255)/256), blk, 0, stream>>>(
      cw1, cw2, cw3, saw, sow, f1w, f2w, cw1b);
  prep_tgt<<<dim3(4096), blk, 0, stream>>>(tgt, qpos, xnh, xnl, qc, cb2, cb3, cbKV);
  prep_mem<<<dim3(32768), blk, 0, stream>>>(mem, kpos, mnh, mnl, kc, vc);
  sim_gemm<<<dim3(32,4,8), blk, 0, stream>>>(xnh, xnl, mnh, mnl, sim);
  topk_k<<<dim3(1024), blk, 0, stream>>>(sim, rns);
  pgemm<1,1,0><<<dim3(64,4), blk, 0, stream>>>(qc, qc, BIG, cw1b, cb1, qh, 256);
  pgemm<1,1,0><<<dim3(512,8), blk, 0, stream>>>(kc, vc, 256, cw2b, cbKV, khvh, 512);
  cross_attn<<<dim3(4096), blk, 0, stream>>>(qh, khvh, rns, cross);
  ln_k<1><<<dim3(4096), blk, 0, stream>>>(tgt, cross, qpos, ln1w, ln1b, t1, t1b, qkb);
  pgemm<1,1,0><<<dim3(64,12), blk, 0, stream>>>(qkb, t1b, 512, sawb, sab, qkv, 768);
  self_attn<<<dim3(16,8,8), blk, 0, stream>>>(qkv, sa_pre);
  pgemm<1,0,0><<<dim3(64,4), blk, 0, stream>>>(sa_pre, sa_pre, BIG, sowb, sob, sa, 256);
  ln_k<2><<<dim3(4096), blk, 0, stream>>>(t1, sa, nullptr, ln2w, ln2b, t2, t2b, nullptr);
  pgemm<1,1,1><<<dim3(64,32), blk, 0, stream>>>(t2b, t2b, BIG, f1wb, f1bs, h1, 2048);
  pgemm<8,0,0><<<dim3(64,4), blk, 0, stream>>>(h1, h1, BIG, f2wb, f2bs, ff, 256);
  ln_k<3><<<dim3(4096), blk, 0, stream>>>(t2, ff, nullptr, ln3w, ln3b, (float*)d_out, nullptr, nullptr);
}

// Round 8
// 442.038 us; speedup vs baseline: 1.9041x; 1.0115x over previous
//
#include <hip/hip_runtime.h>
#include <math.h>

typedef unsigned short u16;
typedef unsigned int u32;
typedef __bf16 bf16x8 __attribute__((ext_vector_type(8)));
typedef float f32x4 __attribute__((ext_vector_type(4)));

#define NPQ 512
#define MNP 4096
#define BSZ 8
#define DIM 256
#define NH 8
#define HD 32
#define TOPK 32
#define FFD 2048
#define SCALE 0.17677669529663687f  // 1/sqrt(32)

__device__ __forceinline__ u16 f2bf(float f){
  u32 u = __builtin_bit_cast(u32, f);
  u = (u + 0x7FFFu + ((u >> 16) & 1u)) >> 16;
  return (u16)u;
}
__device__ __forceinline__ float bf2f(u16 h){
  u32 u = ((u32)h) << 16;
  return __builtin_bit_cast(float, u);
}
__device__ __forceinline__ float wredsum(float v){
#pragma unroll
  for (int m = 32; m; m >>= 1) v += __shfl_xor(v, m, 64);
  return v;
}
__device__ __forceinline__ float gelu_exact(float x){
  return 0.5f * x * (1.0f + erff(x * 0.70710678118654752f));
}
__device__ __forceinline__ u32 keytr(u32 u){
  return u ^ (((u32)((int)u >> 31)) | 0x80000000u);
}

// ---------------- fp32 -> bf16 convert, all weights in one launch --------
__global__ __launch_bounds__(256)
void cvt_all(const float* __restrict__ s0, const float* __restrict__ s1,
             const float* __restrict__ s2, const float* __restrict__ s3,
             const float* __restrict__ s4, const float* __restrict__ s5,
             const float* __restrict__ s6, u16* __restrict__ dst){
  int i = blockIdx.x*256 + threadIdx.x;
  if (i >= 1507328) return;
  const float* s; int base;
  if      (i <  65536){ s = s0; base = 0; }
  else if (i < 131072){ s = s1; base = 65536; }
  else if (i < 196608){ s = s2; base = 131072; }
  else if (i < 393216){ s = s3; base = 196608; }
  else if (i < 458752){ s = s4; base = 393216; }
  else if (i < 983040){ s = s5; base = 458752; }
  else                { s = s6; base = 983040; }
  dst[i] = f2bf(s[i - base]);
}

// ---------------- prep: normalize + split + pos-add ----------------
__global__ __launch_bounds__(256)
void prep_tgt(const float* __restrict__ tgt, const float* __restrict__ qpos,
              u16* __restrict__ xnh, u16* __restrict__ xnl, u16* __restrict__ qc,
              const float* __restrict__ cb2, const float* __restrict__ cb3,
              float* __restrict__ cbKV){
  __shared__ float sc[4];
  int r = blockIdx.x, t = threadIdx.x;
  if (r == 0){ cbKV[t] = cb2[t]; cbKV[256 + t] = cb3[t]; }
  int b = r >> 9, n = r & 511;
  long src = ((long)n*BSZ + b)*DIM + t;
  float x = tgt[src];
  float s = wredsum(x*x);
  if ((t & 63) == 0) sc[t >> 6] = s;
  __syncthreads();
  float tot = sc[0]+sc[1]+sc[2]+sc[3];
  float xn = x / sqrtf(tot);
  u16 hi = f2bf(xn);
  long dst = (long)r*DIM + t;
  xnh[dst] = hi;
  xnl[dst] = f2bf(xn - bf2f(hi));
  qc[dst]  = f2bf(x + qpos[src]);
}

__global__ __launch_bounds__(256)
void prep_mem(const float* __restrict__ mem, const float* __restrict__ kpos,
              u16* __restrict__ mnh, u16* __restrict__ mnl,
              u16* __restrict__ kc, u16* __restrict__ vc){
  __shared__ float sc[4];
  int r = blockIdx.x, t = threadIdx.x;
  int b = r >> 12, mp = r & 4095;
  long src = ((long)mp*BSZ + b)*DIM + t;
  float x = mem[src];
  float s = wredsum(x*x);
  if ((t & 63) == 0) sc[t >> 6] = s;
  __syncthreads();
  float tot = sc[0]+sc[1]+sc[2]+sc[3];
  float xn = x / sqrtf(tot);
  u16 hi = f2bf(xn);
  long dst = (long)r*DIM + t;
  mnh[dst] = hi;
  mnl[dst] = f2bf(xn - bf2f(hi));
  kc[dst]  = f2bf(x + kpos[src]);
  vc[dst]  = f2bf(x);
}

// ---------------- sim GEMM (split bf16, LDS-staged B) ----------------
#define BST 136
__global__ __launch_bounds__(256, 2)
void sim_gemm(const u16* __restrict__ xnh, const u16* __restrict__ xnl,
              const u16* __restrict__ mnh, const u16* __restrict__ mnl,
              float* __restrict__ sim){
  __shared__ __align__(16) u16 Bh[128*BST];
  __shared__ __align__(16) u16 Bl[128*BST];
  int t = threadIdx.x, lane = t & 63, wv = t >> 6;
  int ml = lane & 15, quad = lane >> 4;
  int b = blockIdx.z;
  int tM = blockIdx.y * 128 + (wv & 1) * 64;
  int tN = blockIdx.x * 128;
  int nloc = (wv >> 1) * 64;
  const u16* Ah = xnh + ((long)b*NPQ + tM + ml)*DIM;
  const u16* Al = xnl + ((long)b*NPQ + tM + ml)*DIM;
  f32x4 acc[4][4];
  f32x4 zer = {0.f,0.f,0.f,0.f};
#pragma unroll
  for (int i = 0; i < 4; i++)
#pragma unroll
    for (int j = 0; j < 4; j++) acc[i][j] = zer;

  int srow = t >> 4, scg = t & 15;
  for (int half = 0; half < 2; half++){
    int k0 = half * 128;
    if (half) __syncthreads();
#pragma unroll
    for (int p = 0; p < 8; p++){
      int r = p*16 + srow;
      long g = ((long)b*MNP + tN + r)*DIM + k0 + scg*8;
      *(uint4*)(&Bh[r*BST + scg*8]) = *(const uint4*)(mnh + g);
      *(uint4*)(&Bl[r*BST + scg*8]) = *(const uint4*)(mnl + g);
    }
    bf16x8 ca[4], ca2[4], na[4], na2[4];
#pragma unroll
    for (int i = 0; i < 4; i++){
      ca[i]  = *(const bf16x8*)(Ah + (long)i*16*DIM + k0 + quad*8);
      ca2[i] = *(const bf16x8*)(Al + (long)i*16*DIM + k0 + quad*8);
    }
    __syncthreads();
#pragma unroll
    for (int kk = 0; kk < 128; kk += 32){
      if (kk < 96){
#pragma unroll
        for (int i = 0; i < 4; i++){
          na[i]  = *(const bf16x8*)(Ah + (long)i*16*DIM + k0 + kk + 32 + quad*8);
          na2[i] = *(const bf16x8*)(Al + (long)i*16*DIM + k0 + kk + 32 + quad*8);
        }
      }
      bf16x8 bh[4], bl[4];
#pragma unroll
      for (int j = 0; j < 4; j++){
        int nr = nloc + j*16 + ml;
        bh[j] = *(const bf16x8*)(&Bh[nr*BST + kk + quad*8]);
        bl[j] = *(const bf16x8*)(&Bl[nr*BST + kk + quad*8]);
      }
#pragma unroll
      for (int i = 0; i < 4; i++)
#pragma unroll
        for (int j = 0; j < 4; j++){
          acc[i][j] = __builtin_amdgcn_mfma_f32_16x16x32_bf16(ca[i],  bh[j], acc[i][j], 0, 0, 0);
          acc[i][j] = __builtin_amdgcn_mfma_f32_16x16x32_bf16(ca[i],  bl[j], acc[i][j], 0, 0, 0);
          acc[i][j] = __builtin_amdgcn_mfma_f32_16x16x32_bf16(ca2[i], bh[j], acc[i][j], 0, 0, 0);
        }
#pragma unroll
      for (int i = 0; i < 4; i++){ ca[i] = na[i]; ca2[i] = na2[i]; }
    }
  }
  long zC = (long)b * NPQ * MNP;
#pragma unroll
  for (int i = 0; i < 4; i++)
#pragma unroll
    for (int r = 0; r < 4; r++){
      int row = tM + i*16 + quad*4 + r;
#pragma unroll
      for (int j = 0; j < 4; j++){
        int col = tN + nloc + j*16 + ml;
        sim[zC + (long)row*MNP + col] = acc[i][j][r];
      }
    }
}

// ---------------- projection GEMM (latency-optimized skinny shapes) ----
#define PBST 264
template<int KGROUPS, int OUT_BF16, int ACT>
__global__ __launch_bounds__(256)
void pgemm(const u16* __restrict__ A, const u16* __restrict__ A2, int selCol,
           const u16* __restrict__ B, const float* __restrict__ bias,
           void* __restrict__ Cv, int N){
  __shared__ __align__(16) u16 Bs[64*PBST];
  const int K = KGROUPS*256;
  int t = threadIdx.x, lane = t & 63, wv = t >> 6;
  int ml = lane & 15, quad = lane >> 4;
  int tM = blockIdx.x*64;
  int tN = blockIdx.y*64;
  const u16* Ab = (tN < selCol) ? A : A2;
  const u16* Arow = Ab + (long)(tM + wv*16 + ml)*K;
  f32x4 acc[4];
  f32x4 zer = {0.f,0.f,0.f,0.f};
#pragma unroll
  for (int nj = 0; nj < 4; nj++) acc[nj] = zer;
  int srow = t >> 5, scol = (t & 31)*8;
  for (int g = 0; g < KGROUPS; g++){
    if (g) __syncthreads();
#pragma unroll
    for (int p = 0; p < 8; p++){
      int r = p*8 + srow;
      *(uint4*)(&Bs[r*PBST + scol]) = *(const uint4*)(B + (long)(tN + r)*K + g*256 + scol);
    }
    bf16x8 a[8];
#pragma unroll
    for (int kk = 0; kk < 8; kk++)
      a[kk] = *(const bf16x8*)(Arow + g*256 + kk*32 + quad*8);
    __syncthreads();
#pragma unroll
    for (int kk = 0; kk < 8; kk++){
#pragma unroll
      for (int nj = 0; nj < 4; nj++){
        bf16x8 bv = *(const bf16x8*)(&Bs[(nj*16 + ml)*PBST + kk*32 + quad*8]);
        acc[nj] = __builtin_amdgcn_mfma_f32_16x16x32_bf16(a[kk], bv, acc[nj], 0, 0, 0);
      }
    }
  }
#pragma unroll
  for (int nj = 0; nj < 4; nj++){
    int col = tN + nj*16 + ml;
    float bv = bias[col];
#pragma unroll
    for (int r = 0; r < 4; r++){
      int row = tM + wv*16 + quad*4 + r;
      float v = acc[nj][r] + bv;
      if (ACT == 1) v = gelu_exact(v);
      long idx = (long)row * N + col;
      if (OUT_BF16) ((u16*)Cv)[idx] = f2bf(v);
      else ((float*)Cv)[idx] = v;
    }
  }
}

// ---------------- top-k: per-wave ballot bit-descent (no barriers) -------
// __launch_bounds__(256,4): 128-VGPR budget so key[64] stays REGISTER-
// resident (R7's (256) default gave 44 VGPRs -> keys re-read from cache
// every bit iteration; that was the 69us regression).
__global__ __launch_bounds__(256, 4)
void topk_k(const float* __restrict__ sim, int* __restrict__ rns){
  __shared__ int scnt[4];
  __shared__ int stcnt[4];
  __shared__ int sties[4][64];
  int t = threadIdx.x, lane = t & 63, wv = t >> 6;
  int r = blockIdx.x*4 + wv;
  const uint4* row4 = (const uint4*)(sim + (long)r * 4096);
  u32 key[64];
#pragma unroll
  for (int j = 0; j < 16; j++){
    uint4 v = row4[j*64 + lane];
    key[j*4+0] = keytr(v.x);
    key[j*4+1] = keytr(v.y);
    key[j*4+2] = keytr(v.z);
    key[j*4+3] = keytr(v.w);
  }
  if (lane == 0){ scnt[wv] = 0; stcnt[wv] = 0; }
  u32 pref = 0;
#pragma unroll 1
  for (int bit = 31; bit >= 0; bit--){
    u32 cand = pref | (1u << bit);
    int cnt = 0;
#pragma unroll
    for (int i = 0; i < 64; i++)
      cnt += (int)__popcll(__ballot(key[i] >= cand));
    if (cnt >= TOPK) pref = cand;
  }
  int cg = 0;
#pragma unroll
  for (int i = 0; i < 64; i++)
    cg += (int)__popcll(__ballot(key[i] > pref));
  int k_rem = TOPK - cg;     // >= 1 by construction
  int* out = rns + (long)r * 32;
#pragma unroll
  for (int i = 0; i < 64; i++){
    int gidx = (i >> 2)*256 + lane*4 + (i & 3);
    if (key[i] > pref){
      int p = atomicAdd(&scnt[wv], 1);
      out[p] = gidx;
    } else if (key[i] == pref){
      int p = atomicAdd(&stcnt[wv], 1);
      if (p < 64) sties[wv][p] = gidx;
    }
  }
  // wave-lockstep: all DS atomics above precede these reads in program order
  if (lane == 0){
    int n = stcnt[wv]; if (n > 64) n = 64;
    for (int s = 0; s < k_rem; s++){
      int mb = 0;
      for (int j = 1; j < n; j++) if (sties[wv][j] < sties[wv][mb]) mb = j;
      out[cg + s] = sties[wv][mb];
      sties[wv][mb] = 0x7FFFFFFF;
    }
  }
}

// ---------------- sparse gathered cross-attention ----------------
// khvh layout: [32768][512], K at col 0..255, V at col 256..511
#define CAS 272
__global__ __launch_bounds__(256)
void cross_attn(const u16* __restrict__ qh, const u16* __restrict__ khvh,
                const int* __restrict__ rns, float* __restrict__ crossO){
  __shared__ __align__(16) u16 Kg[32*CAS];
  __shared__ __align__(16) u16 Vg[32*CAS];
  __shared__ float qv[256];
  __shared__ int idxs[32];
  __shared__ float L[256];
  __shared__ float pm[8], ps[8];
  int r = blockIdx.x, t = threadIdx.x;
  int b = r >> 9;
  if (t < 32) idxs[t] = rns[(long)r*32 + t];
  qv[t] = bf2f(qh[(long)r*DIM + t]);
  __syncthreads();
  for (int i = t; i < 32*64; i += 256){
    int k = i >> 6, c = (i & 63) * 4;
    long src = ((long)b*MNP + idxs[k])*512 + c;
    *(ushort4*)(&Kg[k*CAS + c]) = *(const ushort4*)(khvh + src);
    *(ushort4*)(&Vg[k*CAS + c]) = *(const ushort4*)(khvh + src + 256);
  }
  __syncthreads();
  {
    int h = t >> 5, k = t & 31;
    float acc = 0.f;
#pragma unroll
    for (int d = 0; d < 32; d++) acc += qv[h*HD + d] * bf2f(Kg[k*CAS + h*HD + d]);
    L[t] = acc * SCALE;
  }
  __syncthreads();
  if (t < 8){
    float m = L[t*32];
    for (int k = 1; k < 32; k++) m = fmaxf(m, L[t*32 + k]);
    float s = 0.f;
    for (int k = 0; k < 32; k++) s += expf(L[t*32 + k] - m);
    pm[t] = m; ps[t] = s;
  }
  __syncthreads();
  {
    int h = t >> 5, dd = t & 31;
    float m = pm[h], inv = 1.0f/ps[h], acc = 0.f;
#pragma unroll
    for (int k = 0; k < 32; k++) acc += expf(L[h*32 + k] - m) * bf2f(Vg[k*CAS + h*HD + dd]);
    crossO[(long)r*DIM + t] = acc * inv;
  }
}

// ---------------- fused layernorms ----------------
template<int MODE>
__global__ __launch_bounds__(256)
void ln_k(const float* __restrict__ xa, const float* __restrict__ xb,
          const float* __restrict__ qpos,
          const float* __restrict__ w, const float* __restrict__ bsh,
          float* __restrict__ yf, u16* __restrict__ yb, u16* __restrict__ qkb){
  __shared__ float sc[8];
  int r = blockIdx.x, t = threadIdx.x;
  int b = r >> 9, n = r & 511;
  long bidx = (long)r*DIM + t;
  long nidx = ((long)n*BSZ + b)*DIM + t;
  float x = (MODE == 1 ? xa[nidx] : xa[bidx]) + xb[bidx];
  float s  = wredsum(x);
  float s2 = wredsum(x*x);
  int wv = t >> 6;
  if ((t & 63) == 0){ sc[wv] = s; sc[4 + wv] = s2; }
  __syncthreads();
  float S  = sc[0]+sc[1]+sc[2]+sc[3];
  float S2 = sc[4]+sc[5]+sc[6]+sc[7];
  float mu  = S * (1.f/256.f);
  float var = S2 * (1.f/256.f) - mu*mu;
  float y = (x - mu) * (1.0f / sqrtf(var + 1e-5f)) * w[t] + bsh[t];
  if (MODE == 3){
    yf[nidx] = y;
  } else {
    yf[bidx] = y;
    yb[bidx] = f2bf(y);
    if (MODE == 1) qkb[bidx] = f2bf(y + qpos[nidx]);
  }
}

// ---------------- fused dense self-attention (MFMA) ----------------
// qkv layout: [4096][768], q at 0, k at 256, v at 512.
#define KST 40
#define PST 264
__global__ __launch_bounds__(256)
void self_attn(const u16* __restrict__ qkv, u16* __restrict__ sa_pre){
  __shared__ __align__(16) u16 KS[512*KST];
  __shared__ __align__(16) u16 QS[32*KST];
  __shared__ float mbuf[128];
  __shared__ float sbuf[128];
  u16* P  = KS;
  u16* Vt = KS + 32*PST;

  int qt = blockIdx.x, h = blockIdx.y, b = blockIdx.z;
  int t = threadIdx.x, lane = t & 63, wv = t >> 6;
  int ml = lane & 15, quad = lane >> 4;
  int n0 = qt * 32;

  {
    int q = t >> 3, d4 = (t & 7) * 4;
    const u16* src = qkv + ((long)b*NPQ + n0 + q)*768 + h*HD + d4;
    *(ushort2*)(QS + q*KST + d4)     = *(const ushort2*)(src);
    *(ushort2*)(QS + q*KST + d4 + 2) = *(const ushort2*)(src + 2);
  }
  for (int i = t; i < 512*8; i += 256){
    int j = i >> 3, d4 = (i & 7) * 4;
    const u16* src = qkv + ((long)b*NPQ + j)*768 + 256 + h*HD + d4;
    *(ushort2*)(KS + j*KST + d4)     = *(const ushort2*)(src);
    *(ushort2*)(KS + j*KST + d4 + 2) = *(const ushort2*)(src + 2);
  }
  __syncthreads();

  f32x4 acc[2][8];
  {
    bf16x8 aq[2];
#pragma unroll
    for (int mi = 0; mi < 2; mi++)
      aq[mi] = *(const bf16x8*)(QS + (mi*16 + ml)*KST + quad*8);
#pragma unroll
    for (int nj = 0; nj < 8; nj++){
      bf16x8 bk = *(const bf16x8*)(KS + (wv*128 + nj*16 + ml)*KST + quad*8);
      f32x4 z = {0.f,0.f,0.f,0.f};
#pragma unroll
      for (int mi = 0; mi < 2; mi++)
        acc[mi][nj] = __builtin_amdgcn_mfma_f32_16x16x32_bf16(aq[mi], bk, z, 0, 0, 0);
    }
  }
  float lmax[2][4];
#pragma unroll
  for (int mi = 0; mi < 2; mi++)
#pragma unroll
    for (int r = 0; r < 4; r++) lmax[mi][r] = -3.4e38f;
#pragma unroll
  for (int mi = 0; mi < 2; mi++)
#pragma unroll
    for (int nj = 0; nj < 8; nj++)
#pragma unroll
      for (int r = 0; r < 4; r++){
        float v = acc[mi][nj][r] * SCALE;
        acc[mi][nj][r] = v;
        lmax[mi][r] = fmaxf(lmax[mi][r], v);
      }
#pragma unroll
  for (int m = 1; m < 16; m <<= 1)
#pragma unroll
    for (int mi = 0; mi < 2; mi++)
#pragma unroll
      for (int r = 0; r < 4; r++)
        lmax[mi][r] = fmaxf(lmax[mi][r], __shfl_xor(lmax[mi][r], m, 64));
  if (ml == 0){
#pragma unroll
    for (int mi = 0; mi < 2; mi++)
#pragma unroll
      for (int r = 0; r < 4; r++)
        mbuf[(mi*16 + quad*4 + r)*4 + wv] = lmax[mi][r];
  }
  __syncthreads();
  float inv_[2][4];
  float lsum[2][4];
#pragma unroll
  for (int mi = 0; mi < 2; mi++)
#pragma unroll
    for (int r = 0; r < 4; r++){
      int row = mi*16 + quad*4 + r;
      float m0 = fmaxf(fmaxf(mbuf[row*4+0], mbuf[row*4+1]),
                       fmaxf(mbuf[row*4+2], mbuf[row*4+3]));
      float s = 0.f;
#pragma unroll
      for (int nj = 0; nj < 8; nj++){
        float e = __expf(acc[mi][nj][r] - m0);
        acc[mi][nj][r] = e;
        s += e;
      }
      lsum[mi][r] = s;
    }
#pragma unroll
  for (int m = 1; m < 16; m <<= 1)
#pragma unroll
    for (int mi = 0; mi < 2; mi++)
#pragma unroll
      for (int r = 0; r < 4; r++)
        lsum[mi][r] += __shfl_xor(lsum[mi][r], m, 64);
  if (ml == 0){
#pragma unroll
    for (int mi = 0; mi < 2; mi++)
#pragma unroll
      for (int r = 0; r < 4; r++)
        sbuf[(mi*16 + quad*4 + r)*4 + wv] = lsum[mi][r];
  }
  __syncthreads();
#pragma unroll
  for (int mi = 0; mi < 2; mi++)
#pragma unroll
    for (int r = 0; r < 4; r++){
      int row = mi*16 + quad*4 + r;
      inv_[mi][r] = 1.0f / (sbuf[row*4+0]+sbuf[row*4+1]+sbuf[row*4+2]+sbuf[row*4+3]);
    }

  int mi2 = wv >> 1, ni = wv & 1;
  f32x4 acc2 = {0.f,0.f,0.f,0.f};
  for (int half = 0; half < 2; half++){
    __syncthreads();
    if ((wv >> 1) == half){
      int cbase = (wv & 1) * 128;
#pragma unroll
      for (int mi = 0; mi < 2; mi++)
#pragma unroll
        for (int nj = 0; nj < 8; nj++)
#pragma unroll
          for (int r = 0; r < 4; r++)
            P[(mi*16 + quad*4 + r)*PST + cbase + nj*16 + ml] = f2bf(acc[mi][nj][r]);
    }
    for (int i = t; i < 2048; i += 256){
      int j = i >> 3, d4 = (i & 7) * 4;
      const u16* src = qkv + ((long)b*NPQ + half*256 + j)*768 + 512 + h*HD + d4;
      u16 v0 = src[0], v1 = src[1], v2e = src[2], v3 = src[3];
      Vt[(d4+0)*PST + j] = v0;
      Vt[(d4+1)*PST + j] = v1;
      Vt[(d4+2)*PST + j] = v2e;
      Vt[(d4+3)*PST + j] = v3;
    }
    __syncthreads();
#pragma unroll
    for (int k0 = 0; k0 < 256; k0 += 32){
      bf16x8 ap = *(const bf16x8*)(P  + (mi2*16 + ml)*PST + k0 + quad*8);
      bf16x8 bv = *(const bf16x8*)(Vt + (ni*16  + ml)*PST + k0 + quad*8);
      acc2 = __builtin_amdgcn_mfma_f32_16x16x32_bf16(ap, bv, acc2, 0, 0, 0);
    }
  }
#pragma unroll
  for (int r = 0; r < 4; r++){
    int row = mi2*16 + quad*4 + r;
    sa_pre[((long)b*NPQ + n0 + row)*DIM + h*HD + ni*16 + ml] =
        f2bf(acc2[r] * inv_[mi2][r]);
  }
}

// =====================================================================
extern "C" void kernel_launch(void* const* d_in, const int* in_sizes, int n_in,
                              void* d_out, int out_size, void* d_ws, size_t ws_size,
                              hipStream_t stream){
  (void)in_sizes; (void)n_in; (void)out_size; (void)ws_size;
  const float* tgt  = (const float*)d_in[0];
  const float* mem  = (const float*)d_in[1];
  const float* qpos = (const float*)d_in[2];
  const float* kpos = (const float*)d_in[3];
  const float* cw1  = (const float*)d_in[4];  const float* cb1 = (const float*)d_in[5];
  const float* cw2  = (const float*)d_in[6];  const float* cb2 = (const float*)d_in[7];
  const float* cw3  = (const float*)d_in[8];  const float* cb3 = (const float*)d_in[9];
  const float* saw  = (const float*)d_in[10]; const float* sab = (const float*)d_in[11];
  const float* sow  = (const float*)d_in[12]; const float* sob = (const float*)d_in[13];
  const float* ln1w = (const float*)d_in[14]; const float* ln1b = (const float*)d_in[15];
  const float* ln2w = (const float*)d_in[16]; const float* ln2b = (const float*)d_in[17];
  const float* ln3w = (const float*)d_in[18]; const float* ln3b = (const float*)d_in[19];
  const float* f1w  = (const float*)d_in[20]; const float* f1bs = (const float*)d_in[21];
  const float* f2w  = (const float*)d_in[22]; const float* f2bs = (const float*)d_in[23];

  char* base = (char*)d_ws;
  size_t off = 0;
  auto alloc = [&](size_t bytes) -> char* {
    char* p = base + off;
    off += (bytes + 255) & ~(size_t)255;
    return p;
  };
  u16* cw1b = (u16*)alloc(65536u*2);
  u16* cw2b = (u16*)alloc(65536u*2);
  u16* cw3b = (u16*)alloc(65536u*2);   (void)cw3b;
  u16* sawb = (u16*)alloc(196608u*2);
  u16* sowb = (u16*)alloc(65536u*2);
  u16* f1wb = (u16*)alloc(524288u*2);
  u16* f2wb = (u16*)alloc(524288u*2);
  int* rns  = (int*)alloc(4096u*32*4);
  float* cbKV = (float*)alloc(512*4);
  size_t offB = off;
  u16* xnh = (u16*)alloc((size_t)4096*256*2);
  u16* xnl = (u16*)alloc((size_t)4096*256*2);
  u16* mnh = (u16*)alloc((size_t)32768*256*2);
  u16* mnl = (u16*)alloc((size_t)32768*256*2);
  u16* qc  = (u16*)alloc((size_t)4096*256*2);
  u16* kc  = (u16*)alloc((size_t)32768*256*2);
  u16* vc  = (u16*)alloc((size_t)32768*256*2);
  float* sim = (float*)alloc((size_t)8*512*4096*4);

  char* regC = (char*)sim;
  u16* qh   = (u16*)regC;                      // [4096][256]  2 MB
  u16* khvh = (u16*)(regC + 2097152);          // [32768][512] 32 MB
  char* regB = base + offB;
  size_t ob = 0;
  auto allocB = [&](size_t bytes) -> char* {
    char* p = regB + ob;
    ob += (bytes + 255) & ~(size_t)255;
    return p;
  };
  float* cross = (float*)allocB((size_t)4096*256*4);
  float* t1    = (float*)allocB((size_t)4096*256*4);
  u16*   t1b   = (u16*)allocB((size_t)4096*256*2);
  u16*   qkb   = (u16*)allocB((size_t)4096*256*2);
  u16*   qkv   = (u16*)allocB((size_t)4096*768*2);
  u16*   sa_pre= (u16*)allocB((size_t)4096*256*2);
  float* sa    = (float*)allocB((size_t)4096*256*4);
  float* t2    = (float*)allocB((size_t)4096*256*4);
  u16*   t2b   = (u16*)allocB((size_t)4096*256*2);
  u16*   h1    = (u16*)allocB((size_t)4096*2048*2);
  float* ff    = (float*)allocB((size_t)4096*256*4);

  const int BIG = 1 << 30;
  dim3 blk(256);
  cvt_all<<<dim3((1507328 + 255)/256), blk, 0, stream>>>(
      cw1, cw2, cw3, saw, sow, f1w, f2w, cw1b);
  prep_tgt<<<dim3(4096), blk, 0, stream>>>(tgt, qpos, xnh, xnl, qc, cb2, cb3, cbKV);
  prep_mem<<<dim3(32768), blk, 0, stream>>>(mem, kpos, mnh, mnl, kc, vc);
  sim_gemm<<<dim3(32,4,8), blk, 0, stream>>>(xnh, xnl, mnh, mnl, sim);
  topk_k<<<dim3(1024), blk, 0, stream>>>(sim, rns);
  pgemm<1,1,0><<<dim3(64,4), blk, 0, stream>>>(qc, qc, BIG, cw1b, cb1, qh, 256);
  pgemm<1,1,0><<<dim3(512,8), blk, 0, stream>>>(kc, vc, 256, cw2b, cbKV, khvh, 512);
  cross_attn<<<dim3(4096), blk, 0, stream>>>(qh, khvh, rns, cross);
  ln_k<1><<<dim3(4096), blk, 0, stream>>>(tgt, cross, qpos, ln1w, ln1b, t1, t1b, qkb);
  pgemm<1,1,0><<<dim3(64,12), blk, 0, stream>>>(qkb, t1b, 512, sawb, sab, qkv, 768);
  self_attn<<<dim3(16,8,8), blk, 0, stream>>>(qkv, sa_pre);
  pgemm<1,0,0><<<dim3(64,4), blk, 0, stream>>>(sa_pre, sa_pre, BIG, sowb, sob, sa, 256);
  ln_k<2><<<dim3(4096), blk, 0, stream>>>(t1, sa, nullptr, ln2w, ln2b, t2, t2b, nullptr);
  pgemm<1,1,1><<<dim3(64,32), blk, 0, stream>>>(t2b, t2b, BIG, f1wb, f1bs, h1, 2048);
  pgemm<8,0,0><<<dim3(64,4), blk, 0, stream>>>(h1, h1, BIG, f2wb, f2bs, ff, 256);
  ln_k<3><<<dim3(4096), blk, 0, stream>>>(t2, ff, nullptr, ln3w, ln3b, (float*)d_out, nullptr, nullptr);
}